// Round 8
// baseline (144.905 us; speedup 1.0000x reference)
//
#include <hip/hip_runtime.h>

#define EMB 384
#define HEADS 6
#define DH 64
#define TT 256

constexpr float SCALE = 0.05103103630798288f;  // 384^-0.5

typedef __attribute__((ext_vector_type(8))) short short8;
typedef __attribute__((ext_vector_type(4))) float f32x4;
typedef __attribute__((ext_vector_type(4))) unsigned short u16x4;

__device__ __forceinline__ unsigned short f2bf(float f) {
  unsigned int u = __builtin_bit_cast(unsigned int, f);
  u += 0x7FFFu + ((u >> 16) & 1u);   // RNE
  return (unsigned short)(u >> 16);
}
__device__ __forceinline__ float bf2f(unsigned short u) {
  unsigned int v = ((unsigned int)u) << 16;
  return __builtin_bit_cast(float, v);
}
__device__ __forceinline__ void gll16(const void* g, void* l) {
  __builtin_amdgcn_global_load_lds(
      (const __attribute__((address_space(1))) unsigned int*)g,
      (__attribute__((address_space(3))) unsigned int*)l, 16, 0, 0);
}

// ---------------- K0: build Wt[1536][384] bf16 (rows: q 0-383 | k | v | proj^T) ----
__global__ __launch_bounds__(256)
void build_wt(const float* __restrict__ Wq, const float* __restrict__ Wk,
              const float* __restrict__ Wv, const float* __restrict__ Wp,
              unsigned short* __restrict__ Wt) {
  int idx = blockIdx.x * 256 + threadIdx.x;  // 1536*48 = 73728
  int n = idx / 48, e0 = (idx % 48) * 8;
  const float* src; int stride;
  if (n < 1152) {
    int qkv = n / 384, rel = n % 384, h = rel >> 6, d = rel & 63;
    const float* W = (qkv == 0) ? Wq : (qkv == 1) ? Wk : Wv;
    src = W + ((size_t)h * EMB + e0) * DH + d; stride = DH;
  } else {
    int c = n - 1152;
    src = Wp + (size_t)e0 * EMB + c; stride = EMB;
  }
  short8 o;
  #pragma unroll
  for (int j = 0; j < 8; ++j) o[j] = (short)f2bf(src[j * stride]);
  ((short8*)Wt)[idx] = o;
}

// ---------------- panel-persistent GEMM, 3-buffer counted-vmcnt pipeline ----------
// 512 thr / 8 waves (4M x 2N, wave tile 32x64, acc[2][4]).
// A: 128-row panel, 96KB LDS, staged ONCE. B: 3 x 16KB rotating buffers;
// step g issues stage g+2, computes buf g%3, waits vmcnt(2) (stage g+1 landed,
// g+2 in flight) + raw s_barrier. Full drain only at tile boundary (kt==5).
// LDS 144KB -> 1 block/CU, grid = M/128 = 256 = exactly 1 per CU.
// MODE 0: A = x fp32 (reg-convert), NT=9, QKV epilogue (V transposed).
// MODE 1: A = O bf16 (gll16), NT=3, proj epilogue (fp32 + bias).
template<int MODE>
__global__ __launch_bounds__(512, 1)
void gemm_panel(const void* __restrict__ Asrc, const unsigned short* __restrict__ Bt,
                unsigned short* __restrict__ Qo, unsigned short* __restrict__ Ko,
                unsigned short* __restrict__ Vto,
                float* __restrict__ Co, const float* __restrict__ bias)
{
  constexpr int NT  = (MODE == 0) ? 9 : 3;
  constexpr int NTK = NT * 6;
  __shared__ short8 AL8[128 * 48];      // 96 KB : [row][pos], pos = (ch&~7)|((ch^row)&7)
  __shared__ short8 BL8[3][128 * 8];    // 3 x 16 KB

  const int tid = (int)threadIdx.x, w = tid >> 6, lane = tid & 63;
  const int la = lane & 15, kh = lane >> 4;
  const int m0 = blockIdx.x * 128;

  // ---- stage A panel once ----
  if (MODE == 0) {
    const int row = tid & 127, grp = tid >> 7;     // 4 groups x 12 chunks
    const float* xr = (const float*)Asrc + (size_t)(m0 + row) * 384;
    #pragma unroll
    for (int i = 0; i < 12; ++i) {
      const int ch = grp * 12 + i;
      float4 va = *(const float4*)(xr + ch * 8);
      float4 vb = *(const float4*)(xr + ch * 8 + 4);
      short8 o;
      o[0] = (short)f2bf(va.x); o[1] = (short)f2bf(va.y);
      o[2] = (short)f2bf(va.z); o[3] = (short)f2bf(va.w);
      o[4] = (short)f2bf(vb.x); o[5] = (short)f2bf(vb.y);
      o[6] = (short)f2bf(vb.z); o[7] = (short)f2bf(vb.w);
      AL8[row * 48 + ((ch & ~7) | ((ch ^ row) & 7))] = o;
    }
  } else {
    #pragma unroll
    for (int i = 0; i < 12; ++i) {
      const int Lb = i * 8192 + tid * 16;          // wave-linear LDS dest
      const int row = (Lb >> 8) / 3;               // 768 B per row
      const int pos = (Lb - row * 768) >> 4;       // 0..47
      const int src = (pos & ~7) | ((pos ^ row) & 7);
      gll16((const unsigned short*)Asrc + (size_t)(m0 + row) * 384 + src * 8,
            (char*)AL8 + Lb);
    }
  }

  // ---- B staging: global step g2 -> tile (n0=(g2/6)*128, k0=(g2%6)*64) ----
  auto stageB = [&](int buf, int g2) {
    const int n0 = (g2 / 6) * 128, k0 = (g2 - (g2 / 6) * 6) * 64;
    #pragma unroll
    for (int i = 0; i < 2; ++i) {
      const int Lb = i * 8192 + tid * 16;
      const int row = Lb >> 7;                     // 128 B per row
      const int kcs = ((Lb >> 4) & 7) ^ (row & 7);
      gll16(Bt + (size_t)(n0 + row) * 384 + k0 + kcs * 8, (char*)BL8[buf] + Lb);
    }
  };

  stageB(0, 0);
  stageB(1, 1);
  __syncthreads();   // drains A stage + B0,B1 (prologue only)

  const int wr = (w >> 1) * 32, wc = (w & 1) * 64;
  f32x4 acc[2][4];

  for (int g = 0; g < NTK; ++g) {
    const int nt = g / 6, kt = g - nt * 6;
    const int buf = g - (g / 3) * 3;
    if (g + 2 < NTK) stageB((g + 2) - ((g + 2) / 3) * 3, g + 2);
    if (kt == 0) {
      #pragma unroll
      for (int i = 0; i < 2; ++i)
        #pragma unroll
        for (int j = 0; j < 4; ++j) acc[i][j] = f32x4{0.f, 0.f, 0.f, 0.f};
    }

    #pragma unroll
    for (int kk = 0; kk < 2; ++kk) {
      short8 a[2], b[4];
      const int cl = kk * 4 + kh;                  // low-3 chunk index
      #pragma unroll
      for (int mi = 0; mi < 2; ++mi) {
        const int r = wr + mi * 16 + la;
        a[mi] = AL8[r * 48 + kt * 8 + (cl ^ (r & 7))];
      }
      #pragma unroll
      for (int ni = 0; ni < 4; ++ni) {
        const int rB = wc + ni * 16 + la;
        b[ni] = BL8[buf][rB * 8 + (cl ^ (rB & 7))];
      }
      __builtin_amdgcn_s_setprio(1);
      #pragma unroll
      for (int mi = 0; mi < 2; ++mi)
        #pragma unroll
        for (int ni = 0; ni < 4; ++ni)
          acc[mi][ni] = __builtin_amdgcn_mfma_f32_16x16x32_bf16(a[mi], b[ni], acc[mi][ni], 0, 0, 0);
      __builtin_amdgcn_s_setprio(0);
    }

    if (kt == 5) {
      // ---- epilogue for tile nt ----
      if (MODE == 0) {
        const int qkv = nt / 3;
        #pragma unroll
        for (int mi = 0; mi < 2; ++mi) {
          const int mbase = m0 + wr + mi * 16 + kh * 4;
          const int bb = mbase >> 8, tt = mbase & 255;
          #pragma unroll
          for (int ni = 0; ni < 4; ++ni) {
            const int nl = nt * 128 + wc + ni * 16 + la;
            const int rel = nl - qkv * 384;
            const int hh = rel >> 6, dd = rel & 63;
            if (qkv == 0) {
              #pragma unroll
              for (int j = 0; j < 4; ++j)
                Qo[(((size_t)bb * 6 + hh) * 256 + (tt + j)) * 64 + dd] = f2bf(acc[mi][ni][j]);
            } else if (qkv == 1) {
              #pragma unroll
              for (int j = 0; j < 4; ++j)
                Ko[(((size_t)bb * 6 + hh) * 256 + (tt + j)) * 64 + dd] = f2bf(acc[mi][ni][j]);
            } else {
              u16x4 pk;
              #pragma unroll
              for (int j = 0; j < 4; ++j) pk[j] = f2bf(acc[mi][ni][j]);
              *(u16x4*)(Vto + (((size_t)bb * 6 + hh) * 64 + dd) * 256 + tt) = pk;  // Vt[b,h,d,t]
            }
          }
        }
      } else {
        #pragma unroll
        for (int mi = 0; mi < 2; ++mi) {
          const int mbase = m0 + wr + mi * 16 + kh * 4;
          #pragma unroll
          for (int ni = 0; ni < 4; ++ni) {
            const int nl = nt * 128 + wc + ni * 16 + la;
            const float bn = bias[nl];
            #pragma unroll
            for (int j = 0; j < 4; ++j)
              Co[(size_t)(mbase + j) * 384 + nl] = acc[mi][ni][j] + bn;
          }
        }
      }
      asm volatile("s_waitcnt vmcnt(0)" ::: "memory");   // tile-boundary drain
    } else {
      asm volatile("s_waitcnt vmcnt(2)" ::: "memory");   // stage g+1 landed; g+2 in flight
    }
    __builtin_amdgcn_s_barrier();
  }
}

// ---------------- K2: attention, per-KEY (axis=2) softmax, 8 waves ----------------
__global__ __launch_bounds__(512, 1)
void attn_col(const unsigned short* __restrict__ Q, const unsigned short* __restrict__ K,
              const unsigned short* __restrict__ Vt, unsigned short* __restrict__ O)
{
  __shared__ __align__(16) char KL[32768];   // K [256][64] bf16, swizzled (8 chunks/row)
  __shared__ __align__(16) char VL[32768];   // V^T [64][256] bf16, swizzled (32 chunks/row)
  __shared__ __align__(16) char EL[73728];   // E strips, padded to K=32 multiples
  __shared__ float Lpart[8][256];
  __shared__ float invL[256];

  const int bh = blockIdx.x, tid = (int)threadIdx.x;
  const int w = tid >> 6, lane = tid & 63;
  const int la = lane & 15, kh = lane >> 4;
  const unsigned short* Qg = Q + (size_t)bh * 16384;
  const unsigned short* Kg = K + (size_t)bh * 16384;
  const unsigned short* Vg = Vt + (size_t)bh * 16384;

  #pragma unroll
  for (int i = 0; i < 4; ++i) {
    const int Lb = i * 8192 + tid * 16;
    { const int row = Lb >> 7, kcs = ((Lb >> 4) & 7) ^ (row & 7);
      gll16(Kg + row * 64 + kcs * 8, KL + Lb); }
    { const int row = Lb >> 9, kcs = ((Lb >> 4) & 31) ^ (row & 7);
      gll16(Vg + row * 256 + kcs * 8, VL + Lb); }
  }
  __syncthreads();

  const int rts[2] = { w, 15 - w };
  int wps[2], eoffs[2];
  #pragma unroll
  for (int ti = 0; ti < 2; ++ti) {
    const int rt = rts[ti];
    wps[ti] = 32 * ((rt + 2) >> 1);
    const int S = (rt & 1) ? ((rt + 1) * (rt + 1) / 4) : (rt * (rt + 2) / 4);
    eoffs[ti] = 1024 * S;
  }

  // ---- QK^T + masked exp -> E strips ----
  #pragma unroll
  for (int ti = 0; ti < 2; ++ti) {
    const int rt = rts[ti], wp = wps[ti], stride = wp * 2;
    char* Ebase = EL + eoffs[ti];
    short8 qa[2];
    #pragma unroll
    for (int kk = 0; kk < 2; ++kk)
      qa[kk] = *(const short8*)(Qg + (rt * 16 + la) * 64 + (kk * 4 + kh) * 8);
    const int nns = wp >> 4;
    for (int ns = 0; ns < nns; ++ns) {
      f32x4 s4 = f32x4{0.f, 0.f, 0.f, 0.f};
      #pragma unroll
      for (int kk = 0; kk < 2; ++kk) {
        const int rB = ns * 16 + la, kc = kk * 4 + kh;
        short8 bf = *(const short8*)(KL + rB * 128 + ((kc ^ (rB & 7)) << 4));
        s4 = __builtin_amdgcn_mfma_f32_16x16x32_bf16(qa[kk], bf, s4, 0, 0, 0);
      }
      const int c = ns * 16 + la, cc = c >> 3, co = (c & 7) * 2;
      #pragma unroll
      for (int j = 0; j < 4; ++j) {
        const int r = kh * 4 + j;
        const int t = rt * 16 + r;
        const float e = (t >= c) ? __expf(s4[j] * SCALE) : 0.f;
        *(unsigned short*)(Ebase + r * stride + ((cc ^ (r & 3)) << 4) + co) = f2bf(e);
      }
    }
  }
  __syncthreads();

  // ---- column partial sums ----
  {
    float acc4[4] = {0.f, 0.f, 0.f, 0.f};
    #pragma unroll
    for (int ti = 0; ti < 2; ++ti) {
      const int wp = wps[ti], stride = wp * 2;
      const char* Ebase = EL + eoffs[ti];
      #pragma unroll
      for (int cb = 0; cb < 4; ++cb) {
        const int c = cb * 64 + lane;
        if (c < wp) {
          const int cc = c >> 3, co = (c & 7) * 2;
          float p = 0.f;
          #pragma unroll
          for (int r = 0; r < 16; ++r)
            p += bf2f(*(const unsigned short*)(Ebase + r * stride + ((cc ^ (r & 3)) << 4) + co));
          acc4[cb] += p;
        }
      }
    }
    #pragma unroll
    for (int cb = 0; cb < 4; ++cb) Lpart[w][cb * 64 + lane] = acc4[cb];
  }
  __syncthreads();
  if (tid < 256) {
    float Ls = 0.f;
    #pragma unroll
    for (int ww = 0; ww < 8; ++ww) Ls += Lpart[ww][tid];
    invL[tid] = 1.f / Ls;
  }
  __syncthreads();

  // ---- fold 1/L_s into V ----
  {
    const int d = tid >> 3, qq = tid & 7;
    #pragma unroll
    for (int i = 0; i < 4; ++i) {
      const int kcp = qq * 4 + i;
      char* p = VL + d * 512 + kcp * 16;
      short8 v = *(short8*)p;
      const int sb = (kcp ^ (d & 7)) * 8;
      short8 o;
      #pragma unroll
      for (int e = 0; e < 8; ++e)
        o[e] = (short)f2bf(bf2f((unsigned short)v[e]) * invL[sb + e]);
      *(short8*)p = o;
    }
  }
  __syncthreads();

  // ---- O = E * V' ----
  const int b = bh / 6, h = bh - b * 6;
  unsigned short* Og = O + (size_t)b * 256 * 384 + h * 64;
  #pragma unroll
  for (int ti = 0; ti < 2; ++ti) {
    const int rt = rts[ti], wp = wps[ti], stride = wp * 2;
    const char* Ebase = EL + eoffs[ti];
    f32x4 oacc[4];
    #pragma unroll
    for (int nd = 0; nd < 4; ++nd) oacc[nd] = f32x4{0.f, 0.f, 0.f, 0.f};
    const int nks = wp >> 5;
    for (int ks = 0; ks < nks; ++ks) {
      const int cc = ks * 4 + kh;
      short8 ea = *(const short8*)(Ebase + la * stride + ((cc ^ (la & 3)) << 4));
      __builtin_amdgcn_s_setprio(1);
      #pragma unroll
      for (int nd = 0; nd < 4; ++nd) {
        const int d = nd * 16 + la;
        short8 vb = *(const short8*)(VL + d * 512 + ((cc ^ (d & 7)) << 4));
        oacc[nd] = __builtin_amdgcn_mfma_f32_16x16x32_bf16(ea, vb, oacc[nd], 0, 0, 0);
      }
      __builtin_amdgcn_s_setprio(0);
    }
    #pragma unroll
    for (int nd = 0; nd < 4; ++nd) {
      const int d = nd * 16 + la;
      #pragma unroll
      for (int j = 0; j < 4; ++j) {
        const int t = rt * 16 + kh * 4 + j;
        Og[(size_t)t * 384 + d] = f2bf(oacc[nd][j]);
      }
    }
  }
}

// ================= fallback (fp32) for small ws =================
__global__ __launch_bounds__(256, 1)
void mha_fused(const float* __restrict__ x, const float* __restrict__ Wq,
               const float* __restrict__ Wk, const float* __restrict__ Wv,
               const float* __restrict__ Wp, const float* __restrict__ bp,
               float* __restrict__ out)
{
  const int bh = blockIdx.x;
  const int b = bh / HEADS, h = bh % HEADS;
  const int tid = (int)threadIdx.x;
  const int wave = tid >> 6, lane = tid & 63;
  const float* xb = x + (size_t)b * TT * EMB;
  const float* wq = Wq + (size_t)h * EMB * DH;
  const float* wk = Wk + (size_t)h * EMB * DH;
  const float* wv = Wv + (size_t)h * EMB * DH;
  __shared__ float Ks[TT][68];
  __shared__ float Vs[TT][64];
  __shared__ float Qt[64][68];
  for (int c = 0; c < 4; ++c) {
    const int s0 = wave * 64 + c * 16;
    float ak[16], av[16];
    #pragma unroll
    for (int r = 0; r < 16; ++r) { ak[r] = 0.f; av[r] = 0.f; }
    for (int e = 0; e < EMB; ++e) {
      const float kk = wk[e * DH + lane];
      const float vv = wv[e * DH + lane];
      #pragma unroll
      for (int r = 0; r < 16; ++r) {
        const float xv = xb[(s0 + r) * EMB + e];
        ak[r] += xv * kk; av[r] += xv * vv;
      }
    }
    #pragma unroll
    for (int r = 0; r < 16; ++r) { Ks[s0 + r][lane] = ak[r]; Vs[s0 + r][lane] = av[r]; }
  }
  __syncthreads();
  const int s = tid;
  float kreg[64];
  {
    const float4* k4 = (const float4*)&Ks[s][0];
    #pragma unroll
    for (int i = 0; i < 16; ++i) {
      float4 kv = k4[i];
      kreg[4*i+0] = kv.x; kreg[4*i+1] = kv.y; kreg[4*i+2] = kv.z; kreg[4*i+3] = kv.w;
    }
  }
  float Lsum = 0.f;
  for (int tile = 0; tile < 4; ++tile) {
    {
      const int r0 = tile * 64 + wave * 16;
      float aq[16];
      #pragma unroll
      for (int r = 0; r < 16; ++r) aq[r] = 0.f;
      for (int e = 0; e < EMB; ++e) {
        const float qw = wq[e * DH + lane];
        #pragma unroll
        for (int r = 0; r < 16; ++r) aq[r] += xb[(r0 + r) * EMB + e] * qw;
      }
      __syncthreads();
      #pragma unroll
      for (int r = 0; r < 16; ++r) Qt[wave*16 + r][lane] = aq[r];
      __syncthreads();
    }
    const int tbase = tile * 64;
    if (tbase + 63 >= s) {
      for (int tr = 0; tr < 64; ++tr) {
        const int t = tbase + tr;
        if (t < s) continue;
        float w = 0.f;
        const float4* q4 = (const float4*)&Qt[tr][0];
        #pragma unroll
        for (int i = 0; i < 16; ++i) {
          float4 qv = q4[i];
          w += qv.x*kreg[4*i+0] + qv.y*kreg[4*i+1] + qv.z*kreg[4*i+2] + qv.w*kreg[4*i+3];
        }
        Lsum += __expf(w * SCALE);
      }
    }
  }
  __syncthreads();
  {
    const float invL = 1.0f / Lsum;
    float4* v4 = (float4*)&Vs[s][0];
    #pragma unroll
    for (int i = 0; i < 16; ++i) {
      float4 vv = v4[i];
      vv.x *= invL; vv.y *= invL; vv.z *= invL; vv.w *= invL;
      v4[i] = vv;
    }
  }
  __syncthreads();
  const float bias1 = bp[tid];
  const float bias2 = (tid < 128) ? bp[256 + tid] : 0.f;
  const int tr = tid >> 2, dq = tid & 3;
  float* ob = out + (size_t)b * TT * EMB;
  for (int tile = 0; tile < 4; ++tile) {
    {
      const int r0 = tile * 64 + wave * 16;
      float aq[16];
      #pragma unroll
      for (int r = 0; r < 16; ++r) aq[r] = 0.f;
      for (int e = 0; e < EMB; ++e) {
        const float qw = wq[e * DH + lane];
        #pragma unroll
        for (int r = 0; r < 16; ++r) aq[r] += xb[(r0 + r) * EMB + e] * qw;
      }
      __syncthreads();
      #pragma unroll
      for (int r = 0; r < 16; ++r) Qt[wave*16 + r][lane] = aq[r];
      __syncthreads();
    }
    const int t = tile * 64 + tr;
    float qreg[16];
    {
      const float4* q4 = (const float4*)&Qt[tr][dq * 16];
      #pragma unroll
      for (int i = 0; i < 4; ++i) {
        float4 qv = q4[i];
        qreg[4*i+0] = qv.x; qreg[4*i+1] = qv.y; qreg[4*i+2] = qv.z; qreg[4*i+3] = qv.w;
      }
    }
    float acc[16];
    #pragma unroll
    for (int i = 0; i < 16; ++i) acc[i] = 0.f;
    for (int s2 = 0; s2 <= t; ++s2) {
      const float4* kk4 = (const float4*)&Ks[s2][dq * 16];
      float part = 0.f;
      #pragma unroll
      for (int i = 0; i < 4; ++i) {
        float4 kv = kk4[i];
        part += qreg[4*i+0]*kv.x + qreg[4*i+1]*kv.y + qreg[4*i+2]*kv.z + qreg[4*i+3]*kv.w;
      }
      part += __shfl_xor(part, 1);
      part += __shfl_xor(part, 2);
      const float p = __expf(part * SCALE);
      const float4* vv4 = (const float4*)&Vs[s2][dq * 16];
      #pragma unroll
      for (int i = 0; i < 4; ++i) {
        float4 vv = vv4[i];
        acc[4*i+0] += p * vv.x; acc[4*i+1] += p * vv.y;
        acc[4*i+2] += p * vv.z; acc[4*i+3] += p * vv.w;
      }
    }
    __syncthreads();
    #pragma unroll
    for (int i = 0; i < 16; ++i) Qt[tr][dq*16 + i] = acc[i];
    __syncthreads();
    const int c1 = tid;
    const int c2 = 256 + tid;
    for (int rg = 0; rg < 4; ++rg) {
      float a1[16], a2[16];
      #pragma unroll
      for (int r = 0; r < 16; ++r) { a1[r] = 0.f; a2[r] = 0.f; }
      for (int d = 0; d < 64; ++d) {
        const float wp1 = Wp[(size_t)(h*64 + d) * EMB + c1];
        const float wp2 = (tid < 128) ? Wp[(size_t)(h*64 + d) * EMB + c2] : 0.f;
        #pragma unroll
        for (int r = 0; r < 16; ++r) {
          const float a = Qt[rg*16 + r][d];
          a1[r] += a * wp1; a2[r] += a * wp2;
        }
      }
      if (h == 0) {
        #pragma unroll
        for (int r = 0; r < 16; ++r) { a1[r] += bias1; a2[r] += bias2; }
      }
      const int trow0 = tile*64 + rg*16;
      #pragma unroll
      for (int r = 0; r < 16; ++r)
        atomicAdd(&ob[(size_t)(trow0 + r) * EMB + c1], a1[r]);
      if (tid < 128) {
        #pragma unroll
        for (int r = 0; r < 16; ++r)
          atomicAdd(&ob[(size_t)(trow0 + r) * EMB + c2], a2[r]);
      }
    }
    __syncthreads();
  }
}

extern "C" void kernel_launch(void* const* d_in, const int* in_sizes, int n_in,
                              void* d_out, int out_size, void* d_ws, size_t ws_size,
                              hipStream_t stream) {
  const float* x  = (const float*)d_in[0];
  const float* Wq = (const float*)d_in[1];
  const float* Wk = (const float*)d_in[2];
  const float* Wv = (const float*)d_in[3];
  const float* Wp = (const float*)d_in[4];
  const float* bp = (const float*)d_in[5];

  const int nb = in_sizes[0] / (TT * EMB);       // batch (128)
  const size_t M = (size_t)nb * TT;              // 32768 rows
  const size_t XB = M * EMB * 2;                 // bf16 activation bytes (25 MB)
  const size_t WT = (size_t)1536 * 384 * 2;

  const size_t off_wt = 0;
  const size_t off_q  = off_wt + WT;
  const size_t off_k  = off_q + XB;
  const size_t off_vt = off_k + XB;
  const size_t off_o  = off_vt + XB;
  const size_t need   = off_o + XB;

  if (ws_size < need) {
    hipMemsetAsync(d_out, 0, (size_t)out_size * sizeof(float), stream);
    mha_fused<<<nb * HEADS, 256, 0, stream>>>(x, Wq, Wk, Wv, Wp, bp, (float*)d_out);
    return;
  }

  char* ws = (char*)d_ws;
  unsigned short* Wt  = (unsigned short*)(ws + off_wt);
  unsigned short* Qw  = (unsigned short*)(ws + off_q);
  unsigned short* Kw  = (unsigned short*)(ws + off_k);
  unsigned short* Vtw = (unsigned short*)(ws + off_vt);
  unsigned short* Ow  = (unsigned short*)(ws + off_o);

  build_wt<<<288, 256, 0, stream>>>(Wq, Wk, Wv, Wp, Wt);

  gemm_panel<0><<<(unsigned)(M / 128), 512, 0, stream>>>(
      (const void*)x, Wt, Qw, Kw, Vtw, nullptr, nullptr);

  attn_col<<<nb * HEADS, 512, 0, stream>>>(Qw, Kw, Vtw, Ow);

  gemm_panel<1><<<(unsigned)(M / 128), 512, 0, stream>>>(
      (const void*)Ow, Wt + (size_t)1152 * 384, nullptr, nullptr, nullptr,
      (float*)d_out, bp);
}

// Round 9
// 143.053 us; speedup vs baseline: 1.0129x; 1.0129x over previous
//
#include <hip/hip_runtime.h>

#define EMB 384
#define HEADS 6
#define DH 64
#define TT 256

constexpr float SCALE = 0.05103103630798288f;  // 384^-0.5

typedef __attribute__((ext_vector_type(8))) short short8;
typedef __attribute__((ext_vector_type(4))) float f32x4;
typedef __attribute__((ext_vector_type(4))) unsigned short u16x4;

__device__ __forceinline__ unsigned short f2bf(float f) {
  unsigned int u = __builtin_bit_cast(unsigned int, f);
  u += 0x7FFFu + ((u >> 16) & 1u);   // RNE
  return (unsigned short)(u >> 16);
}
__device__ __forceinline__ float bf2f(unsigned short u) {
  unsigned int v = ((unsigned int)u) << 16;
  return __builtin_bit_cast(float, v);
}
__device__ __forceinline__ void gll16(const void* g, void* l) {
  __builtin_amdgcn_global_load_lds(
      (const __attribute__((address_space(1))) unsigned int*)g,
      (__attribute__((address_space(3))) unsigned int*)l, 16, 0, 0);
}

// ---------------- K0: build Wt[1536][384] bf16 (rows: q 0-383 | k | v | proj^T) ----
__global__ __launch_bounds__(256)
void build_wt(const float* __restrict__ Wq, const float* __restrict__ Wk,
              const float* __restrict__ Wv, const float* __restrict__ Wp,
              unsigned short* __restrict__ Wt) {
  int idx = blockIdx.x * 256 + threadIdx.x;  // 1536*48 = 73728
  int n = idx / 48, e0 = (idx % 48) * 8;
  const float* src; int stride;
  if (n < 1152) {
    int qkv = n / 384, rel = n % 384, h = rel >> 6, d = rel & 63;
    const float* W = (qkv == 0) ? Wq : (qkv == 1) ? Wk : Wv;
    src = W + ((size_t)h * EMB + e0) * DH + d; stride = DH;
  } else {
    int c = n - 1152;
    src = Wp + (size_t)e0 * EMB + c; stride = EMB;
  }
  short8 o;
  #pragma unroll
  for (int j = 0; j < 8; ++j) o[j] = (short)f2bf(src[j * stride]);
  ((short8*)Wt)[idx] = o;
}

// ---------------- barrier-free GEMM: A panel in LDS, B direct from L2 ----------------
// 256 thr / 4 waves. Block owns a 64-row A-panel (48KB LDS, staged once,
// row=lane conflict-free swizzle). B (Wt, 1.1MB, L2-resident) is loaded per-wave
// straight into registers: per-lane base pointer + immediate offsets -> the
// compiler software-pipelines with per-wave vmcnt. ONE __syncthreads total.
// Wave tile 64x32: acc[4][2], per kt: 4 ds_read(A) + 2 global(B) + 8 MFMA.
// 48KB LDS -> 3 blocks/CU ceiling.
// MODE 0: A = x fp32 (reg-convert in stage), NT=9, QKV epilogue (V transposed).
// MODE 1: A = O bf16, NT=3, proj epilogue (fp32 + bias).
template<int MODE>
__global__ __launch_bounds__(256, 3)
void gemm_l2(const void* __restrict__ Asrc, const unsigned short* __restrict__ Bt,
             unsigned short* __restrict__ Qo, unsigned short* __restrict__ Ko,
             unsigned short* __restrict__ Vto,
             float* __restrict__ Co, const float* __restrict__ bias)
{
  constexpr int NT = (MODE == 0) ? 9 : 3;
  __shared__ short8 AL8[64 * 48];       // 48 KB : [row][pos], pos = (ch&~7)|((ch^row)&7)

  const int tid = (int)threadIdx.x, w = tid >> 6, lane = tid & 63;
  const int la = lane & 15, kh = lane >> 4;
  const int m0 = blockIdx.x * 64;

  // ---- stage A panel once: row = lane (conflict-free ds_write_b128) ----
  {
    const int row = lane;               // wave w covers chunks w, w+4, ..., w+44
    if (MODE == 0) {
      const float* xr = (const float*)Asrc + (size_t)(m0 + row) * 384;
      #pragma unroll
      for (int i = 0; i < 12; ++i) {
        const int ch = w + 4 * i;
        float4 va = *(const float4*)(xr + ch * 8);
        float4 vb = *(const float4*)(xr + ch * 8 + 4);
        short8 o;
        o[0] = (short)f2bf(va.x); o[1] = (short)f2bf(va.y);
        o[2] = (short)f2bf(va.z); o[3] = (short)f2bf(va.w);
        o[4] = (short)f2bf(vb.x); o[5] = (short)f2bf(vb.y);
        o[6] = (short)f2bf(vb.z); o[7] = (short)f2bf(vb.w);
        AL8[row * 48 + ((ch & ~7) | ((ch ^ row) & 7))] = o;
      }
    } else {
      const short8* O8 = (const short8*)((const unsigned short*)Asrc + (size_t)(m0 + row) * 384);
      #pragma unroll
      for (int i = 0; i < 12; ++i) {
        const int ch = w + 4 * i;
        AL8[row * 48 + ((ch & ~7) | ((ch ^ row) & 7))] = O8[ch];
      }
    }
  }
  __syncthreads();   // the ONLY block-wide barrier

  const int s7 = la & 7;   // r&7 for all my A rows (r = mi*16+la)

  for (int nt = 0; nt < NT; ++nt) {
    const int nb0 = nt * 128 + w * 32;            // wave's 32-col strip base row in Bt
    const unsigned short* p0 = Bt + (size_t)(nb0 + la) * 384 + kh * 8;
    const unsigned short* p1 = p0 + 16 * 384;

    f32x4 acc[4][2];
    #pragma unroll
    for (int i = 0; i < 4; ++i) { acc[i][0] = f32x4{0.f,0.f,0.f,0.f}; acc[i][1] = f32x4{0.f,0.f,0.f,0.f}; }

    #pragma unroll
    for (int kt = 0; kt < 12; ++kt) {
      short8 b0 = *(const short8*)(p0 + kt * 32);   // imm offset kt*64 bytes
      short8 b1 = *(const short8*)(p1 + kt * 32);
      const int ch = kt * 4 + kh;
      const int pos = (ch & ~7) | ((ch & 7) ^ s7);
      short8 a[4];
      #pragma unroll
      for (int mi = 0; mi < 4; ++mi)
        a[mi] = AL8[(mi * 16 + la) * 48 + pos];
      __builtin_amdgcn_s_setprio(1);
      #pragma unroll
      for (int mi = 0; mi < 4; ++mi) {
        acc[mi][0] = __builtin_amdgcn_mfma_f32_16x16x32_bf16(a[mi], b0, acc[mi][0], 0, 0, 0);
        acc[mi][1] = __builtin_amdgcn_mfma_f32_16x16x32_bf16(a[mi], b1, acc[mi][1], 0, 0, 0);
      }
      __builtin_amdgcn_s_setprio(0);
    }

    // ---- epilogue for this N-tile ----
    if (MODE == 0) {
      const int qkv = nt / 3;
      #pragma unroll
      for (int mi = 0; mi < 4; ++mi) {
        const int mbase = m0 + mi * 16 + kh * 4;
        const int bb = mbase >> 8, tt = mbase & 255;
        #pragma unroll
        for (int ni = 0; ni < 2; ++ni) {
          const int nl = nt * 128 + w * 32 + ni * 16 + la;
          const int rel = nl - qkv * 384;
          const int hh = rel >> 6, dd = rel & 63;
          if (qkv == 0) {
            #pragma unroll
            for (int j = 0; j < 4; ++j)
              Qo[(((size_t)bb * 6 + hh) * 256 + (tt + j)) * 64 + dd] = f2bf(acc[mi][ni][j]);
          } else if (qkv == 1) {
            #pragma unroll
            for (int j = 0; j < 4; ++j)
              Ko[(((size_t)bb * 6 + hh) * 256 + (tt + j)) * 64 + dd] = f2bf(acc[mi][ni][j]);
          } else {
            u16x4 pk;
            #pragma unroll
            for (int j = 0; j < 4; ++j) pk[j] = f2bf(acc[mi][ni][j]);
            *(u16x4*)(Vto + (((size_t)bb * 6 + hh) * 64 + dd) * 256 + tt) = pk;  // Vt[b,h,d,t]
          }
        }
      }
    } else {
      #pragma unroll
      for (int mi = 0; mi < 4; ++mi) {
        const int mbase = m0 + mi * 16 + kh * 4;
        #pragma unroll
        for (int ni = 0; ni < 2; ++ni) {
          const int nl = nt * 128 + w * 32 + ni * 16 + la;
          const float bn = bias[nl];
          #pragma unroll
          for (int j = 0; j < 4; ++j)
            Co[(size_t)(mbase + j) * 384 + nl] = acc[mi][ni][j] + bn;
        }
      }
    }
  }
}

// ---------------- K2: attention, per-KEY (axis=2) softmax, 8 waves ----------------
__global__ __launch_bounds__(512, 1)
void attn_col(const unsigned short* __restrict__ Q, const unsigned short* __restrict__ K,
              const unsigned short* __restrict__ Vt, unsigned short* __restrict__ O)
{
  __shared__ __align__(16) char KL[32768];   // K [256][64] bf16, swizzled (8 chunks/row)
  __shared__ __align__(16) char VL[32768];   // V^T [64][256] bf16, swizzled (32 chunks/row)
  __shared__ __align__(16) char EL[73728];   // E strips, padded to K=32 multiples
  __shared__ float Lpart[8][256];
  __shared__ float invL[256];

  const int bh = blockIdx.x, tid = (int)threadIdx.x;
  const int w = tid >> 6, lane = tid & 63;
  const int la = lane & 15, kh = lane >> 4;
  const unsigned short* Qg = Q + (size_t)bh * 16384;
  const unsigned short* Kg = K + (size_t)bh * 16384;
  const unsigned short* Vg = Vt + (size_t)bh * 16384;

  #pragma unroll
  for (int i = 0; i < 4; ++i) {
    const int Lb = i * 8192 + tid * 16;
    { const int row = Lb >> 7, kcs = ((Lb >> 4) & 7) ^ (row & 7);
      gll16(Kg + row * 64 + kcs * 8, KL + Lb); }
    { const int row = Lb >> 9, kcs = ((Lb >> 4) & 31) ^ (row & 7);
      gll16(Vg + row * 256 + kcs * 8, VL + Lb); }
  }
  __syncthreads();

  const int rts[2] = { w, 15 - w };
  int wps[2], eoffs[2];
  #pragma unroll
  for (int ti = 0; ti < 2; ++ti) {
    const int rt = rts[ti];
    wps[ti] = 32 * ((rt + 2) >> 1);
    const int S = (rt & 1) ? ((rt + 1) * (rt + 1) / 4) : (rt * (rt + 2) / 4);
    eoffs[ti] = 1024 * S;
  }

  // ---- QK^T + masked exp -> E strips ----
  #pragma unroll
  for (int ti = 0; ti < 2; ++ti) {
    const int rt = rts[ti], wp = wps[ti], stride = wp * 2;
    char* Ebase = EL + eoffs[ti];
    short8 qa[2];
    #pragma unroll
    for (int kk = 0; kk < 2; ++kk)
      qa[kk] = *(const short8*)(Qg + (rt * 16 + la) * 64 + (kk * 4 + kh) * 8);
    const int nns = wp >> 4;
    for (int ns = 0; ns < nns; ++ns) {
      f32x4 s4 = f32x4{0.f, 0.f, 0.f, 0.f};
      #pragma unroll
      for (int kk = 0; kk < 2; ++kk) {
        const int rB = ns * 16 + la, kc = kk * 4 + kh;
        short8 bf = *(const short8*)(KL + rB * 128 + ((kc ^ (rB & 7)) << 4));
        s4 = __builtin_amdgcn_mfma_f32_16x16x32_bf16(qa[kk], bf, s4, 0, 0, 0);
      }
      const int c = ns * 16 + la, cc = c >> 3, co = (c & 7) * 2;
      #pragma unroll
      for (int j = 0; j < 4; ++j) {
        const int r = kh * 4 + j;
        const int t = rt * 16 + r;
        const float e = (t >= c) ? __expf(s4[j] * SCALE) : 0.f;
        *(unsigned short*)(Ebase + r * stride + ((cc ^ (r & 3)) << 4) + co) = f2bf(e);
      }
    }
  }
  __syncthreads();

  // ---- column partial sums ----
  {
    float acc4[4] = {0.f, 0.f, 0.f, 0.f};
    #pragma unroll
    for (int ti = 0; ti < 2; ++ti) {
      const int wp = wps[ti], stride = wp * 2;
      const char* Ebase = EL + eoffs[ti];
      #pragma unroll
      for (int cb = 0; cb < 4; ++cb) {
        const int c = cb * 64 + lane;
        if (c < wp) {
          const int cc = c >> 3, co = (c & 7) * 2;
          float p = 0.f;
          #pragma unroll
          for (int r = 0; r < 16; ++r)
            p += bf2f(*(const unsigned short*)(Ebase + r * stride + ((cc ^ (r & 3)) << 4) + co));
          acc4[cb] += p;
        }
      }
    }
    #pragma unroll
    for (int cb = 0; cb < 4; ++cb) Lpart[w][cb * 64 + lane] = acc4[cb];
  }
  __syncthreads();
  if (tid < 256) {
    float Ls = 0.f;
    #pragma unroll
    for (int ww = 0; ww < 8; ++ww) Ls += Lpart[ww][tid];
    invL[tid] = 1.f / Ls;
  }
  __syncthreads();

  // ---- fold 1/L_s into V ----
  {
    const int d = tid >> 3, qq = tid & 7;
    #pragma unroll
    for (int i = 0; i < 4; ++i) {
      const int kcp = qq * 4 + i;
      char* p = VL + d * 512 + kcp * 16;
      short8 v = *(short8*)p;
      const int sb = (kcp ^ (d & 7)) * 8;
      short8 o;
      #pragma unroll
      for (int e = 0; e < 8; ++e)
        o[e] = (short)f2bf(bf2f((unsigned short)v[e]) * invL[sb + e]);
      *(short8*)p = o;
    }
  }
  __syncthreads();

  // ---- O = E * V' ----
  const int b = bh / 6, h = bh - b * 6;
  unsigned short* Og = O + (size_t)b * 256 * 384 + h * 64;
  #pragma unroll
  for (int ti = 0; ti < 2; ++ti) {
    const int rt = rts[ti], wp = wps[ti], stride = wp * 2;
    const char* Ebase = EL + eoffs[ti];
    f32x4 oacc[4];
    #pragma unroll
    for (int nd = 0; nd < 4; ++nd) oacc[nd] = f32x4{0.f, 0.f, 0.f, 0.f};
    const int nks = wp >> 5;
    for (int ks = 0; ks < nks; ++ks) {
      const int cc = ks * 4 + kh;
      short8 ea = *(const short8*)(Ebase + la * stride + ((cc ^ (la & 3)) << 4));
      __builtin_amdgcn_s_setprio(1);
      #pragma unroll
      for (int nd = 0; nd < 4; ++nd) {
        const int d = nd * 16 + la;
        short8 vb = *(const short8*)(VL + d * 512 + ((cc ^ (d & 7)) << 4));
        oacc[nd] = __builtin_amdgcn_mfma_f32_16x16x32_bf16(ea, vb, oacc[nd], 0, 0, 0);
      }
      __builtin_amdgcn_s_setprio(0);
    }
    #pragma unroll
    for (int nd = 0; nd < 4; ++nd) {
      const int d = nd * 16 + la;
      #pragma unroll
      for (int j = 0; j < 4; ++j) {
        const int t = rt * 16 + kh * 4 + j;
        Og[(size_t)t * 384 + d] = f2bf(oacc[nd][j]);
      }
    }
  }
}

// ================= fallback (fp32) for small ws =================
__global__ __launch_bounds__(256, 1)
void mha_fused(const float* __restrict__ x, const float* __restrict__ Wq,
               const float* __restrict__ Wk, const float* __restrict__ Wv,
               const float* __restrict__ Wp, const float* __restrict__ bp,
               float* __restrict__ out)
{
  const int bh = blockIdx.x;
  const int b = bh / HEADS, h = bh % HEADS;
  const int tid = (int)threadIdx.x;
  const int wave = tid >> 6, lane = tid & 63;
  const float* xb = x + (size_t)b * TT * EMB;
  const float* wq = Wq + (size_t)h * EMB * DH;
  const float* wk = Wk + (size_t)h * EMB * DH;
  const float* wv = Wv + (size_t)h * EMB * DH;
  __shared__ float Ks[TT][68];
  __shared__ float Vs[TT][64];
  __shared__ float Qt[64][68];
  for (int c = 0; c < 4; ++c) {
    const int s0 = wave * 64 + c * 16;
    float ak[16], av[16];
    #pragma unroll
    for (int r = 0; r < 16; ++r) { ak[r] = 0.f; av[r] = 0.f; }
    for (int e = 0; e < EMB; ++e) {
      const float kk = wk[e * DH + lane];
      const float vv = wv[e * DH + lane];
      #pragma unroll
      for (int r = 0; r < 16; ++r) {
        const float xv = xb[(s0 + r) * EMB + e];
        ak[r] += xv * kk; av[r] += xv * vv;
      }
    }
    #pragma unroll
    for (int r = 0; r < 16; ++r) { Ks[s0 + r][lane] = ak[r]; Vs[s0 + r][lane] = av[r]; }
  }
  __syncthreads();
  const int s = tid;
  float kreg[64];
  {
    const float4* k4 = (const float4*)&Ks[s][0];
    #pragma unroll
    for (int i = 0; i < 16; ++i) {
      float4 kv = k4[i];
      kreg[4*i+0] = kv.x; kreg[4*i+1] = kv.y; kreg[4*i+2] = kv.z; kreg[4*i+3] = kv.w;
    }
  }
  float Lsum = 0.f;
  for (int tile = 0; tile < 4; ++tile) {
    {
      const int r0 = tile * 64 + wave * 16;
      float aq[16];
      #pragma unroll
      for (int r = 0; r < 16; ++r) aq[r] = 0.f;
      for (int e = 0; e < EMB; ++e) {
        const float qw = wq[e * DH + lane];
        #pragma unroll
        for (int r = 0; r < 16; ++r) aq[r] += xb[(r0 + r) * EMB + e] * qw;
      }
      __syncthreads();
      #pragma unroll
      for (int r = 0; r < 16; ++r) Qt[wave*16 + r][lane] = aq[r];
      __syncthreads();
    }
    const int tbase = tile * 64;
    if (tbase + 63 >= s) {
      for (int tr = 0; tr < 64; ++tr) {
        const int t = tbase + tr;
        if (t < s) continue;
        float w = 0.f;
        const float4* q4 = (const float4*)&Qt[tr][0];
        #pragma unroll
        for (int i = 0; i < 16; ++i) {
          float4 qv = q4[i];
          w += qv.x*kreg[4*i+0] + qv.y*kreg[4*i+1] + qv.z*kreg[4*i+2] + qv.w*kreg[4*i+3];
        }
        Lsum += __expf(w * SCALE);
      }
    }
  }
  __syncthreads();
  {
    const float invL = 1.0f / Lsum;
    float4* v4 = (float4*)&Vs[s][0];
    #pragma unroll
    for (int i = 0; i < 16; ++i) {
      float4 vv = v4[i];
      vv.x *= invL; vv.y *= invL; vv.z *= invL; vv.w *= invL;
      v4[i] = vv;
    }
  }
  __syncthreads();
  const float bias1 = bp[tid];
  const float bias2 = (tid < 128) ? bp[256 + tid] : 0.f;
  const int tr = tid >> 2, dq = tid & 3;
  float* ob = out + (size_t)b * TT * EMB;
  for (int tile = 0; tile < 4; ++tile) {
    {
      const int r0 = tile * 64 + wave * 16;
      float aq[16];
      #pragma unroll
      for (int r = 0; r < 16; ++r) aq[r] = 0.f;
      for (int e = 0; e < EMB; ++e) {
        const float qw = wq[e * DH + lane];
        #pragma unroll
        for (int r = 0; r < 16; ++r) aq[r] += xb[(r0 + r) * EMB + e] * qw;
      }
      __syncthreads();
      #pragma unroll
      for (int r = 0; r < 16; ++r) Qt[wave*16 + r][lane] = aq[r];
      __syncthreads();
    }
    const int t = tile * 64 + tr;
    float qreg[16];
    {
      const float4* q4 = (const float4*)&Qt[tr][dq * 16];
      #pragma unroll
      for (int i = 0; i < 4; ++i) {
        float4 qv = q4[i];
        qreg[4*i+0] = qv.x; qreg[4*i+1] = qv.y; qreg[4*i+2] = qv.z; qreg[4*i+3] = qv.w;
      }
    }
    float acc[16];
    #pragma unroll
    for (int i = 0; i < 16; ++i) acc[i] = 0.f;
    for (int s2 = 0; s2 <= t; ++s2) {
      const float4* kk4 = (const float4*)&Ks[s2][dq * 16];
      float part = 0.f;
      #pragma unroll
      for (int i = 0; i < 4; ++i) {
        float4 kv = kk4[i];
        part += qreg[4*i+0]*kv.x + qreg[4*i+1]*kv.y + qreg[4*i+2]*kv.z + qreg[4*i+3]*kv.w;
      }
      part += __shfl_xor(part, 1);
      part += __shfl_xor(part, 2);
      const float p = __expf(part * SCALE);
      const float4* vv4 = (const float4*)&Vs[s2][dq * 16];
      #pragma unroll
      for (int i = 0; i < 4; ++i) {
        float4 vv = vv4[i];
        acc[4*i+0] += p * vv.x; acc[4*i+1] += p * vv.y;
        acc[4*i+2] += p * vv.z; acc[4*i+3] += p * vv.w;
      }
    }
    __syncthreads();
    #pragma unroll
    for (int i = 0; i < 16; ++i) Qt[tr][dq*16 + i] = acc[i];
    __syncthreads();
    const int c1 = tid;
    const int c2 = 256 + tid;
    for (int rg = 0; rg < 4; ++rg) {
      float a1[16], a2[16];
      #pragma unroll
      for (int r = 0; r < 16; ++r) { a1[r] = 0.f; a2[r] = 0.f; }
      for (int d = 0; d < 64; ++d) {
        const float wp1 = Wp[(size_t)(h*64 + d) * EMB + c1];
        const float wp2 = (tid < 128) ? Wp[(size_t)(h*64 + d) * EMB + c2] : 0.f;
        #pragma unroll
        for (int r = 0; r < 16; ++r) {
          const float a = Qt[rg*16 + r][d];
          a1[r] += a * wp1; a2[r] += a * wp2;
        }
      }
      if (h == 0) {
        #pragma unroll
        for (int r = 0; r < 16; ++r) { a1[r] += bias1; a2[r] += bias2; }
      }
      const int trow0 = tile*64 + rg*16;
      #pragma unroll
      for (int r = 0; r < 16; ++r)
        atomicAdd(&ob[(size_t)(trow0 + r) * EMB + c1], a1[r]);
      if (tid < 128) {
        #pragma unroll
        for (int r = 0; r < 16; ++r)
          atomicAdd(&ob[(size_t)(trow0 + r) * EMB + c2], a2[r]);
      }
    }
    __syncthreads();
  }
}

extern "C" void kernel_launch(void* const* d_in, const int* in_sizes, int n_in,
                              void* d_out, int out_size, void* d_ws, size_t ws_size,
                              hipStream_t stream) {
  const float* x  = (const float*)d_in[0];
  const float* Wq = (const float*)d_in[1];
  const float* Wk = (const float*)d_in[2];
  const float* Wv = (const float*)d_in[3];
  const float* Wp = (const float*)d_in[4];
  const float* bp = (const float*)d_in[5];

  const int nb = in_sizes[0] / (TT * EMB);       // batch (128)
  const size_t M = (size_t)nb * TT;              // 32768 rows
  const size_t XB = M * EMB * 2;                 // bf16 activation bytes (25 MB)
  const size_t WT = (size_t)1536 * 384 * 2;

  const size_t off_wt = 0;
  const size_t off_q  = off_wt + WT;
  const size_t off_k  = off_q + XB;
  const size_t off_vt = off_k + XB;
  const size_t off_o  = off_vt + XB;
  const size_t need   = off_o + XB;

  if (ws_size < need) {
    hipMemsetAsync(d_out, 0, (size_t)out_size * sizeof(float), stream);
    mha_fused<<<nb * HEADS, 256, 0, stream>>>(x, Wq, Wk, Wv, Wp, bp, (float*)d_out);
    return;
  }

  char* ws = (char*)d_ws;
  unsigned short* Wt  = (unsigned short*)(ws + off_wt);
  unsigned short* Qw  = (unsigned short*)(ws + off_q);
  unsigned short* Kw  = (unsigned short*)(ws + off_k);
  unsigned short* Vtw = (unsigned short*)(ws + off_vt);
  unsigned short* Ow  = (unsigned short*)(ws + off_o);

  build_wt<<<288, 256, 0, stream>>>(Wq, Wk, Wv, Wp, Wt);

  gemm_l2<0><<<(unsigned)(M / 64), 256, 0, stream>>>(
      (const void*)x, Wt, Qw, Kw, Vtw, nullptr, nullptr);

  attn_col<<<nb * HEADS, 512, 0, stream>>>(Qw, Kw, Vtw, Ow);

  gemm_l2<1><<<(unsigned)(M / 64), 256, 0, stream>>>(
      (const void*)Ow, Wt + (size_t)1152 * 384, nullptr, nullptr, nullptr,
      (float*)d_out, bp);
}

// Round 10
// 122.776 us; speedup vs baseline: 1.1802x; 1.1652x over previous
//
#include <hip/hip_runtime.h>

#define EMB 384
#define HEADS 6
#define DH 64
#define TT 256

constexpr float SCALE = 0.05103103630798288f;  // 384^-0.5

typedef __attribute__((ext_vector_type(8))) short short8;
typedef __attribute__((ext_vector_type(4))) float f32x4;

__device__ __forceinline__ unsigned short f2bf(float f) {
  unsigned int u = __builtin_bit_cast(unsigned int, f);
  u += 0x7FFFu + ((u >> 16) & 1u);   // RNE
  return (unsigned short)(u >> 16);
}
__device__ __forceinline__ float bf2f(unsigned short u) {
  unsigned int v = ((unsigned int)u) << 16;
  return __builtin_bit_cast(float, v);
}
__device__ __forceinline__ void gll16(const void* g, void* l) {
  __builtin_amdgcn_global_load_lds(
      (const __attribute__((address_space(1))) unsigned int*)g,
      (__attribute__((address_space(3))) unsigned int*)l, 16, 0, 0);
}

// ---------------- K0a: convert x fp32 -> bf16 ----------------
__global__ __launch_bounds__(256)
void cvt_x(const float* __restrict__ x, unsigned short* __restrict__ xb, int n8) {
  int i = blockIdx.x * 256 + threadIdx.x;
  if (i < n8) {
    const float4* src = (const float4*)x;
    float4 a = src[i * 2], b = src[i * 2 + 1];
    short8 o;
    o[0] = (short)f2bf(a.x); o[1] = (short)f2bf(a.y);
    o[2] = (short)f2bf(a.z); o[3] = (short)f2bf(a.w);
    o[4] = (short)f2bf(b.x); o[5] = (short)f2bf(b.y);
    o[6] = (short)f2bf(b.z); o[7] = (short)f2bf(b.w);
    ((short8*)xb)[i] = o;
  }
}

// ---- K0b: build Wt[1536][384] bf16. Rows 0..1151: per-HEAD blocks of 192
// (q d0-63 | k d0-63 | v d0-63); rows 1152..1535: proj^T. ----
__global__ __launch_bounds__(256)
void build_wt(const float* __restrict__ Wq, const float* __restrict__ Wk,
              const float* __restrict__ Wv, const float* __restrict__ Wp,
              unsigned short* __restrict__ Wt) {
  int idx = blockIdx.x * 256 + threadIdx.x;  // 1536*48 = 73728
  int n = idx / 48, e0 = (idx % 48) * 8;
  const float* src; int stride;
  if (n < 1152) {
    int h = n / 192, rem = n % 192, qkv = rem >> 6, d = rem & 63;
    const float* W = (qkv == 0) ? Wq : (qkv == 1) ? Wk : Wv;
    src = W + ((size_t)h * EMB + e0) * DH + d; stride = DH;
  } else {
    int c = n - 1152;
    src = Wp + (size_t)e0 * EMB + c; stride = EMB;
  }
  short8 o;
  #pragma unroll
  for (int j = 0; j < 8; ++j) o[j] = (short)f2bf(src[j * stride]);
  ((short8*)Wt)[idx] = o;
}

// ================= fused QKV-GEMM + attention, one block per (b,h) =================
// 512 thr / 8 waves. GEMM: C[256 x 192] = xb[256 x 384] * Wh[192 x 384]^T, 6 BK=64
// steps single-buffered in the E-region; epilogue routes Q->Qtmp(EL), K->KL, V^T->VL
// (swizzled layouts the attn phase consumes). Then per-KEY (axis=2) softmax attn.
__global__ __launch_bounds__(512, 1)
void qkv_attn(const unsigned short* __restrict__ xb16, const unsigned short* __restrict__ Wt,
              unsigned short* __restrict__ O)
{
  __shared__ __align__(16) char EL[73728];   // GEMM: AL(32K)+BL(24K); then Qtmp; then E
  __shared__ __align__(16) char KL[32768];   // K [256][64] bf16, chunk pos = dc^(t&7)
  __shared__ __align__(16) char VL[32768];   // V^T [64][256] bf16, chunk pos = tc^(d&7)
  __shared__ float Lpart[8][256];
  __shared__ float invL[256];

  const int bh = blockIdx.x, tid = (int)threadIdx.x;
  const int w = tid >> 6, lane = tid & 63;
  const int la = lane & 15, kh = lane >> 4;
  const int b = bh / 6, h = bh - b * 6;
  const unsigned short* xb = xb16 + (size_t)b * 256 * 384;
  const unsigned short* Wb = Wt + (size_t)h * 192 * 384;
  char* AL = EL;            // 32 KB
  char* BL = EL + 32768;    // 24 KB

  // ---------------- QKV GEMM ----------------
  const int wr = (w >> 1) * 64, wc = (w & 1) * 96;
  f32x4 acc[4][6];
  #pragma unroll
  for (int i = 0; i < 4; ++i)
    #pragma unroll
    for (int j = 0; j < 6; ++j) acc[i][j] = f32x4{0.f, 0.f, 0.f, 0.f};

  for (int kt = 0; kt < 6; ++kt) {
    if (kt) __syncthreads();           // previous step's reads done
    #pragma unroll
    for (int i = 0; i < 4; ++i) {      // A: x chunk [256][64] bf16, 32KB
      const int Lb = i * 8192 + tid * 16;
      const int row = Lb >> 7;
      const int kcs = ((Lb >> 4) & 7) ^ (row & 7);
      gll16(xb + (size_t)row * 384 + kt * 64 + kcs * 8, AL + Lb);
    }
    #pragma unroll
    for (int i = 0; i < 3; ++i) {      // B: W chunk [192][64] bf16, 24KB
      const int Lb = i * 8192 + tid * 16;
      const int row = Lb >> 7;
      const int kcs = ((Lb >> 4) & 7) ^ (row & 7);
      gll16(Wb + (size_t)row * 384 + kt * 64 + kcs * 8, BL + Lb);
    }
    __syncthreads();                   // stages landed
    #pragma unroll
    for (int kk = 0; kk < 2; ++kk) {
      const int ch = kk * 4 + kh;
      short8 a[4], bfr[6];
      #pragma unroll
      for (int mi = 0; mi < 4; ++mi) {
        const int r = wr + mi * 16 + la;
        a[mi] = *(const short8*)(AL + r * 128 + ((ch ^ (r & 7)) << 4));
      }
      #pragma unroll
      for (int ni = 0; ni < 6; ++ni) {
        const int rB = wc + ni * 16 + la;
        bfr[ni] = *(const short8*)(BL + rB * 128 + ((ch ^ (rB & 7)) << 4));
      }
      __builtin_amdgcn_s_setprio(1);
      #pragma unroll
      for (int mi = 0; mi < 4; ++mi)
        #pragma unroll
        for (int ni = 0; ni < 6; ++ni)
          acc[mi][ni] = __builtin_amdgcn_mfma_f32_16x16x32_bf16(a[mi], bfr[ni], acc[mi][ni], 0, 0, 0);
      __builtin_amdgcn_s_setprio(0);
    }
  }
  __syncthreads();   // all reads of AL/BL done before Qtmp overwrites EL

  // ---- epilogue: Q -> Qtmp (EL, [256][64] swizzled), K -> KL, V^T -> VL ----
  #pragma unroll
  for (int mi = 0; mi < 4; ++mi) {
    #pragma unroll
    for (int ni = 0; ni < 6; ++ni) {
      const int col = wc + ni * 16 + la;
      #pragma unroll
      for (int j = 0; j < 4; ++j) {
        const int t = wr + mi * 16 + kh * 4 + j;
        const unsigned short v = f2bf(acc[mi][ni][j]);
        if (col < 64) {
          const int d = col;
          *(unsigned short*)(EL + t * 128 + ((((d >> 3)) ^ (t & 7)) << 4) + (d & 7) * 2) = v;
        } else if (col < 128) {
          const int d = col - 64;
          *(unsigned short*)(KL + t * 128 + ((((d >> 3)) ^ (t & 7)) << 4) + (d & 7) * 2) = v;
        } else {
          const int d = col - 128;
          *(unsigned short*)(VL + d * 512 + ((((t >> 3)) ^ (d & 7)) << 4) + (t & 7) * 2) = v;
        }
      }
    }
  }
  __syncthreads();

  // ---- hoist Q fragments from Qtmp ----
  const int rts[2] = { w, 15 - w };
  short8 qa[2][2];
  #pragma unroll
  for (int ti = 0; ti < 2; ++ti)
    #pragma unroll
    for (int kk = 0; kk < 2; ++kk) {
      const int r = rts[ti] * 16 + la;
      const int ch = kk * 4 + kh;
      qa[ti][kk] = *(const short8*)(EL + r * 128 + ((ch ^ (r & 7)) << 4));
    }
  __syncthreads();   // EL now free for E strips

  int wps[2], eoffs[2];
  #pragma unroll
  for (int ti = 0; ti < 2; ++ti) {
    const int rt = rts[ti];
    wps[ti] = 32 * ((rt + 2) >> 1);
    const int S = (rt & 1) ? ((rt + 1) * (rt + 1) / 4) : (rt * (rt + 2) / 4);
    eoffs[ti] = 1024 * S;
  }

  // ---- QK^T + masked exp -> E strips ----
  #pragma unroll
  for (int ti = 0; ti < 2; ++ti) {
    const int rt = rts[ti], wp = wps[ti], stride = wp * 2;
    char* Ebase = EL + eoffs[ti];
    const int nns = wp >> 4;
    for (int ns = 0; ns < nns; ++ns) {
      f32x4 s4 = f32x4{0.f, 0.f, 0.f, 0.f};
      #pragma unroll
      for (int kk = 0; kk < 2; ++kk) {
        const int rB = ns * 16 + la, kc = kk * 4 + kh;
        short8 bf = *(const short8*)(KL + rB * 128 + ((kc ^ (rB & 7)) << 4));
        s4 = __builtin_amdgcn_mfma_f32_16x16x32_bf16(qa[ti][kk], bf, s4, 0, 0, 0);
      }
      const int c = ns * 16 + la, cc = c >> 3, co = (c & 7) * 2;
      #pragma unroll
      for (int j = 0; j < 4; ++j) {
        const int r = kh * 4 + j;
        const int t = rt * 16 + r;
        const float e = (t >= c) ? __expf(s4[j] * SCALE) : 0.f;
        *(unsigned short*)(Ebase + r * stride + ((cc ^ (r & 3)) << 4) + co) = f2bf(e);
      }
    }
  }
  __syncthreads();

  // ---- column partial sums ----
  {
    float acc4[4] = {0.f, 0.f, 0.f, 0.f};
    #pragma unroll
    for (int ti = 0; ti < 2; ++ti) {
      const int wp = wps[ti], stride = wp * 2;
      const char* Ebase = EL + eoffs[ti];
      #pragma unroll
      for (int cb = 0; cb < 4; ++cb) {
        const int c = cb * 64 + lane;
        if (c < wp) {
          const int cc = c >> 3, co = (c & 7) * 2;
          float p = 0.f;
          #pragma unroll
          for (int r = 0; r < 16; ++r)
            p += bf2f(*(const unsigned short*)(Ebase + r * stride + ((cc ^ (r & 3)) << 4) + co));
          acc4[cb] += p;
        }
      }
    }
    #pragma unroll
    for (int cb = 0; cb < 4; ++cb) Lpart[w][cb * 64 + lane] = acc4[cb];
  }
  __syncthreads();
  if (tid < 256) {
    float Ls = 0.f;
    #pragma unroll
    for (int ww = 0; ww < 8; ++ww) Ls += Lpart[ww][tid];
    invL[tid] = 1.f / Ls;
  }
  __syncthreads();

  // ---- fold 1/L_s into V ----
  {
    const int d = tid >> 3, qq = tid & 7;
    #pragma unroll
    for (int i = 0; i < 4; ++i) {
      const int kcp = qq * 4 + i;
      char* p = VL + d * 512 + kcp * 16;
      short8 v = *(short8*)p;
      const int sb = (kcp ^ (d & 7)) * 8;
      short8 o;
      #pragma unroll
      for (int e = 0; e < 8; ++e)
        o[e] = (short)f2bf(bf2f((unsigned short)v[e]) * invL[sb + e]);
      *(short8*)p = o;
    }
  }
  __syncthreads();

  // ---- O = E * V' ----
  unsigned short* Og = O + (size_t)b * 256 * 384 + h * 64;
  #pragma unroll
  for (int ti = 0; ti < 2; ++ti) {
    const int rt = rts[ti], wp = wps[ti], stride = wp * 2;
    const char* Ebase = EL + eoffs[ti];
    f32x4 oacc[4];
    #pragma unroll
    for (int nd = 0; nd < 4; ++nd) oacc[nd] = f32x4{0.f, 0.f, 0.f, 0.f};
    const int nks = wp >> 5;
    for (int ks = 0; ks < nks; ++ks) {
      const int cc = ks * 4 + kh;
      short8 ea = *(const short8*)(Ebase + la * stride + ((cc ^ (la & 3)) << 4));
      __builtin_amdgcn_s_setprio(1);
      #pragma unroll
      for (int nd = 0; nd < 4; ++nd) {
        const int d = nd * 16 + la;
        short8 vb = *(const short8*)(VL + d * 512 + ((cc ^ (d & 7)) << 4));
        oacc[nd] = __builtin_amdgcn_mfma_f32_16x16x32_bf16(ea, vb, oacc[nd], 0, 0, 0);
      }
      __builtin_amdgcn_s_setprio(0);
    }
    #pragma unroll
    for (int nd = 0; nd < 4; ++nd) {
      const int d = nd * 16 + la;
      #pragma unroll
      for (int j = 0; j < 4; ++j) {
        const int t = rt * 16 + kh * 4 + j;
        Og[(size_t)t * 384 + d] = f2bf(oacc[nd][j]);
      }
    }
  }
}

// ---------------- proj GEMM (R4 structure): out = O * proj + bias ----------------
__global__ __launch_bounds__(512, 1)
void proj_gemm(const unsigned short* __restrict__ A, const unsigned short* __restrict__ Bt,
               float* __restrict__ Co, const float* __restrict__ bias)
{
  __shared__ __align__(16) unsigned short AL[128 * 384];    // 96 KB
  __shared__ __align__(16) unsigned short BL[2][128 * 64];  // 2 x 16 KB
  const int tid = (int)threadIdx.x, w = tid >> 6, lane = tid & 63;
  const int la = lane & 15, kh = lane >> 4;
  const int m0 = blockIdx.x * 128;

  {
    const int row = tid >> 2, qq = tid & 3;
    const short8* O8 = (const short8*)(A + (size_t)(m0 + row) * 384);
    #pragma unroll
    for (int i = 0; i < 12; ++i) {
      const int ch = qq + 4 * i;
      *(short8*)((char*)AL + row * 768 + ((ch ^ (row & 7)) << 4)) = O8[ch];
    }
  }

  auto stageB = [&](int buf, int n0, int k0) {
    #pragma unroll
    for (int i = 0; i < 2; ++i) {
      const int Lb = i * 8192 + tid * 16;
      const int row = Lb >> 7;
      const int kcs = ((Lb >> 4) & 7) ^ (row & 7);
      gll16(Bt + (size_t)(n0 + row) * 384 + k0 + kcs * 8, (char*)BL[buf] + Lb);
    }
  };

  stageB(0, 0, 0);
  __syncthreads();

  const int wr = (w >> 2) * 64, wc = (w & 3) * 32;
  int buf = 0;
  for (int nt = 0; nt < 3; ++nt) {
    f32x4 acc[4][2];
    #pragma unroll
    for (int i = 0; i < 4; ++i) { acc[i][0] = f32x4{0.f,0.f,0.f,0.f}; acc[i][1] = f32x4{0.f,0.f,0.f,0.f}; }

    for (int kt = 0; kt < 6; ++kt) {
      if (kt < 5)          stageB(buf ^ 1, nt * 128, (kt + 1) * 64);
      else if (nt + 1 < 3) stageB(buf ^ 1, (nt + 1) * 128, 0);
      #pragma unroll
      for (int kk = 0; kk < 2; ++kk) {
        short8 a[4], b[2];
        const int chA = kt * 8 + kk * 4 + kh;
        #pragma unroll
        for (int mi = 0; mi < 4; ++mi) {
          const int r = wr + mi * 16 + la;
          a[mi] = *(const short8*)((const char*)AL + r * 768 + ((chA ^ (r & 7)) << 4));
        }
        const int chB = kk * 4 + kh;
        #pragma unroll
        for (int ni = 0; ni < 2; ++ni) {
          const int rB = wc + ni * 16 + la;
          b[ni] = *(const short8*)((const char*)BL[buf] + rB * 128 + ((chB ^ (rB & 7)) << 4));
        }
        __builtin_amdgcn_s_setprio(1);
        #pragma unroll
        for (int mi = 0; mi < 4; ++mi)
          #pragma unroll
          for (int ni = 0; ni < 2; ++ni)
            acc[mi][ni] = __builtin_amdgcn_mfma_f32_16x16x32_bf16(a[mi], b[ni], acc[mi][ni], 0, 0, 0);
        __builtin_amdgcn_s_setprio(0);
      }
      __syncthreads();
      buf ^= 1;
    }

    #pragma unroll
    for (int mi = 0; mi < 4; ++mi) {
      const int mbase = m0 + wr + mi * 16 + kh * 4;
      #pragma unroll
      for (int ni = 0; ni < 2; ++ni) {
        const int nl = nt * 128 + wc + ni * 16 + la;
        const float bn = bias[nl];
        #pragma unroll
        for (int j = 0; j < 4; ++j)
          Co[(size_t)(mbase + j) * 384 + nl] = acc[mi][ni][j] + bn;
      }
    }
  }
}

// ================= fallback (fp32) for small ws =================
__global__ __launch_bounds__(256, 1)
void mha_fused(const float* __restrict__ x, const float* __restrict__ Wq,
               const float* __restrict__ Wk, const float* __restrict__ Wv,
               const float* __restrict__ Wp, const float* __restrict__ bp,
               float* __restrict__ out)
{
  const int bh = blockIdx.x;
  const int b = bh / HEADS, h = bh % HEADS;
  const int tid = (int)threadIdx.x;
  const int wave = tid >> 6, lane = tid & 63;
  const float* xb = x + (size_t)b * TT * EMB;
  const float* wq = Wq + (size_t)h * EMB * DH;
  const float* wk = Wk + (size_t)h * EMB * DH;
  const float* wv = Wv + (size_t)h * EMB * DH;
  __shared__ float Ks[TT][68];
  __shared__ float Vs[TT][64];
  __shared__ float Qt[64][68];
  for (int c = 0; c < 4; ++c) {
    const int s0 = wave * 64 + c * 16;
    float ak[16], av[16];
    #pragma unroll
    for (int r = 0; r < 16; ++r) { ak[r] = 0.f; av[r] = 0.f; }
    for (int e = 0; e < EMB; ++e) {
      const float kk = wk[e * DH + lane];
      const float vv = wv[e * DH + lane];
      #pragma unroll
      for (int r = 0; r < 16; ++r) {
        const float xv = xb[(s0 + r) * EMB + e];
        ak[r] += xv * kk; av[r] += xv * vv;
      }
    }
    #pragma unroll
    for (int r = 0; r < 16; ++r) { Ks[s0 + r][lane] = ak[r]; Vs[s0 + r][lane] = av[r]; }
  }
  __syncthreads();
  const int s = tid;
  float kreg[64];
  {
    const float4* k4 = (const float4*)&Ks[s][0];
    #pragma unroll
    for (int i = 0; i < 16; ++i) {
      float4 kv = k4[i];
      kreg[4*i+0] = kv.x; kreg[4*i+1] = kv.y; kreg[4*i+2] = kv.z; kreg[4*i+3] = kv.w;
    }
  }
  float Lsum = 0.f;
  for (int tile = 0; tile < 4; ++tile) {
    {
      const int r0 = tile * 64 + wave * 16;
      float aq[16];
      #pragma unroll
      for (int r = 0; r < 16; ++r) aq[r] = 0.f;
      for (int e = 0; e < EMB; ++e) {
        const float qw = wq[e * DH + lane];
        #pragma unroll
        for (int r = 0; r < 16; ++r) aq[r] += xb[(r0 + r) * EMB + e] * qw;
      }
      __syncthreads();
      #pragma unroll
      for (int r = 0; r < 16; ++r) Qt[wave*16 + r][lane] = aq[r];
      __syncthreads();
    }
    const int tbase = tile * 64;
    if (tbase + 63 >= s) {
      for (int tr = 0; tr < 64; ++tr) {
        const int t = tbase + tr;
        if (t < s) continue;
        float w = 0.f;
        const float4* q4 = (const float4*)&Qt[tr][0];
        #pragma unroll
        for (int i = 0; i < 16; ++i) {
          float4 qv = q4[i];
          w += qv.x*kreg[4*i+0] + qv.y*kreg[4*i+1] + qv.z*kreg[4*i+2] + qv.w*kreg[4*i+3];
        }
        Lsum += __expf(w * SCALE);
      }
    }
  }
  __syncthreads();
  {
    const float invL = 1.0f / Lsum;
    float4* v4 = (float4*)&Vs[s][0];
    #pragma unroll
    for (int i = 0; i < 16; ++i) {
      float4 vv = v4[i];
      vv.x *= invL; vv.y *= invL; vv.z *= invL; vv.w *= invL;
      v4[i] = vv;
    }
  }
  __syncthreads();
  const float bias1 = bp[tid];
  const float bias2 = (tid < 128) ? bp[256 + tid] : 0.f;
  const int tr = tid >> 2, dq = tid & 3;
  float* ob = out + (size_t)b * TT * EMB;
  for (int tile = 0; tile < 4; ++tile) {
    {
      const int r0 = tile * 64 + wave * 16;
      float aq[16];
      #pragma unroll
      for (int r = 0; r < 16; ++r) aq[r] = 0.f;
      for (int e = 0; e < EMB; ++e) {
        const float qw = wq[e * DH + lane];
        #pragma unroll
        for (int r = 0; r < 16; ++r) aq[r] += xb[(r0 + r) * EMB + e] * qw;
      }
      __syncthreads();
      #pragma unroll
      for (int r = 0; r < 16; ++r) Qt[wave*16 + r][lane] = aq[r];
      __syncthreads();
    }
    const int t = tile * 64 + tr;
    float qreg[16];
    {
      const float4* q4 = (const float4*)&Qt[tr][dq * 16];
      #pragma unroll
      for (int i = 0; i < 4; ++i) {
        float4 qv = q4[i];
        qreg[4*i+0] = qv.x; qreg[4*i+1] = qv.y; qreg[4*i+2] = qv.z; qreg[4*i+3] = qv.w;
      }
    }
    float acc[16];
    #pragma unroll
    for (int i = 0; i < 16; ++i) acc[i] = 0.f;
    for (int s2 = 0; s2 <= t; ++s2) {
      const float4* kk4 = (const float4*)&Ks[s2][dq * 16];
      float part = 0.f;
      #pragma unroll
      for (int i = 0; i < 4; ++i) {
        float4 kv = kk4[i];
        part += qreg[4*i+0]*kv.x + qreg[4*i+1]*kv.y + qreg[4*i+2]*kv.z + qreg[4*i+3]*kv.w;
      }
      part += __shfl_xor(part, 1);
      part += __shfl_xor(part, 2);
      const float p = __expf(part * SCALE);
      const float4* vv4 = (const float4*)&Vs[s2][dq * 16];
      #pragma unroll
      for (int i = 0; i < 4; ++i) {
        float4 vv = vv4[i];
        acc[4*i+0] += p * vv.x; acc[4*i+1] += p * vv.y;
        acc[4*i+2] += p * vv.z; acc[4*i+3] += p * vv.w;
      }
    }
    __syncthreads();
    #pragma unroll
    for (int i = 0; i < 16; ++i) Qt[tr][dq*16 + i] = acc[i];
    __syncthreads();
    const int c1 = tid;
    const int c2 = 256 + tid;
    for (int rg = 0; rg < 4; ++rg) {
      float a1[16], a2[16];
      #pragma unroll
      for (int r = 0; r < 16; ++r) { a1[r] = 0.f; a2[r] = 0.f; }
      for (int d = 0; d < 64; ++d) {
        const float wp1 = Wp[(size_t)(h*64 + d) * EMB + c1];
        const float wp2 = (tid < 128) ? Wp[(size_t)(h*64 + d) * EMB + c2] : 0.f;
        #pragma unroll
        for (int r = 0; r < 16; ++r) {
          const float a = Qt[rg*16 + r][d];
          a1[r] += a * wp1; a2[r] += a * wp2;
        }
      }
      if (h == 0) {
        #pragma unroll
        for (int r = 0; r < 16; ++r) { a1[r] += bias1; a2[r] += bias2; }
      }
      const int trow0 = tile*64 + rg*16;
      #pragma unroll
      for (int r = 0; r < 16; ++r)
        atomicAdd(&ob[(size_t)(trow0 + r) * EMB + c1], a1[r]);
      if (tid < 128) {
        #pragma unroll
        for (int r = 0; r < 16; ++r)
          atomicAdd(&ob[(size_t)(trow0 + r) * EMB + c2], a2[r]);
      }
    }
    __syncthreads();
  }
}

extern "C" void kernel_launch(void* const* d_in, const int* in_sizes, int n_in,
                              void* d_out, int out_size, void* d_ws, size_t ws_size,
                              hipStream_t stream) {
  const float* x  = (const float*)d_in[0];
  const float* Wq = (const float*)d_in[1];
  const float* Wk = (const float*)d_in[2];
  const float* Wv = (const float*)d_in[3];
  const float* Wp = (const float*)d_in[4];
  const float* bp = (const float*)d_in[5];

  const int nb = in_sizes[0] / (TT * EMB);       // batch (128)
  const size_t M = (size_t)nb * TT;              // 32768 rows
  const size_t XB = M * EMB * 2;                 // bf16 activation bytes (25 MB)
  const size_t WT = (size_t)1536 * 384 * 2;

  const size_t off_x  = 0;
  const size_t off_wt = XB;
  const size_t off_o  = off_wt + WT;
  const size_t need   = off_o + XB;

  if (ws_size < need) {
    hipMemsetAsync(d_out, 0, (size_t)out_size * sizeof(float), stream);
    mha_fused<<<nb * HEADS, 256, 0, stream>>>(x, Wq, Wk, Wv, Wp, bp, (float*)d_out);
    return;
  }

  char* ws = (char*)d_ws;
  unsigned short* xb16 = (unsigned short*)(ws + off_x);
  unsigned short* Wt   = (unsigned short*)(ws + off_wt);
  unsigned short* Ow   = (unsigned short*)(ws + off_o);

  const int n8 = (int)(M * EMB / 8);
  cvt_x<<<(n8 + 255) / 256, 256, 0, stream>>>(x, xb16, n8);
  build_wt<<<288, 256, 0, stream>>>(Wq, Wk, Wv, Wp, Wt);

  qkv_attn<<<nb * HEADS, 512, 0, stream>>>(xb16, Wt, Ow);

  proj_gemm<<<(unsigned)(M / 128), 512, 0, stream>>>(
      Ow, Wt + (size_t)1152 * 384, (float*)d_out, bp);
}

// Round 11
// 118.727 us; speedup vs baseline: 1.2205x; 1.0341x over previous
//
#include <hip/hip_runtime.h>

#define EMB 384
#define HEADS 6
#define DH 64
#define TT 256

constexpr float SCALE = 0.05103103630798288f;  // 384^-0.5

typedef __attribute__((ext_vector_type(8))) short short8;
typedef __attribute__((ext_vector_type(4))) float f32x4;
typedef __attribute__((ext_vector_type(4))) unsigned short u16x4;

__device__ __forceinline__ unsigned short f2bf(float f) {
  unsigned int u = __builtin_bit_cast(unsigned int, f);
  u += 0x7FFFu + ((u >> 16) & 1u);   // RNE
  return (unsigned short)(u >> 16);
}
__device__ __forceinline__ float bf2f(unsigned short u) {
  unsigned int v = ((unsigned int)u) << 16;
  return __builtin_bit_cast(float, v);
}
__device__ __forceinline__ void gll16(const void* g, void* l) {
  __builtin_amdgcn_global_load_lds(
      (const __attribute__((address_space(1))) unsigned int*)g,
      (__attribute__((address_space(3))) unsigned int*)l, 16, 0, 0);
}

// ---------------- K0a: convert x fp32 -> bf16 ----------------
__global__ __launch_bounds__(256)
void cvt_x(const float* __restrict__ x, unsigned short* __restrict__ xb, int n8) {
  int i = blockIdx.x * 256 + threadIdx.x;
  if (i < n8) {
    const float4* src = (const float4*)x;
    float4 a = src[i * 2], b = src[i * 2 + 1];
    short8 o;
    o[0] = (short)f2bf(a.x); o[1] = (short)f2bf(a.y);
    o[2] = (short)f2bf(a.z); o[3] = (short)f2bf(a.w);
    o[4] = (short)f2bf(b.x); o[5] = (short)f2bf(b.y);
    o[6] = (short)f2bf(b.z); o[7] = (short)f2bf(b.w);
    ((short8*)xb)[i] = o;
  }
}

// ---- K0b: build Wt[1536][384] bf16. Rows 0..1151: per-HEAD blocks of 192
// (q d0-63 | k d0-63 | v d0-63); rows 1152..1535: proj^T. ----
__global__ __launch_bounds__(256)
void build_wt(const float* __restrict__ Wq, const float* __restrict__ Wk,
              const float* __restrict__ Wv, const float* __restrict__ Wp,
              unsigned short* __restrict__ Wt) {
  int idx = blockIdx.x * 256 + threadIdx.x;  // 1536*48 = 73728
  int n = idx / 48, e0 = (idx % 48) * 8;
  const float* src; int stride;
  if (n < 1152) {
    int h = n / 192, rem = n % 192, qkv = rem >> 6, d = rem & 63;
    const float* W = (qkv == 0) ? Wq : (qkv == 1) ? Wk : Wv;
    src = W + ((size_t)h * EMB + e0) * DH + d; stride = DH;
  } else {
    int c = n - 1152;
    src = Wp + (size_t)e0 * EMB + c; stride = EMB;
  }
  short8 o;
  #pragma unroll
  for (int j = 0; j < 8; ++j) o[j] = (short)f2bf(src[j * stride]);
  ((short8*)Wt)[idx] = o;
}

// ================= fused QKV-GEMM + attention, one block per (b,h) =================
// 512 thr / 8 waves. GEMM: C[256 x 192] = xb[256 x 384] * Wh[192 x 384]^T, 6 BK=64
// steps single-buffered in the E-region; epilogue routes Q->Qtmp(EL), K->KL, V^T->VL.
// Column sums fused into QK^T via shfl_xor (no E read-back pass).
__global__ __launch_bounds__(512, 1)
void qkv_attn(const unsigned short* __restrict__ xb16, const unsigned short* __restrict__ Wt,
              unsigned short* __restrict__ O)
{
  __shared__ __align__(16) char EL[73728];   // GEMM: AL(32K)+BL(24K); then Qtmp; then E
  __shared__ __align__(16) char KL[32768];   // K [256][64] bf16, chunk pos = dc^(t&7)
  __shared__ __align__(16) char VL[32768];   // V^T [64][256] bf16, chunk pos = tc^(d&7)
  __shared__ float Lpart[8][256];
  __shared__ float invL[256];

  const int bh = blockIdx.x, tid = (int)threadIdx.x;
  const int w = tid >> 6, lane = tid & 63;
  const int la = lane & 15, kh = lane >> 4;
  const int b = bh / 6, h = bh - b * 6;
  const unsigned short* xb = xb16 + (size_t)b * 256 * 384;
  const unsigned short* Wb = Wt + (size_t)h * 192 * 384;
  char* AL = EL;            // 32 KB
  char* BL = EL + 32768;    // 24 KB

  // ---------------- QKV GEMM ----------------
  const int wr = (w >> 1) * 64, wc = (w & 1) * 96;
  f32x4 acc[4][6];
  #pragma unroll
  for (int i = 0; i < 4; ++i)
    #pragma unroll
    for (int j = 0; j < 6; ++j) acc[i][j] = f32x4{0.f, 0.f, 0.f, 0.f};

  for (int kt = 0; kt < 6; ++kt) {
    if (kt) __syncthreads();           // previous step's reads done
    #pragma unroll
    for (int i = 0; i < 4; ++i) {      // A: x chunk [256][64] bf16, 32KB
      const int Lb = i * 8192 + tid * 16;
      const int row = Lb >> 7;
      const int kcs = ((Lb >> 4) & 7) ^ (row & 7);
      gll16(xb + (size_t)row * 384 + kt * 64 + kcs * 8, AL + Lb);
    }
    #pragma unroll
    for (int i = 0; i < 3; ++i) {      // B: W chunk [192][64] bf16, 24KB
      const int Lb = i * 8192 + tid * 16;
      const int row = Lb >> 7;
      const int kcs = ((Lb >> 4) & 7) ^ (row & 7);
      gll16(Wb + (size_t)row * 384 + kt * 64 + kcs * 8, BL + Lb);
    }
    __syncthreads();                   // stages landed
    #pragma unroll
    for (int kk = 0; kk < 2; ++kk) {
      const int ch = kk * 4 + kh;
      short8 a[4], bfr[6];
      #pragma unroll
      for (int mi = 0; mi < 4; ++mi) {
        const int r = wr + mi * 16 + la;
        a[mi] = *(const short8*)(AL + r * 128 + ((ch ^ (r & 7)) << 4));
      }
      #pragma unroll
      for (int ni = 0; ni < 6; ++ni) {
        const int rB = wc + ni * 16 + la;
        bfr[ni] = *(const short8*)(BL + rB * 128 + ((ch ^ (rB & 7)) << 4));
      }
      __builtin_amdgcn_s_setprio(1);
      #pragma unroll
      for (int mi = 0; mi < 4; ++mi)
        #pragma unroll
        for (int ni = 0; ni < 6; ++ni)
          acc[mi][ni] = __builtin_amdgcn_mfma_f32_16x16x32_bf16(a[mi], bfr[ni], acc[mi][ni], 0, 0, 0);
      __builtin_amdgcn_s_setprio(0);
    }
  }
  __syncthreads();   // all reads of AL/BL done before Qtmp overwrites EL

  // ---- epilogue: Q -> Qtmp (EL, [256][64] swizzled), K -> KL, V^T -> VL ----
  #pragma unroll
  for (int mi = 0; mi < 4; ++mi) {
    #pragma unroll
    for (int ni = 0; ni < 6; ++ni) {
      const int col = wc + ni * 16 + la;
      const int tb = wr + mi * 16 + kh * 4;
      if (col < 64) {
        const int d = col;
        #pragma unroll
        for (int j = 0; j < 4; ++j) {
          const int t = tb + j;
          *(unsigned short*)(EL + t * 128 + (((d >> 3) ^ (t & 7)) << 4) + (d & 7) * 2)
              = f2bf(acc[mi][ni][j]);
        }
      } else if (col < 128) {
        const int d = col - 64;
        #pragma unroll
        for (int j = 0; j < 4; ++j) {
          const int t = tb + j;
          *(unsigned short*)(KL + t * 128 + (((d >> 3) ^ (t & 7)) << 4) + (d & 7) * 2)
              = f2bf(acc[mi][ni][j]);
        }
      } else {
        const int d = col - 128;
        u16x4 pk;
        #pragma unroll
        for (int j = 0; j < 4; ++j) pk[j] = f2bf(acc[mi][ni][j]);
        *(u16x4*)(VL + d * 512 + (((tb >> 3) ^ (d & 7)) << 4) + (tb & 7) * 2) = pk;
      }
    }
  }
  __syncthreads();

  // ---- hoist Q fragments from Qtmp ----
  const int rts[2] = { w, 15 - w };
  short8 qa[2][2];
  #pragma unroll
  for (int ti = 0; ti < 2; ++ti)
    #pragma unroll
    for (int kk = 0; kk < 2; ++kk) {
      const int r = rts[ti] * 16 + la;
      const int ch = kk * 4 + kh;
      qa[ti][kk] = *(const short8*)(EL + r * 128 + ((ch ^ (r & 7)) << 4));
    }
  __syncthreads();   // EL now free for E strips

  int wps[2], eoffs[2];
  #pragma unroll
  for (int ti = 0; ti < 2; ++ti) {
    const int rt = rts[ti];
    wps[ti] = 32 * ((rt + 2) >> 1);
    const int S = (rt & 1) ? ((rt + 1) * (rt + 1) / 4) : (rt * (rt + 2) / 4);
    eoffs[ti] = 1024 * S;
  }

  // ---- zero own Lpart row (wave-local, no barrier needed) ----
  #pragma unroll
  for (int i = 0; i < 4; ++i) Lpart[w][i * 64 + lane] = 0.f;

  // ---- QK^T + masked exp -> E strips; column sums fused via shuffles ----
  #pragma unroll
  for (int ti = 0; ti < 2; ++ti) {
    const int rt = rts[ti], wp = wps[ti], stride = wp * 2;
    char* Ebase = EL + eoffs[ti];
    const int nns = wp >> 4;
    for (int ns = 0; ns < nns; ++ns) {
      f32x4 s4 = f32x4{0.f, 0.f, 0.f, 0.f};
      #pragma unroll
      for (int kk = 0; kk < 2; ++kk) {
        const int rB = ns * 16 + la, kc = kk * 4 + kh;
        short8 bf = *(const short8*)(KL + rB * 128 + ((kc ^ (rB & 7)) << 4));
        s4 = __builtin_amdgcn_mfma_f32_16x16x32_bf16(qa[ti][kk], bf, s4, 0, 0, 0);
      }
      const int c = ns * 16 + la, cc = c >> 3, co = (c & 7) * 2;
      float ps = 0.f;
      #pragma unroll
      for (int j = 0; j < 4; ++j) {
        const int r = kh * 4 + j;
        const int t = rt * 16 + r;
        const float e = (t >= c) ? __expf(s4[j] * SCALE) : 0.f;
        ps += e;
        *(unsigned short*)(Ebase + r * stride + ((cc ^ (r & 3)) << 4) + co) = f2bf(e);
      }
      ps += __shfl_xor(ps, 16);
      ps += __shfl_xor(ps, 32);        // all 4 kh-lanes hold the 16-row col sum
      if (kh == 0) Lpart[w][c] += ps;  // wave-local row: no race
    }
  }
  __syncthreads();

  if (tid < 256) {
    float Ls = 0.f;
    #pragma unroll
    for (int ww = 0; ww < 8; ++ww) Ls += Lpart[ww][tid];
    invL[tid] = 1.f / Ls;
  }
  __syncthreads();

  // ---- fold 1/L_s into V ----
  {
    const int d = tid >> 3, qq = tid & 7;
    #pragma unroll
    for (int i = 0; i < 4; ++i) {
      const int kcp = qq * 4 + i;
      char* p = VL + d * 512 + kcp * 16;
      short8 v = *(short8*)p;
      const int sb = (kcp ^ (d & 7)) * 8;
      short8 o;
      #pragma unroll
      for (int e = 0; e < 8; ++e)
        o[e] = (short)f2bf(bf2f((unsigned short)v[e]) * invL[sb + e]);
      *(short8*)p = o;
    }
  }
  __syncthreads();

  // ---- O = E * V' ----
  unsigned short* Og = O + (size_t)b * 256 * 384 + h * 64;
  #pragma unroll
  for (int ti = 0; ti < 2; ++ti) {
    const int rt = rts[ti], wp = wps[ti], stride = wp * 2;
    const char* Ebase = EL + eoffs[ti];
    f32x4 oacc[4];
    #pragma unroll
    for (int nd = 0; nd < 4; ++nd) oacc[nd] = f32x4{0.f, 0.f, 0.f, 0.f};
    const int nks = wp >> 5;
    for (int ks = 0; ks < nks; ++ks) {
      const int cc = ks * 4 + kh;
      short8 ea = *(const short8*)(Ebase + la * stride + ((cc ^ (la & 3)) << 4));
      __builtin_amdgcn_s_setprio(1);
      #pragma unroll
      for (int nd = 0; nd < 4; ++nd) {
        const int d = nd * 16 + la;
        short8 vb = *(const short8*)(VL + d * 512 + ((cc ^ (d & 7)) << 4));
        oacc[nd] = __builtin_amdgcn_mfma_f32_16x16x32_bf16(ea, vb, oacc[nd], 0, 0, 0);
      }
      __builtin_amdgcn_s_setprio(0);
    }
    #pragma unroll
    for (int nd = 0; nd < 4; ++nd) {
      const int d = nd * 16 + la;
      #pragma unroll
      for (int j = 0; j < 4; ++j) {
        const int t = rt * 16 + kh * 4 + j;
        Og[(size_t)t * 384 + d] = f2bf(oacc[nd][j]);
      }
    }
  }
}

// ---------------- proj GEMM: out = O * proj + bias ----------------
__global__ __launch_bounds__(512, 1)
void proj_gemm(const unsigned short* __restrict__ A, const unsigned short* __restrict__ Bt,
               float* __restrict__ Co, const float* __restrict__ bias)
{
  __shared__ __align__(16) unsigned short AL[128 * 384];    // 96 KB
  __shared__ __align__(16) unsigned short BL[2][128 * 64];  // 2 x 16 KB
  const int tid = (int)threadIdx.x, w = tid >> 6, lane = tid & 63;
  const int la = lane & 15, kh = lane >> 4;
  const int m0 = blockIdx.x * 128;

  {
    const int row = tid >> 2, qq = tid & 3;
    const short8* O8 = (const short8*)(A + (size_t)(m0 + row) * 384);
    #pragma unroll
    for (int i = 0; i < 12; ++i) {
      const int ch = qq + 4 * i;
      *(short8*)((char*)AL + row * 768 + ((ch ^ (row & 7)) << 4)) = O8[ch];
    }
  }

  auto stageB = [&](int buf, int n0, int k0) {
    #pragma unroll
    for (int i = 0; i < 2; ++i) {
      const int Lb = i * 8192 + tid * 16;
      const int row = Lb >> 7;
      const int kcs = ((Lb >> 4) & 7) ^ (row & 7);
      gll16(Bt + (size_t)(n0 + row) * 384 + k0 + kcs * 8, (char*)BL[buf] + Lb);
    }
  };

  stageB(0, 0, 0);
  __syncthreads();

  const int wr = (w >> 2) * 64, wc = (w & 3) * 32;
  int buf = 0;
  for (int nt = 0; nt < 3; ++nt) {
    f32x4 acc[4][2];
    #pragma unroll
    for (int i = 0; i < 4; ++i) { acc[i][0] = f32x4{0.f,0.f,0.f,0.f}; acc[i][1] = f32x4{0.f,0.f,0.f,0.f}; }

    for (int kt = 0; kt < 6; ++kt) {
      if (kt < 5)          stageB(buf ^ 1, nt * 128, (kt + 1) * 64);
      else if (nt + 1 < 3) stageB(buf ^ 1, (nt + 1) * 128, 0);
      #pragma unroll
      for (int kk = 0; kk < 2; ++kk) {
        short8 a[4], b[2];
        const int chA = kt * 8 + kk * 4 + kh;
        #pragma unroll
        for (int mi = 0; mi < 4; ++mi) {
          const int r = wr + mi * 16 + la;
          a[mi] = *(const short8*)((const char*)AL + r * 768 + ((chA ^ (r & 7)) << 4));
        }
        const int chB = kk * 4 + kh;
        #pragma unroll
        for (int ni = 0; ni < 2; ++ni) {
          const int rB = wc + ni * 16 + la;
          b[ni] = *(const short8*)((const char*)BL[buf] + rB * 128 + ((chB ^ (rB & 7)) << 4));
        }
        __builtin_amdgcn_s_setprio(1);
        #pragma unroll
        for (int mi = 0; mi < 4; ++mi)
          #pragma unroll
          for (int ni = 0; ni < 2; ++ni)
            acc[mi][ni] = __builtin_amdgcn_mfma_f32_16x16x32_bf16(a[mi], b[ni], acc[mi][ni], 0, 0, 0);
        __builtin_amdgcn_s_setprio(0);
      }
      __syncthreads();
      buf ^= 1;
    }

    #pragma unroll
    for (int mi = 0; mi < 4; ++mi) {
      const int mbase = m0 + wr + mi * 16 + kh * 4;
      #pragma unroll
      for (int ni = 0; ni < 2; ++ni) {
        const int nl = nt * 128 + wc + ni * 16 + la;
        const float bn = bias[nl];
        #pragma unroll
        for (int j = 0; j < 4; ++j)
          Co[(size_t)(mbase + j) * 384 + nl] = acc[mi][ni][j] + bn;
      }
    }
  }
}

// ================= fallback (fp32) for small ws =================
__global__ __launch_bounds__(256, 1)
void mha_fused(const float* __restrict__ x, const float* __restrict__ Wq,
               const float* __restrict__ Wk, const float* __restrict__ Wv,
               const float* __restrict__ Wp, const float* __restrict__ bp,
               float* __restrict__ out)
{
  const int bh = blockIdx.x;
  const int b = bh / HEADS, h = bh % HEADS;
  const int tid = (int)threadIdx.x;
  const int wave = tid >> 6, lane = tid & 63;
  const float* xb = x + (size_t)b * TT * EMB;
  const float* wq = Wq + (size_t)h * EMB * DH;
  const float* wk = Wk + (size_t)h * EMB * DH;
  const float* wv = Wv + (size_t)h * EMB * DH;
  __shared__ float Ks[TT][68];
  __shared__ float Vs[TT][64];
  __shared__ float Qt[64][68];
  for (int c = 0; c < 4; ++c) {
    const int s0 = wave * 64 + c * 16;
    float ak[16], av[16];
    #pragma unroll
    for (int r = 0; r < 16; ++r) { ak[r] = 0.f; av[r] = 0.f; }
    for (int e = 0; e < EMB; ++e) {
      const float kk = wk[e * DH + lane];
      const float vv = wv[e * DH + lane];
      #pragma unroll
      for (int r = 0; r < 16; ++r) {
        const float xv = xb[(s0 + r) * EMB + e];
        ak[r] += xv * kk; av[r] += xv * vv;
      }
    }
    #pragma unroll
    for (int r = 0; r < 16; ++r) { Ks[s0 + r][lane] = ak[r]; Vs[s0 + r][lane] = av[r]; }
  }
  __syncthreads();
  const int s = tid;
  float kreg[64];
  {
    const float4* k4 = (const float4*)&Ks[s][0];
    #pragma unroll
    for (int i = 0; i < 16; ++i) {
      float4 kv = k4[i];
      kreg[4*i+0] = kv.x; kreg[4*i+1] = kv.y; kreg[4*i+2] = kv.z; kreg[4*i+3] = kv.w;
    }
  }
  float Lsum = 0.f;
  for (int tile = 0; tile < 4; ++tile) {
    {
      const int r0 = tile * 64 + wave * 16;
      float aq[16];
      #pragma unroll
      for (int r = 0; r < 16; ++r) aq[r] = 0.f;
      for (int e = 0; e < EMB; ++e) {
        const float qw = wq[e * DH + lane];
        #pragma unroll
        for (int r = 0; r < 16; ++r) aq[r] += xb[(r0 + r) * EMB + e] * qw;
      }
      __syncthreads();
      #pragma unroll
      for (int r = 0; r < 16; ++r) Qt[wave*16 + r][lane] = aq[r];
      __syncthreads();
    }
    const int tbase = tile * 64;
    if (tbase + 63 >= s) {
      for (int tr = 0; tr < 64; ++tr) {
        const int t = tbase + tr;
        if (t < s) continue;
        float w = 0.f;
        const float4* q4 = (const float4*)&Qt[tr][0];
        #pragma unroll
        for (int i = 0; i < 16; ++i) {
          float4 qv = q4[i];
          w += qv.x*kreg[4*i+0] + qv.y*kreg[4*i+1] + qv.z*kreg[4*i+2] + qv.w*kreg[4*i+3];
        }
        Lsum += __expf(w * SCALE);
      }
    }
  }
  __syncthreads();
  {
    const float invL = 1.0f / Lsum;
    float4* v4 = (float4*)&Vs[s][0];
    #pragma unroll
    for (int i = 0; i < 16; ++i) {
      float4 vv = v4[i];
      vv.x *= invL; vv.y *= invL; vv.z *= invL; vv.w *= invL;
      v4[i] = vv;
    }
  }
  __syncthreads();
  const float bias1 = bp[tid];
  const float bias2 = (tid < 128) ? bp[256 + tid] : 0.f;
  const int tr = tid >> 2, dq = tid & 3;
  float* ob = out + (size_t)b * TT * EMB;
  for (int tile = 0; tile < 4; ++tile) {
    {
      const int r0 = tile * 64 + wave * 16;
      float aq[16];
      #pragma unroll
      for (int r = 0; r < 16; ++r) aq[r] = 0.f;
      for (int e = 0; e < EMB; ++e) {
        const float qw = wq[e * DH + lane];
        #pragma unroll
        for (int r = 0; r < 16; ++r) aq[r] += xb[(r0 + r) * EMB + e] * qw;
      }
      __syncthreads();
      #pragma unroll
      for (int r = 0; r < 16; ++r) Qt[wave*16 + r][lane] = aq[r];
      __syncthreads();
    }
    const int t = tile * 64 + tr;
    float qreg[16];
    {
      const float4* q4 = (const float4*)&Qt[tr][dq * 16];
      #pragma unroll
      for (int i = 0; i < 4; ++i) {
        float4 qv = q4[i];
        qreg[4*i+0] = qv.x; qreg[4*i+1] = qv.y; qreg[4*i+2] = qv.z; qreg[4*i+3] = qv.w;
      }
    }
    float acc[16];
    #pragma unroll
    for (int i = 0; i < 16; ++i) acc[i] = 0.f;
    for (int s2 = 0; s2 <= t; ++s2) {
      const float4* kk4 = (const float4*)&Ks[s2][dq * 16];
      float part = 0.f;
      #pragma unroll
      for (int i = 0; i < 4; ++i) {
        float4 kv = kk4[i];
        part += qreg[4*i+0]*kv.x + qreg[4*i+1]*kv.y + qreg[4*i+2]*kv.z + qreg[4*i+3]*kv.w;
      }
      part += __shfl_xor(part, 1);
      part += __shfl_xor(part, 2);
      const float p = __expf(part * SCALE);
      const float4* vv4 = (const float4*)&Vs[s2][dq * 16];
      #pragma unroll
      for (int i = 0; i < 4; ++i) {
        float4 vv = vv4[i];
        acc[4*i+0] += p * vv.x; acc[4*i+1] += p * vv.y;
        acc[4*i+2] += p * vv.z; acc[4*i+3] += p * vv.w;
      }
    }
    __syncthreads();
    #pragma unroll
    for (int i = 0; i < 16; ++i) Qt[tr][dq*16 + i] = acc[i];
    __syncthreads();
    const int c1 = tid;
    const int c2 = 256 + tid;
    for (int rg = 0; rg < 4; ++rg) {
      float a1[16], a2[16];
      #pragma unroll
      for (int r = 0; r < 16; ++r) { a1[r] = 0.f; a2[r] = 0.f; }
      for (int d = 0; d < 64; ++d) {
        const float wp1 = Wp[(size_t)(h*64 + d) * EMB + c1];
        const float wp2 = (tid < 128) ? Wp[(size_t)(h*64 + d) * EMB + c2] : 0.f;
        #pragma unroll
        for (int r = 0; r < 16; ++r) {
          const float a = Qt[rg*16 + r][d];
          a1[r] += a * wp1; a2[r] += a * wp2;
        }
      }
      if (h == 0) {
        #pragma unroll
        for (int r = 0; r < 16; ++r) { a1[r] += bias1; a2[r] += bias2; }
      }
      const int trow0 = tile*64 + rg*16;
      #pragma unroll
      for (int r = 0; r < 16; ++r)
        atomicAdd(&ob[(size_t)(trow0 + r) * EMB + c1], a1[r]);
      if (tid < 128) {
        #pragma unroll
        for (int r = 0; r < 16; ++r)
          atomicAdd(&ob[(size_t)(trow0 + r) * EMB + c2], a2[r]);
      }
    }
    __syncthreads();
  }
}

extern "C" void kernel_launch(void* const* d_in, const int* in_sizes, int n_in,
                              void* d_out, int out_size, void* d_ws, size_t ws_size,
                              hipStream_t stream) {
  const float* x  = (const float*)d_in[0];
  const float* Wq = (const float*)d_in[1];
  const float* Wk = (const float*)d_in[2];
  const float* Wv = (const float*)d_in[3];
  const float* Wp = (const float*)d_in[4];
  const float* bp = (const float*)d_in[5];

  const int nb = in_sizes[0] / (TT * EMB);       // batch (128)
  const size_t M = (size_t)nb * TT;              // 32768 rows
  const size_t XB = M * EMB * 2;                 // bf16 activation bytes (25 MB)
  const size_t WT = (size_t)1536 * 384 * 2;

  const size_t off_x  = 0;
  const size_t off_wt = XB;
  const size_t off_o  = off_wt + WT;
  const size_t need   = off_o + XB;

  if (ws_size < need) {
    hipMemsetAsync(d_out, 0, (size_t)out_size * sizeof(float), stream);
    mha_fused<<<nb * HEADS, 256, 0, stream>>>(x, Wq, Wk, Wv, Wp, bp, (float*)d_out);
    return;
  }

  char* ws = (char*)d_ws;
  unsigned short* xb16 = (unsigned short*)(ws + off_x);
  unsigned short* Wt   = (unsigned short*)(ws + off_wt);
  unsigned short* Ow   = (unsigned short*)(ws + off_o);

  const int n8 = (int)(M * EMB / 8);
  cvt_x<<<(n8 + 255) / 256, 256, 0, stream>>>(x, xb16, n8);
  build_wt<<<288, 256, 0, stream>>>(Wq, Wk, Wv, Wp, Wt);

  qkv_attn<<<nb * HEADS, 512, 0, stream>>>(xb16, Wt, Ow);

  proj_gemm<<<(unsigned)(M / 128), 512, 0, stream>>>(
      Ow, Wt + (size_t)1152 * 384, (float*)d_out, bp);
}

// Round 12
// 116.987 us; speedup vs baseline: 1.2386x; 1.0149x over previous
//
#include <hip/hip_runtime.h>

#define EMB 384
#define HEADS 6
#define DH 64
#define TT 256

constexpr float SCALE = 0.05103103630798288f;  // 384^-0.5

typedef __attribute__((ext_vector_type(8))) short short8;
typedef __attribute__((ext_vector_type(4))) float f32x4;
typedef __attribute__((ext_vector_type(4))) unsigned short u16x4;

__device__ __forceinline__ unsigned short f2bf(float f) {
  unsigned int u = __builtin_bit_cast(unsigned int, f);
  u += 0x7FFFu + ((u >> 16) & 1u);   // RNE
  return (unsigned short)(u >> 16);
}
__device__ __forceinline__ float bf2f(unsigned short u) {
  unsigned int v = ((unsigned int)u) << 16;
  return __builtin_bit_cast(float, v);
}
__device__ __forceinline__ void gll16(const void* g, void* l) {
  __builtin_amdgcn_global_load_lds(
      (const __attribute__((address_space(1))) unsigned int*)g,
      (__attribute__((address_space(3))) unsigned int*)l, 16, 0, 0);
}

// ---------------- K0a: convert x fp32 -> bf16 ----------------
__global__ __launch_bounds__(256)
void cvt_x(const float* __restrict__ x, unsigned short* __restrict__ xb, int n8) {
  int i = blockIdx.x * 256 + threadIdx.x;
  if (i < n8) {
    const float4* src = (const float4*)x;
    float4 a = src[i * 2], b = src[i * 2 + 1];
    short8 o;
    o[0] = (short)f2bf(a.x); o[1] = (short)f2bf(a.y);
    o[2] = (short)f2bf(a.z); o[3] = (short)f2bf(a.w);
    o[4] = (short)f2bf(b.x); o[5] = (short)f2bf(b.y);
    o[6] = (short)f2bf(b.z); o[7] = (short)f2bf(b.w);
    ((short8*)xb)[i] = o;
  }
}

// ---- K0b: build Wt[1536][384] bf16. Rows 0..1151: per-HEAD blocks of 192
// (q d0-63 | k d0-63 | v d0-63); rows 1152..1535: proj^T. ----
__global__ __launch_bounds__(256)
void build_wt(const float* __restrict__ Wq, const float* __restrict__ Wk,
              const float* __restrict__ Wv, const float* __restrict__ Wp,
              unsigned short* __restrict__ Wt) {
  int idx = blockIdx.x * 256 + threadIdx.x;  // 1536*48 = 73728
  int n = idx / 48, e0 = (idx % 48) * 8;
  const float* src; int stride;
  if (n < 1152) {
    int h = n / 192, rem = n % 192, qkv = rem >> 6, d = rem & 63;
    const float* W = (qkv == 0) ? Wq : (qkv == 1) ? Wk : Wv;
    src = W + ((size_t)h * EMB + e0) * DH + d; stride = DH;
  } else {
    int c = n - 1152;
    src = Wp + (size_t)e0 * EMB + c; stride = EMB;
  }
  short8 o;
  #pragma unroll
  for (int j = 0; j < 8; ++j) o[j] = (short)f2bf(src[j * stride]);
  ((short8*)Wt)[idx] = o;
}

// ================= fused QKV-GEMM + attention, one block per (b,h) =================
// 1024 thr / 16 waves (4 waves/SIMD). GEMM: 4x4 wave grid, tile 64x48, acc[4][3].
// QK^T: pair p={p,15-p} split across waves {2p,2p+1} by ns-parity -> exactly
// 9 col-tile units per wave (perfect balance). PV: wave 2p takes big tile,
// 2p+1 small tile. Col sums fused into QK^T via shfl_xor.
__global__ __launch_bounds__(1024, 1)
void qkv_attn(const unsigned short* __restrict__ xb16, const unsigned short* __restrict__ Wt,
              unsigned short* __restrict__ O)
{
  __shared__ __align__(16) char EL[73728];   // GEMM: AL(32K)+BL(24K); then Qtmp; then E
  __shared__ __align__(16) char KL[32768];   // K [256][64] bf16, chunk pos = dc^(t&7)
  __shared__ __align__(16) char VL[32768];   // V^T [64][256] bf16, chunk pos = tc^(d&7)
  __shared__ float Lpart[16][256];
  __shared__ float invL[256];

  const int bh = blockIdx.x, tid = (int)threadIdx.x;
  const int w = tid >> 6, lane = tid & 63;
  const int la = lane & 15, kh = lane >> 4;
  const int b = bh / 6, h = bh - b * 6;
  const unsigned short* xb = xb16 + (size_t)b * 256 * 384;
  const unsigned short* Wb = Wt + (size_t)h * 192 * 384;
  char* AL = EL;            // 32 KB
  char* BL = EL + 32768;    // 24 KB

  // ---------------- QKV GEMM: wave tile 64 x 48 ----------------
  const int wr = (w >> 2) * 64, wc = (w & 3) * 48;
  f32x4 acc[4][3];
  #pragma unroll
  for (int i = 0; i < 4; ++i)
    #pragma unroll
    for (int j = 0; j < 3; ++j) acc[i][j] = f32x4{0.f, 0.f, 0.f, 0.f};

  for (int kt = 0; kt < 6; ++kt) {
    if (kt) __syncthreads();           // previous step's reads done
    #pragma unroll
    for (int i = 0; i < 2; ++i) {      // A: x chunk [256][64] bf16, 32KB
      const int Lb = i * 16384 + tid * 16;
      const int row = Lb >> 7;
      const int kcs = ((Lb >> 4) & 7) ^ (row & 7);
      gll16(xb + (size_t)row * 384 + kt * 64 + kcs * 8, AL + Lb);
    }
    {                                  // B: W chunk [192][64] bf16, 24KB
      const int Lb0 = tid * 16;
      const int row0 = Lb0 >> 7;
      const int kcs0 = ((Lb0 >> 4) & 7) ^ (row0 & 7);
      gll16(Wb + (size_t)row0 * 384 + kt * 64 + kcs0 * 8, BL + Lb0);
      if (tid < 512) {
        const int Lb = 16384 + tid * 16;
        const int row = Lb >> 7;
        const int kcs = ((Lb >> 4) & 7) ^ (row & 7);
        gll16(Wb + (size_t)row * 384 + kt * 64 + kcs * 8, BL + Lb);
      }
    }
    __syncthreads();                   // stages landed
    #pragma unroll
    for (int kk = 0; kk < 2; ++kk) {
      const int ch = kk * 4 + kh;
      short8 a[4], bfr[3];
      #pragma unroll
      for (int mi = 0; mi < 4; ++mi) {
        const int r = wr + mi * 16 + la;
        a[mi] = *(const short8*)(AL + r * 128 + ((ch ^ (r & 7)) << 4));
      }
      #pragma unroll
      for (int ni = 0; ni < 3; ++ni) {
        const int rB = wc + ni * 16 + la;
        bfr[ni] = *(const short8*)(BL + rB * 128 + ((ch ^ (rB & 7)) << 4));
      }
      __builtin_amdgcn_s_setprio(1);
      #pragma unroll
      for (int mi = 0; mi < 4; ++mi)
        #pragma unroll
        for (int ni = 0; ni < 3; ++ni)
          acc[mi][ni] = __builtin_amdgcn_mfma_f32_16x16x32_bf16(a[mi], bfr[ni], acc[mi][ni], 0, 0, 0);
      __builtin_amdgcn_s_setprio(0);
    }
  }
  __syncthreads();   // all reads of AL/BL done before Qtmp overwrites EL

  // ---- epilogue: Q -> Qtmp (EL, [256][64] swizzled), K -> KL, V^T -> VL ----
  #pragma unroll
  for (int mi = 0; mi < 4; ++mi) {
    #pragma unroll
    for (int ni = 0; ni < 3; ++ni) {
      const int col = wc + ni * 16 + la;
      const int tb = wr + mi * 16 + kh * 4;
      if (col < 64) {
        const int d = col;
        #pragma unroll
        for (int j = 0; j < 4; ++j) {
          const int t = tb + j;
          *(unsigned short*)(EL + t * 128 + (((d >> 3) ^ (t & 7)) << 4) + (d & 7) * 2)
              = f2bf(acc[mi][ni][j]);
        }
      } else if (col < 128) {
        const int d = col - 64;
        #pragma unroll
        for (int j = 0; j < 4; ++j) {
          const int t = tb + j;
          *(unsigned short*)(KL + t * 128 + (((d >> 3) ^ (t & 7)) << 4) + (d & 7) * 2)
              = f2bf(acc[mi][ni][j]);
        }
      } else {
        const int d = col - 128;
        u16x4 pk;
        #pragma unroll
        for (int j = 0; j < 4; ++j) pk[j] = f2bf(acc[mi][ni][j]);
        *(u16x4*)(VL + d * 512 + (((tb >> 3) ^ (d & 7)) << 4) + (tb & 7) * 2) = pk;
      }
    }
  }
  __syncthreads();

  // ---- hoist Q fragments for this wave's PAIR {p, 15-p}, p = w>>1 ----
  const int p = w >> 1;
  const int rts[2] = { p, 15 - p };
  short8 qa[2][2];
  #pragma unroll
  for (int ti = 0; ti < 2; ++ti)
    #pragma unroll
    for (int kk = 0; kk < 2; ++kk) {
      const int r = rts[ti] * 16 + la;
      const int ch = kk * 4 + kh;
      qa[ti][kk] = *(const short8*)(EL + r * 128 + ((ch ^ (r & 7)) << 4));
    }
  __syncthreads();   // EL now free for E strips

  int wps[2], eoffs[2];
  #pragma unroll
  for (int ti = 0; ti < 2; ++ti) {
    const int rt = rts[ti];
    wps[ti] = 32 * ((rt + 2) >> 1);
    const int S = (rt & 1) ? ((rt + 1) * (rt + 1) / 4) : (rt * (rt + 2) / 4);
    eoffs[ti] = 1024 * S;
  }

  // ---- zero own Lpart row (wave-local) ----
  #pragma unroll
  for (int i = 0; i < 4; ++i) Lpart[w][i * 64 + lane] = 0.f;

  // ---- QK^T + masked exp -> E strips; ns-parity split across the pair's waves ----
  #pragma unroll
  for (int ti = 0; ti < 2; ++ti) {
    const int rt = rts[ti], wp = wps[ti], stride = wp * 2;
    char* Ebase = EL + eoffs[ti];
    const int nns = wp >> 4;
    for (int ns = (w & 1); ns < nns; ns += 2) {
      f32x4 s4 = f32x4{0.f, 0.f, 0.f, 0.f};
      #pragma unroll
      for (int kk = 0; kk < 2; ++kk) {
        const int rB = ns * 16 + la, kc = kk * 4 + kh;
        short8 bf = *(const short8*)(KL + rB * 128 + ((kc ^ (rB & 7)) << 4));
        s4 = __builtin_amdgcn_mfma_f32_16x16x32_bf16(qa[ti][kk], bf, s4, 0, 0, 0);
      }
      const int c = ns * 16 + la, cc = c >> 3, co = (c & 7) * 2;
      float ps = 0.f;
      #pragma unroll
      for (int j = 0; j < 4; ++j) {
        const int r = kh * 4 + j;
        const int t = rt * 16 + r;
        const float e = (t >= c) ? __expf(s4[j] * SCALE) : 0.f;
        ps += e;
        *(unsigned short*)(Ebase + r * stride + ((cc ^ (r & 3)) << 4) + co) = f2bf(e);
      }
      ps += __shfl_xor(ps, 16);
      ps += __shfl_xor(ps, 32);        // 16-row tile-column sum in all kh lanes
      if (kh == 0) Lpart[w][c] += ps;  // wave-local row: no race
    }
  }
  __syncthreads();

  if (tid < 256) {
    float Ls = 0.f;
    #pragma unroll
    for (int ww = 0; ww < 16; ++ww) Ls += Lpart[ww][tid];
    invL[tid] = 1.f / Ls;
  }
  __syncthreads();

  // ---- fold 1/L_s into V (1024 threads: 2 chunks each) ----
  {
    const int d = tid >> 4, qq = tid & 15;
    #pragma unroll
    for (int i = 0; i < 2; ++i) {
      const int kcp = qq * 2 + i;
      char* pch = VL + d * 512 + kcp * 16;
      short8 v = *(short8*)pch;
      const int sb = (kcp ^ (d & 7)) * 8;
      short8 o;
      #pragma unroll
      for (int e = 0; e < 8; ++e)
        o[e] = (short)f2bf(bf2f((unsigned short)v[e]) * invL[sb + e]);
      *(short8*)pch = o;
    }
  }
  __syncthreads();

  // ---- O = E * V': wave 2p -> big tile (15-p), wave 2p+1 -> small tile (p) ----
  unsigned short* Og = O + (size_t)b * 256 * 384 + h * 64;
  {
    const int ti = (w & 1) ? 0 : 1;
    const int rt = rts[ti], wp = wps[ti], stride = wp * 2;
    const char* Ebase = EL + eoffs[ti];
    f32x4 oacc[4];
    #pragma unroll
    for (int nd = 0; nd < 4; ++nd) oacc[nd] = f32x4{0.f, 0.f, 0.f, 0.f};
    const int nks = wp >> 5;
    for (int ks = 0; ks < nks; ++ks) {
      const int cc = ks * 4 + kh;
      short8 ea = *(const short8*)(Ebase + la * stride + ((cc ^ (la & 3)) << 4));
      __builtin_amdgcn_s_setprio(1);
      #pragma unroll
      for (int nd = 0; nd < 4; ++nd) {
        const int d = nd * 16 + la;
        short8 vb = *(const short8*)(VL + d * 512 + ((cc ^ (d & 7)) << 4));
        oacc[nd] = __builtin_amdgcn_mfma_f32_16x16x32_bf16(ea, vb, oacc[nd], 0, 0, 0);
      }
      __builtin_amdgcn_s_setprio(0);
    }
    #pragma unroll
    for (int nd = 0; nd < 4; ++nd) {
      const int d = nd * 16 + la;
      #pragma unroll
      for (int j = 0; j < 4; ++j) {
        const int t = rt * 16 + kh * 4 + j;
        Og[(size_t)t * 384 + d] = f2bf(oacc[nd][j]);
      }
    }
  }
}

// ---------------- proj GEMM: out = O * proj + bias ----------------
__global__ __launch_bounds__(512, 1)
void proj_gemm(const unsigned short* __restrict__ A, const unsigned short* __restrict__ Bt,
               float* __restrict__ Co, const float* __restrict__ bias)
{
  __shared__ __align__(16) unsigned short AL[128 * 384];    // 96 KB
  __shared__ __align__(16) unsigned short BL[2][128 * 64];  // 2 x 16 KB
  const int tid = (int)threadIdx.x, w = tid >> 6, lane = tid & 63;
  const int la = lane & 15, kh = lane >> 4;
  const int m0 = blockIdx.x * 128;

  {
    const int row = tid >> 2, qq = tid & 3;
    const short8* O8 = (const short8*)(A + (size_t)(m0 + row) * 384);
    #pragma unroll
    for (int i = 0; i < 12; ++i) {
      const int ch = qq + 4 * i;
      *(short8*)((char*)AL + row * 768 + ((ch ^ (row & 7)) << 4)) = O8[ch];
    }
  }

  auto stageB = [&](int buf, int n0, int k0) {
    #pragma unroll
    for (int i = 0; i < 2; ++i) {
      const int Lb = i * 8192 + tid * 16;
      const int row = Lb >> 7;
      const int kcs = ((Lb >> 4) & 7) ^ (row & 7);
      gll16(Bt + (size_t)(n0 + row) * 384 + k0 + kcs * 8, (char*)BL[buf] + Lb);
    }
  };

  stageB(0, 0, 0);
  __syncthreads();

  const int wr = (w >> 2) * 64, wc = (w & 3) * 32;
  int buf = 0;
  for (int nt = 0; nt < 3; ++nt) {
    f32x4 acc[4][2];
    #pragma unroll
    for (int i = 0; i < 4; ++i) { acc[i][0] = f32x4{0.f,0.f,0.f,0.f}; acc[i][1] = f32x4{0.f,0.f,0.f,0.f}; }

    for (int kt = 0; kt < 6; ++kt) {
      if (kt < 5)          stageB(buf ^ 1, nt * 128, (kt + 1) * 64);
      else if (nt + 1 < 3) stageB(buf ^ 1, (nt + 1) * 128, 0);
      #pragma unroll
      for (int kk = 0; kk < 2; ++kk) {
        short8 a[4], bb[2];
        const int chA = kt * 8 + kk * 4 + kh;
        #pragma unroll
        for (int mi = 0; mi < 4; ++mi) {
          const int r = wr + mi * 16 + la;
          a[mi] = *(const short8*)((const char*)AL + r * 768 + ((chA ^ (r & 7)) << 4));
        }
        const int chB = kk * 4 + kh;
        #pragma unroll
        for (int ni = 0; ni < 2; ++ni) {
          const int rB = wc + ni * 16 + la;
          bb[ni] = *(const short8*)((const char*)BL[buf] + rB * 128 + ((chB ^ (rB & 7)) << 4));
        }
        __builtin_amdgcn_s_setprio(1);
        #pragma unroll
        for (int mi = 0; mi < 4; ++mi)
          #pragma unroll
          for (int ni = 0; ni < 2; ++ni)
            acc[mi][ni] = __builtin_amdgcn_mfma_f32_16x16x32_bf16(a[mi], bb[ni], acc[mi][ni], 0, 0, 0);
        __builtin_amdgcn_s_setprio(0);
      }
      __syncthreads();
      buf ^= 1;
    }

    #pragma unroll
    for (int mi = 0; mi < 4; ++mi) {
      const int mbase = m0 + wr + mi * 16 + kh * 4;
      #pragma unroll
      for (int ni = 0; ni < 2; ++ni) {
        const int nl = nt * 128 + wc + ni * 16 + la;
        const float bn = bias[nl];
        #pragma unroll
        for (int j = 0; j < 4; ++j)
          Co[(size_t)(mbase + j) * 384 + nl] = acc[mi][ni][j] + bn;
      }
    }
  }
}

// ================= fallback (fp32) for small ws =================
__global__ __launch_bounds__(256, 1)
void mha_fused(const float* __restrict__ x, const float* __restrict__ Wq,
               const float* __restrict__ Wk, const float* __restrict__ Wv,
               const float* __restrict__ Wp, const float* __restrict__ bp,
               float* __restrict__ out)
{
  const int bh = blockIdx.x;
  const int b = bh / HEADS, h = bh % HEADS;
  const int tid = (int)threadIdx.x;
  const int wave = tid >> 6, lane = tid & 63;
  const float* xb = x + (size_t)b * TT * EMB;
  const float* wq = Wq + (size_t)h * EMB * DH;
  const float* wk = Wk + (size_t)h * EMB * DH;
  const float* wv = Wv + (size_t)h * EMB * DH;
  __shared__ float Ks[TT][68];
  __shared__ float Vs[TT][64];
  __shared__ float Qt[64][68];
  for (int c = 0; c < 4; ++c) {
    const int s0 = wave * 64 + c * 16;
    float ak[16], av[16];
    #pragma unroll
    for (int r = 0; r < 16; ++r) { ak[r] = 0.f; av[r] = 0.f; }
    for (int e = 0; e < EMB; ++e) {
      const float kk = wk[e * DH + lane];
      const float vv = wv[e * DH + lane];
      #pragma unroll
      for (int r = 0; r < 16; ++r) {
        const float xv = xb[(s0 + r) * EMB + e];
        ak[r] += xv * kk; av[r] += xv * vv;
      }
    }
    #pragma unroll
    for (int r = 0; r < 16; ++r) { Ks[s0 + r][lane] = ak[r]; Vs[s0 + r][lane] = av[r]; }
  }
  __syncthreads();
  const int s = tid;
  float kreg[64];
  {
    const float4* k4 = (const float4*)&Ks[s][0];
    #pragma unroll
    for (int i = 0; i < 16; ++i) {
      float4 kv = k4[i];
      kreg[4*i+0] = kv.x; kreg[4*i+1] = kv.y; kreg[4*i+2] = kv.z; kreg[4*i+3] = kv.w;
    }
  }
  float Lsum = 0.f;
  for (int tile = 0; tile < 4; ++tile) {
    {
      const int r0 = tile * 64 + wave * 16;
      float aq[16];
      #pragma unroll
      for (int r = 0; r < 16; ++r) aq[r] = 0.f;
      for (int e = 0; e < EMB; ++e) {
        const float qw = wq[e * DH + lane];
        #pragma unroll
        for (int r = 0; r < 16; ++r) aq[r] += xb[(r0 + r) * EMB + e] * qw;
      }
      __syncthreads();
      #pragma unroll
      for (int r = 0; r < 16; ++r) Qt[wave*16 + r][lane] = aq[r];
      __syncthreads();
    }
    const int tbase = tile * 64;
    if (tbase + 63 >= s) {
      for (int tr = 0; tr < 64; ++tr) {
        const int t = tbase + tr;
        if (t < s) continue;
        float w = 0.f;
        const float4* q4 = (const float4*)&Qt[tr][0];
        #pragma unroll
        for (int i = 0; i < 16; ++i) {
          float4 qv = q4[i];
          w += qv.x*kreg[4*i+0] + qv.y*kreg[4*i+1] + qv.z*kreg[4*i+2] + qv.w*kreg[4*i+3];
        }
        Lsum += __expf(w * SCALE);
      }
    }
  }
  __syncthreads();
  {
    const float invL = 1.0f / Lsum;
    float4* v4 = (float4*)&Vs[s][0];
    #pragma unroll
    for (int i = 0; i < 16; ++i) {
      float4 vv = v4[i];
      vv.x *= invL; vv.y *= invL; vv.z *= invL; vv.w *= invL;
      v4[i] = vv;
    }
  }
  __syncthreads();
  const float bias1 = bp[tid];
  const float bias2 = (tid < 128) ? bp[256 + tid] : 0.f;
  const int tr = tid >> 2, dq = tid & 3;
  float* ob = out + (size_t)b * TT * EMB;
  for (int tile = 0; tile < 4; ++tile) {
    {
      const int r0 = tile * 64 + wave * 16;
      float aq[16];
      #pragma unroll
      for (int r = 0; r < 16; ++r) aq[r] = 0.f;
      for (int e = 0; e < EMB; ++e) {
        const float qw = wq[e * DH + lane];
        #pragma unroll
        for (int r = 0; r < 16; ++r) aq[r] += xb[(r0 + r) * EMB + e] * qw;
      }
      __syncthreads();
      #pragma unroll
      for (int r = 0; r < 16; ++r) Qt[wave*16 + r][lane] = aq[r];
      __syncthreads();
    }
    const int t = tile * 64 + tr;
    float qreg[16];
    {
      const float4* q4 = (const float4*)&Qt[tr][dq * 16];
      #pragma unroll
      for (int i = 0; i < 4; ++i) {
        float4 qv = q4[i];
        qreg[4*i+0] = qv.x; qreg[4*i+1] = qv.y; qreg[4*i+2] = qv.z; qreg[4*i+3] = qv.w;
      }
    }
    float acc[16];
    #pragma unroll
    for (int i = 0; i < 16; ++i) acc[i] = 0.f;
    for (int s2 = 0; s2 <= t; ++s2) {
      const float4* kk4 = (const float4*)&Ks[s2][dq * 16];
      float part = 0.f;
      #pragma unroll
      for (int i = 0; i < 4; ++i) {
        float4 kv = kk4[i];
        part += qreg[4*i+0]*kv.x + qreg[4*i+1]*kv.y + qreg[4*i+2]*kv.z + qreg[4*i+3]*kv.w;
      }
      part += __shfl_xor(part, 1);
      part += __shfl_xor(part, 2);
      const float p = __expf(part * SCALE);
      const float4* vv4 = (const float4*)&Vs[s2][dq * 16];
      #pragma unroll
      for (int i = 0; i < 4; ++i) {
        float4 vv = vv4[i];
        acc[4*i+0] += p * vv.x; acc[4*i+1] += p * vv.y;
        acc[4*i+2] += p * vv.z; acc[4*i+3] += p * vv.w;
      }
    }
    __syncthreads();
    #pragma unroll
    for (int i = 0; i < 16; ++i) Qt[tr][dq*16 + i] = acc[i];
    __syncthreads();
    const int c1 = tid;
    const int c2 = 256 + tid;
    for (int rg = 0; rg < 4; ++rg) {
      float a1[16], a2[16];
      #pragma unroll
      for (int r = 0; r < 16; ++r) { a1[r] = 0.f; a2[r] = 0.f; }
      for (int d = 0; d < 64; ++d) {
        const float wp1 = Wp[(size_t)(h*64 + d) * EMB + c1];
        const float wp2 = (tid < 128) ? Wp[(size_t)(h*64 + d) * EMB + c2] : 0.f;
        #pragma unroll
        for (int r = 0; r < 16; ++r) {
          const float a = Qt[rg*16 + r][d];
          a1[r] += a * wp1; a2[r] += a * wp2;
        }
      }
      if (h == 0) {
        #pragma unroll
        for (int r = 0; r < 16; ++r) { a1[r] += bias1; a2[r] += bias2; }
      }
      const int trow0 = tile*64 + rg*16;
      #pragma unroll
      for (int r = 0; r < 16; ++r)
        atomicAdd(&ob[(size_t)(trow0 + r) * EMB + c1], a1[r]);
      if (tid < 128) {
        #pragma unroll
        for (int r = 0; r < 16; ++r)
          atomicAdd(&ob[(size_t)(trow0 + r) * EMB + c2], a2[r]);
      }
    }
    __syncthreads();
  }
}

extern "C" void kernel_launch(void* const* d_in, const int* in_sizes, int n_in,
                              void* d_out, int out_size, void* d_ws, size_t ws_size,
                              hipStream_t stream) {
  const float* x  = (const float*)d_in[0];
  const float* Wq = (const float*)d_in[1];
  const float* Wk = (const float*)d_in[2];
  const float* Wv = (const float*)d_in[3];
  const float* Wp = (const float*)d_in[4];
  const float* bp = (const float*)d_in[5];

  const int nb = in_sizes[0] / (TT * EMB);       // batch (128)
  const size_t M = (size_t)nb * TT;              // 32768 rows
  const size_t XB = M * EMB * 2;                 // bf16 activation bytes (25 MB)
  const size_t WT = (size_t)1536 * 384 * 2;

  const size_t off_x  = 0;
  const size_t off_wt = XB;
  const size_t off_o  = off_wt + WT;
  const size_t need   = off_o + XB;

  if (ws_size < need) {
    hipMemsetAsync(d_out, 0, (size_t)out_size * sizeof(float), stream);
    mha_fused<<<nb * HEADS, 256, 0, stream>>>(x, Wq, Wk, Wv, Wp, bp, (float*)d_out);
    return;
  }

  char* ws = (char*)d_ws;
  unsigned short* xb16 = (unsigned short*)(ws + off_x);
  unsigned short* Wt   = (unsigned short*)(ws + off_wt);
  unsigned short* Ow   = (unsigned short*)(ws + off_o);

  const int n8 = (int)(M * EMB / 8);
  cvt_x<<<(n8 + 255) / 256, 256, 0, stream>>>(x, xb16, n8);
  build_wt<<<288, 256, 0, stream>>>(Wq, Wk, Wv, Wp, Wt);

  qkv_attn<<<nb * HEADS, 1024, 0, stream>>>(xb16, Wt, Ow);

  proj_gemm<<<(unsigned)(M / 128), 512, 0, stream>>>(
      Ow, Wt + (size_t)1152 * 384, (float*)d_out, bp);
}

// Round 13
// 106.198 us; speedup vs baseline: 1.3645x; 1.1016x over previous
//
#include <hip/hip_runtime.h>

#define EMB 384
#define HEADS 6
#define DH 64
#define TT 256

constexpr float SCALE = 0.05103103630798288f;  // 384^-0.5

typedef __attribute__((ext_vector_type(8))) short short8;
typedef __attribute__((ext_vector_type(4))) float f32x4;
typedef __attribute__((ext_vector_type(4))) unsigned short u16x4;

__device__ __forceinline__ unsigned short f2bf(float f) {
  unsigned int u = __builtin_bit_cast(unsigned int, f);
  u += 0x7FFFu + ((u >> 16) & 1u);   // RNE
  return (unsigned short)(u >> 16);
}
__device__ __forceinline__ float bf2f(unsigned short u) {
  unsigned int v = ((unsigned int)u) << 16;
  return __builtin_bit_cast(float, v);
}
__device__ __forceinline__ void gll16(const void* g, void* l) {
  __builtin_amdgcn_global_load_lds(
      (const __attribute__((address_space(1))) unsigned int*)g,
      (__attribute__((address_space(3))) unsigned int*)l, 16, 0, 0);
}

// ---------------- K0a: convert x fp32 -> bf16 ----------------
__global__ __launch_bounds__(256)
void cvt_x(const float* __restrict__ x, unsigned short* __restrict__ xb, int n8) {
  int i = blockIdx.x * 256 + threadIdx.x;
  if (i < n8) {
    const float4* src = (const float4*)x;
    float4 a = src[i * 2], b = src[i * 2 + 1];
    short8 o;
    o[0] = (short)f2bf(a.x); o[1] = (short)f2bf(a.y);
    o[2] = (short)f2bf(a.z); o[3] = (short)f2bf(a.w);
    o[4] = (short)f2bf(b.x); o[5] = (short)f2bf(b.y);
    o[6] = (short)f2bf(b.z); o[7] = (short)f2bf(b.w);
    ((short8*)xb)[i] = o;
  }
}

// ---- K0b: build Wt[1536][384] bf16. Rows 0..1151: per-HEAD blocks of 192
// (q d0-63 | k d0-63 | v d0-63); rows 1152..1535: proj^T. ----
__global__ __launch_bounds__(256)
void build_wt(const float* __restrict__ Wq, const float* __restrict__ Wk,
              const float* __restrict__ Wv, const float* __restrict__ Wp,
              unsigned short* __restrict__ Wt) {
  int idx = blockIdx.x * 256 + threadIdx.x;  // 1536*48 = 73728
  int n = idx / 48, e0 = (idx % 48) * 8;
  const float* src; int stride;
  if (n < 1152) {
    int h = n / 192, rem = n % 192, qkv = rem >> 6, d = rem & 63;
    const float* W = (qkv == 0) ? Wq : (qkv == 1) ? Wk : Wv;
    src = W + ((size_t)h * EMB + e0) * DH + d; stride = DH;
  } else {
    int c = n - 1152;
    src = Wp + (size_t)e0 * EMB + c; stride = EMB;
  }
  short8 o;
  #pragma unroll
  for (int j = 0; j < 8; ++j) o[j] = (short)f2bf(src[j * stride]);
  ((short8*)Wt)[idx] = o;
}

// ================= fused QKV-GEMM + attention, one block per (b,h) =================
// 1024 thr / 16 waves. GEMM: 4x4 wave grid, tile 64x48, acc[4][3], DOUBLE-BUFFERED
// staging (buf1 = KL/VL, dead until epilogue): stage(kt+1) overlaps compute(kt),
// one barrier/step. XCD swizzle: contiguous 96-bh chunks per XCD -> x L2-resident.
__global__ __launch_bounds__(1024, 1)
void qkv_attn(const unsigned short* __restrict__ xb16, const unsigned short* __restrict__ Wt,
              unsigned short* __restrict__ O)
{
  __shared__ __align__(16) char EL[73728];   // GEMM buf0: A0(32K)+B0(24K); then Qtmp; then E
  __shared__ __align__(16) char KL[32768];   // GEMM buf1 A1; then K [256][64] swizzled
  __shared__ __align__(16) char VL[32768];   // GEMM buf1 B1 (24K); then V^T [64][256] swizzled
  __shared__ float Lpart[16][256];
  __shared__ float invL[256];

  const int bhRaw = blockIdx.x, tid = (int)threadIdx.x;
  const int bh = (bhRaw & 7) * 96 + (bhRaw >> 3);   // 768 = 8*96: bijective XCD swizzle
  const int w = tid >> 6, lane = tid & 63;
  const int la = lane & 15, kh = lane >> 4;
  const int b = bh / 6, h = bh - b * 6;
  const unsigned short* xb = xb16 + (size_t)b * 256 * 384;
  const unsigned short* Wb = Wt + (size_t)h * 192 * 384;
  char* A0 = EL;            // 32 KB
  char* B0 = EL + 32768;    // 24 KB
  char* A1 = KL;            // 32 KB (scratch during GEMM)
  char* B1 = VL;            // 24 KB of 32 KB (scratch during GEMM)

  // ---------------- QKV GEMM: wave tile 64 x 48, double-buffered ----------------
  const int wr = (w >> 2) * 64, wc = (w & 3) * 48;
  f32x4 acc[4][3];
  #pragma unroll
  for (int i = 0; i < 4; ++i)
    #pragma unroll
    for (int j = 0; j < 3; ++j) acc[i][j] = f32x4{0.f, 0.f, 0.f, 0.f};

  auto stage = [&](char* A, char* B, int kt) {
    #pragma unroll
    for (int i = 0; i < 2; ++i) {      // A: x chunk [256][64] bf16, 32KB
      const int Lb = i * 16384 + tid * 16;
      const int row = Lb >> 7;
      const int kcs = ((Lb >> 4) & 7) ^ (row & 7);
      gll16(xb + (size_t)row * 384 + kt * 64 + kcs * 8, A + Lb);
    }
    {                                  // B: W chunk [192][64] bf16, 24KB
      const int Lb0 = tid * 16;
      const int row0 = Lb0 >> 7;
      const int kcs0 = ((Lb0 >> 4) & 7) ^ (row0 & 7);
      gll16(Wb + (size_t)row0 * 384 + kt * 64 + kcs0 * 8, B + Lb0);
      if (tid < 512) {
        const int Lb = 16384 + tid * 16;
        const int row = Lb >> 7;
        const int kcs = ((Lb >> 4) & 7) ^ (row & 7);
        gll16(Wb + (size_t)row * 384 + kt * 64 + kcs * 8, B + Lb);
      }
    }
  };

  auto compute = [&](const char* A, const char* B) {
    #pragma unroll
    for (int kk = 0; kk < 2; ++kk) {
      const int ch = kk * 4 + kh;
      short8 a[4], bfr[3];
      #pragma unroll
      for (int mi = 0; mi < 4; ++mi) {
        const int r = wr + mi * 16 + la;
        a[mi] = *(const short8*)(A + r * 128 + ((ch ^ (r & 7)) << 4));
      }
      #pragma unroll
      for (int ni = 0; ni < 3; ++ni) {
        const int rB = wc + ni * 16 + la;
        bfr[ni] = *(const short8*)(B + rB * 128 + ((ch ^ (rB & 7)) << 4));
      }
      __builtin_amdgcn_s_setprio(1);
      #pragma unroll
      for (int mi = 0; mi < 4; ++mi)
        #pragma unroll
        for (int ni = 0; ni < 3; ++ni)
          acc[mi][ni] = __builtin_amdgcn_mfma_f32_16x16x32_bf16(a[mi], bfr[ni], acc[mi][ni], 0, 0, 0);
      __builtin_amdgcn_s_setprio(0);
    }
  };

  stage(A0, B0, 0);
  __syncthreads();                       // buf0 ready
  #pragma unroll
  for (int g = 0; g < 3; ++g) {
    const int k1 = 2 * g + 1;
    stage(A1, B1, k1);                   // issue next while computing current
    compute(A0, B0);
    __syncthreads();                     // buf1 landed; buf0 readers done
    if (k1 + 1 < 6) stage(A0, B0, k1 + 1);
    compute(A1, B1);
    __syncthreads();                     // buf0 landed; buf1 readers done
  }

  // ---- epilogue: Q -> Qtmp (EL, [256][64] swizzled), K -> KL, V^T -> VL ----
  #pragma unroll
  for (int mi = 0; mi < 4; ++mi) {
    #pragma unroll
    for (int ni = 0; ni < 3; ++ni) {
      const int col = wc + ni * 16 + la;
      const int tb = wr + mi * 16 + kh * 4;
      if (col < 64) {
        const int d = col;
        #pragma unroll
        for (int j = 0; j < 4; ++j) {
          const int t = tb + j;
          *(unsigned short*)(EL + t * 128 + (((d >> 3) ^ (t & 7)) << 4) + (d & 7) * 2)
              = f2bf(acc[mi][ni][j]);
        }
      } else if (col < 128) {
        const int d = col - 64;
        #pragma unroll
        for (int j = 0; j < 4; ++j) {
          const int t = tb + j;
          *(unsigned short*)(KL + t * 128 + (((d >> 3) ^ (t & 7)) << 4) + (d & 7) * 2)
              = f2bf(acc[mi][ni][j]);
        }
      } else {
        const int d = col - 128;
        u16x4 pk;
        #pragma unroll
        for (int j = 0; j < 4; ++j) pk[j] = f2bf(acc[mi][ni][j]);
        *(u16x4*)(VL + d * 512 + (((tb >> 3) ^ (d & 7)) << 4) + (tb & 7) * 2) = pk;
      }
    }
  }
  __syncthreads();

  // ---- hoist Q fragments for this wave's PAIR {p, 15-p}, p = w>>1 ----
  const int p = w >> 1;
  const int rts[2] = { p, 15 - p };
  short8 qa[2][2];
  #pragma unroll
  for (int ti = 0; ti < 2; ++ti)
    #pragma unroll
    for (int kk = 0; kk < 2; ++kk) {
      const int r = rts[ti] * 16 + la;
      const int ch = kk * 4 + kh;
      qa[ti][kk] = *(const short8*)(EL + r * 128 + ((ch ^ (r & 7)) << 4));
    }
  __syncthreads();   // EL now free for E strips

  int wps[2], eoffs[2];
  #pragma unroll
  for (int ti = 0; ti < 2; ++ti) {
    const int rt = rts[ti];
    wps[ti] = 32 * ((rt + 2) >> 1);
    const int S = (rt & 1) ? ((rt + 1) * (rt + 1) / 4) : (rt * (rt + 2) / 4);
    eoffs[ti] = 1024 * S;
  }

  // ---- zero own Lpart row (wave-local) ----
  #pragma unroll
  for (int i = 0; i < 4; ++i) Lpart[w][i * 64 + lane] = 0.f;

  // ---- QK^T + masked exp -> E strips; ns-parity split across the pair's waves ----
  #pragma unroll
  for (int ti = 0; ti < 2; ++ti) {
    const int rt = rts[ti], wp = wps[ti], stride = wp * 2;
    char* Ebase = EL + eoffs[ti];
    const int nns = wp >> 4;
    for (int ns = (w & 1); ns < nns; ns += 2) {
      f32x4 s4 = f32x4{0.f, 0.f, 0.f, 0.f};
      #pragma unroll
      for (int kk = 0; kk < 2; ++kk) {
        const int rB = ns * 16 + la, kc = kk * 4 + kh;
        short8 bf = *(const short8*)(KL + rB * 128 + ((kc ^ (rB & 7)) << 4));
        s4 = __builtin_amdgcn_mfma_f32_16x16x32_bf16(qa[ti][kk], bf, s4, 0, 0, 0);
      }
      const int c = ns * 16 + la, cc = c >> 3, co = (c & 7) * 2;
      float ps = 0.f;
      #pragma unroll
      for (int j = 0; j < 4; ++j) {
        const int r = kh * 4 + j;
        const int t = rt * 16 + r;
        const float e = (t >= c) ? __expf(s4[j] * SCALE) : 0.f;
        ps += e;
        *(unsigned short*)(Ebase + r * stride + ((cc ^ (r & 3)) << 4) + co) = f2bf(e);
      }
      ps += __shfl_xor(ps, 16);
      ps += __shfl_xor(ps, 32);        // 16-row tile-column sum in all kh lanes
      if (kh == 0) Lpart[w][c] += ps;  // wave-local row: no race
    }
  }
  __syncthreads();

  if (tid < 256) {
    float Ls = 0.f;
    #pragma unroll
    for (int ww = 0; ww < 16; ++ww) Ls += Lpart[ww][tid];
    invL[tid] = 1.f / Ls;
  }
  __syncthreads();

  // ---- fold 1/L_s into V (1024 threads: 2 chunks each) ----
  {
    const int d = tid >> 4, qq = tid & 15;
    #pragma unroll
    for (int i = 0; i < 2; ++i) {
      const int kcp = qq * 2 + i;
      char* pch = VL + d * 512 + kcp * 16;
      short8 v = *(short8*)pch;
      const int sb = (kcp ^ (d & 7)) * 8;
      short8 o;
      #pragma unroll
      for (int e = 0; e < 8; ++e)
        o[e] = (short)f2bf(bf2f((unsigned short)v[e]) * invL[sb + e]);
      *(short8*)pch = o;
    }
  }
  __syncthreads();

  // ---- O = E * V': wave 2p -> big tile (15-p), wave 2p+1 -> small tile (p) ----
  unsigned short* Og = O + (size_t)b * 256 * 384 + h * 64;
  {
    const int ti = (w & 1) ? 0 : 1;
    const int rt = rts[ti], wp = wps[ti], stride = wp * 2;
    const char* Ebase = EL + eoffs[ti];
    f32x4 oacc[4];
    #pragma unroll
    for (int nd = 0; nd < 4; ++nd) oacc[nd] = f32x4{0.f, 0.f, 0.f, 0.f};
    const int nks = wp >> 5;
    for (int ks = 0; ks < nks; ++ks) {
      const int cc = ks * 4 + kh;
      short8 ea = *(const short8*)(Ebase + la * stride + ((cc ^ (la & 3)) << 4));
      __builtin_amdgcn_s_setprio(1);
      #pragma unroll
      for (int nd = 0; nd < 4; ++nd) {
        const int d = nd * 16 + la;
        short8 vb = *(const short8*)(VL + d * 512 + ((cc ^ (d & 7)) << 4));
        oacc[nd] = __builtin_amdgcn_mfma_f32_16x16x32_bf16(ea, vb, oacc[nd], 0, 0, 0);
      }
      __builtin_amdgcn_s_setprio(0);
    }
    #pragma unroll
    for (int nd = 0; nd < 4; ++nd) {
      const int d = nd * 16 + la;
      #pragma unroll
      for (int j = 0; j < 4; ++j) {
        const int t = rt * 16 + kh * 4 + j;
        Og[(size_t)t * 384 + d] = f2bf(oacc[nd][j]);
      }
    }
  }
}

// ---------------- proj GEMM: out = O * proj + bias ----------------
__global__ __launch_bounds__(512, 1)
void proj_gemm(const unsigned short* __restrict__ A, const unsigned short* __restrict__ Bt,
               float* __restrict__ Co, const float* __restrict__ bias)
{
  __shared__ __align__(16) unsigned short AL[128 * 384];    // 96 KB
  __shared__ __align__(16) unsigned short BL[2][128 * 64];  // 2 x 16 KB
  const int tid = (int)threadIdx.x, w = tid >> 6, lane = tid & 63;
  const int la = lane & 15, kh = lane >> 4;
  const int m0 = blockIdx.x * 128;

  {
    const int row = tid >> 2, qq = tid & 3;
    const short8* O8 = (const short8*)(A + (size_t)(m0 + row) * 384);
    #pragma unroll
    for (int i = 0; i < 12; ++i) {
      const int ch = qq + 4 * i;
      *(short8*)((char*)AL + row * 768 + ((ch ^ (row & 7)) << 4)) = O8[ch];
    }
  }

  auto stageB = [&](int buf, int n0, int k0) {
    #pragma unroll
    for (int i = 0; i < 2; ++i) {
      const int Lb = i * 8192 + tid * 16;
      const int row = Lb >> 7;
      const int kcs = ((Lb >> 4) & 7) ^ (row & 7);
      gll16(Bt + (size_t)(n0 + row) * 384 + k0 + kcs * 8, (char*)BL[buf] + Lb);
    }
  };

  stageB(0, 0, 0);
  __syncthreads();

  const int wr = (w >> 2) * 64, wc = (w & 3) * 32;
  int buf = 0;
  for (int nt = 0; nt < 3; ++nt) {
    f32x4 acc[4][2];
    #pragma unroll
    for (int i = 0; i < 4; ++i) { acc[i][0] = f32x4{0.f,0.f,0.f,0.f}; acc[i][1] = f32x4{0.f,0.f,0.f,0.f}; }

    for (int kt = 0; kt < 6; ++kt) {
      if (kt < 5)          stageB(buf ^ 1, nt * 128, (kt + 1) * 64);
      else if (nt + 1 < 3) stageB(buf ^ 1, (nt + 1) * 128, 0);
      #pragma unroll
      for (int kk = 0; kk < 2; ++kk) {
        short8 a[4], bb[2];
        const int chA = kt * 8 + kk * 4 + kh;
        #pragma unroll
        for (int mi = 0; mi < 4; ++mi) {
          const int r = wr + mi * 16 + la;
          a[mi] = *(const short8*)((const char*)AL + r * 768 + ((chA ^ (r & 7)) << 4));
        }
        const int chB = kk * 4 + kh;
        #pragma unroll
        for (int ni = 0; ni < 2; ++ni) {
          const int rB = wc + ni * 16 + la;
          bb[ni] = *(const short8*)((const char*)BL[buf] + rB * 128 + ((chB ^ (rB & 7)) << 4));
        }
        __builtin_amdgcn_s_setprio(1);
        #pragma unroll
        for (int mi = 0; mi < 4; ++mi)
          #pragma unroll
          for (int ni = 0; ni < 2; ++ni)
            acc[mi][ni] = __builtin_amdgcn_mfma_f32_16x16x32_bf16(a[mi], bb[ni], acc[mi][ni], 0, 0, 0);
        __builtin_amdgcn_s_setprio(0);
      }
      __syncthreads();
      buf ^= 1;
    }

    #pragma unroll
    for (int mi = 0; mi < 4; ++mi) {
      const int mbase = m0 + wr + mi * 16 + kh * 4;
      #pragma unroll
      for (int ni = 0; ni < 2; ++ni) {
        const int nl = nt * 128 + wc + ni * 16 + la;
        const float bn = bias[nl];
        #pragma unroll
        for (int j = 0; j < 4; ++j)
          Co[(size_t)(mbase + j) * 384 + nl] = acc[mi][ni][j] + bn;
      }
    }
  }
}

// ================= fallback (fp32) for small ws =================
__global__ __launch_bounds__(256, 1)
void mha_fused(const float* __restrict__ x, const float* __restrict__ Wq,
               const float* __restrict__ Wk, const float* __restrict__ Wv,
               const float* __restrict__ Wp, const float* __restrict__ bp,
               float* __restrict__ out)
{
  const int bh = blockIdx.x;
  const int b = bh / HEADS, h = bh % HEADS;
  const int tid = (int)threadIdx.x;
  const int wave = tid >> 6, lane = tid & 63;
  const float* xb = x + (size_t)b * TT * EMB;
  const float* wq = Wq + (size_t)h * EMB * DH;
  const float* wk = Wk + (size_t)h * EMB * DH;
  const float* wv = Wv + (size_t)h * EMB * DH;
  __shared__ float Ks[TT][68];
  __shared__ float Vs[TT][64];
  __shared__ float Qt[64][68];
  for (int c = 0; c < 4; ++c) {
    const int s0 = wave * 64 + c * 16;
    float ak[16], av[16];
    #pragma unroll
    for (int r = 0; r < 16; ++r) { ak[r] = 0.f; av[r] = 0.f; }
    for (int e = 0; e < EMB; ++e) {
      const float kk = wk[e * DH + lane];
      const float vv = wv[e * DH + lane];
      #pragma unroll
      for (int r = 0; r < 16; ++r) {
        const float xv = xb[(s0 + r) * EMB + e];
        ak[r] += xv * kk; av[r] += xv * vv;
      }
    }
    #pragma unroll
    for (int r = 0; r < 16; ++r) { Ks[s0 + r][lane] = ak[r]; Vs[s0 + r][lane] = av[r]; }
  }
  __syncthreads();
  const int s = tid;
  float kreg[64];
  {
    const float4* k4 = (const float4*)&Ks[s][0];
    #pragma unroll
    for (int i = 0; i < 16; ++i) {
      float4 kv = k4[i];
      kreg[4*i+0] = kv.x; kreg[4*i+1] = kv.y; kreg[4*i+2] = kv.z; kreg[4*i+3] = kv.w;
    }
  }
  float Lsum = 0.f;
  for (int tile = 0; tile < 4; ++tile) {
    {
      const int r0 = tile * 64 + wave * 16;
      float aq[16];
      #pragma unroll
      for (int r = 0; r < 16; ++r) aq[r] = 0.f;
      for (int e = 0; e < EMB; ++e) {
        const float qw = wq[e * DH + lane];
        #pragma unroll
        for (int r = 0; r < 16; ++r) aq[r] += xb[(r0 + r) * EMB + e] * qw;
      }
      __syncthreads();
      #pragma unroll
      for (int r = 0; r < 16; ++r) Qt[wave*16 + r][lane] = aq[r];
      __syncthreads();
    }
    const int tbase = tile * 64;
    if (tbase + 63 >= s) {
      for (int tr = 0; tr < 64; ++tr) {
        const int t = tbase + tr;
        if (t < s) continue;
        float w = 0.f;
        const float4* q4 = (const float4*)&Qt[tr][0];
        #pragma unroll
        for (int i = 0; i < 16; ++i) {
          float4 qv = q4[i];
          w += qv.x*kreg[4*i+0] + qv.y*kreg[4*i+1] + qv.z*kreg[4*i+2] + qv.w*kreg[4*i+3];
        }
        Lsum += __expf(w * SCALE);
      }
    }
  }
  __syncthreads();
  {
    const float invL = 1.0f / Lsum;
    float4* v4 = (float4*)&Vs[s][0];
    #pragma unroll
    for (int i = 0; i < 16; ++i) {
      float4 vv = v4[i];
      vv.x *= invL; vv.y *= invL; vv.z *= invL; vv.w *= invL;
      v4[i] = vv;
    }
  }
  __syncthreads();
  const float bias1 = bp[tid];
  const float bias2 = (tid < 128) ? bp[256 + tid] : 0.f;
  const int tr = tid >> 2, dq = tid & 3;
  float* ob = out + (size_t)b * TT * EMB;
  for (int tile = 0; tile < 4; ++tile) {
    {
      const int r0 = tile * 64 + wave * 16;
      float aq[16];
      #pragma unroll
      for (int r = 0; r < 16; ++r) aq[r] = 0.f;
      for (int e = 0; e < EMB; ++e) {
        const float qw = wq[e * DH + lane];
        #pragma unroll
        for (int r = 0; r < 16; ++r) aq[r] += xb[(r0 + r) * EMB + e] * qw;
      }
      __syncthreads();
      #pragma unroll
      for (int r = 0; r < 16; ++r) Qt[wave*16 + r][lane] = aq[r];
      __syncthreads();
    }
    const int t = tile * 64 + tr;
    float qreg[16];
    {
      const float4* q4 = (const float4*)&Qt[tr][dq * 16];
      #pragma unroll
      for (int i = 0; i < 4; ++i) {
        float4 qv = q4[i];
        qreg[4*i+0] = qv.x; qreg[4*i+1] = qv.y; qreg[4*i+2] = qv.z; qreg[4*i+3] = qv.w;
      }
    }
    float acc[16];
    #pragma unroll
    for (int i = 0; i < 16; ++i) acc[i] = 0.f;
    for (int s2 = 0; s2 <= t; ++s2) {
      const float4* kk4 = (const float4*)&Ks[s2][dq * 16];
      float part = 0.f;
      #pragma unroll
      for (int i = 0; i < 4; ++i) {
        float4 kv = kk4[i];
        part += qreg[4*i+0]*kv.x + qreg[4*i+1]*kv.y + qreg[4*i+2]*kv.z + qreg[4*i+3]*kv.w;
      }
      part += __shfl_xor(part, 1);
      part += __shfl_xor(part, 2);
      const float p = __expf(part * SCALE);
      const float4* vv4 = (const float4*)&Vs[s2][dq * 16];
      #pragma unroll
      for (int i = 0; i < 4; ++i) {
        float4 vv = vv4[i];
        acc[4*i+0] += p * vv.x; acc[4*i+1] += p * vv.y;
        acc[4*i+2] += p * vv.z; acc[4*i+3] += p * vv.w;
      }
    }
    __syncthreads();
    #pragma unroll
    for (int i = 0; i < 16; ++i) Qt[tr][dq*16 + i] = acc[i];
    __syncthreads();
    const int c1 = tid;
    const int c2 = 256 + tid;
    for (int rg = 0; rg < 4; ++rg) {
      float a1[16], a2[16];
      #pragma unroll
      for (int r = 0; r < 16; ++r) { a1[r] = 0.f; a2[r] = 0.f; }
      for (int d = 0; d < 64; ++d) {
        const float wp1 = Wp[(size_t)(h*64 + d) * EMB + c1];
        const float wp2 = (tid < 128) ? Wp[(size_t)(h*64 + d) * EMB + c2] : 0.f;
        #pragma unroll
        for (int r = 0; r < 16; ++r) {
          const float a = Qt[rg*16 + r][d];
          a1[r] += a * wp1; a2[r] += a * wp2;
        }
      }
      if (h == 0) {
        #pragma unroll
        for (int r = 0; r < 16; ++r) { a1[r] += bias1; a2[r] += bias2; }
      }
      const int trow0 = tile*64 + rg*16;
      #pragma unroll
      for (int r = 0; r < 16; ++r)
        atomicAdd(&ob[(size_t)(trow0 + r) * EMB + c1], a1[r]);
      if (tid < 128) {
        #pragma unroll
        for (int r = 0; r < 16; ++r)
          atomicAdd(&ob[(size_t)(trow0 + r) * EMB + c2], a2[r]);
      }
    }
    __syncthreads();
  }
}

extern "C" void kernel_launch(void* const* d_in, const int* in_sizes, int n_in,
                              void* d_out, int out_size, void* d_ws, size_t ws_size,
                              hipStream_t stream) {
  const float* x  = (const float*)d_in[0];
  const float* Wq = (const float*)d_in[1];
  const float* Wk = (const float*)d_in[2];
  const float* Wv = (const float*)d_in[3];
  const float* Wp = (const float*)d_in[4];
  const float* bp = (const float*)d_in[5];

  const int nb = in_sizes[0] / (TT * EMB);       // batch (128)
  const size_t M = (size_t)nb * TT;              // 32768 rows
  const size_t XB = M * EMB * 2;                 // bf16 activation bytes (25 MB)
  const size_t WT = (size_t)1536 * 384 * 2;

  const size_t off_x  = 0;
  const size_t off_wt = XB;
  const size_t off_o  = off_wt + WT;
  const size_t need   = off_o + XB;

  if (ws_size < need || nb * HEADS != 768) {
    hipMemsetAsync(d_out, 0, (size_t)out_size * sizeof(float), stream);
    mha_fused<<<nb * HEADS, 256, 0, stream>>>(x, Wq, Wk, Wv, Wp, bp, (float*)d_out);
    return;
  }

  char* ws = (char*)d_ws;
  unsigned short* xb16 = (unsigned short*)(ws + off_x);
  unsigned short* Wt   = (unsigned short*)(ws + off_wt);
  unsigned short* Ow   = (unsigned short*)(ws + off_o);

  const int n8 = (int)(M * EMB / 8);
  cvt_x<<<(n8 + 255) / 256, 256, 0, stream>>>(x, xb16, n8);
  build_wt<<<288, 256, 0, stream>>>(Wq, Wk, Wv, Wp, Wt);

  qkv_attn<<<nb * HEADS, 1024, 0, stream>>>(xb16, Wt, Ow);

  proj_gemm<<<(unsigned)(M / 128), 512, 0, stream>>>(
      Ow, Wt + (size_t)1152 * 384, (float*)d_out, bp);
}

// Round 14
// 103.627 us; speedup vs baseline: 1.3983x; 1.0248x over previous
//
#include <hip/hip_runtime.h>

#define EMB 384
#define HEADS 6
#define DH 64
#define TT 256

constexpr float SCALE = 0.05103103630798288f;  // 384^-0.5

typedef __attribute__((ext_vector_type(8))) short short8;
typedef __attribute__((ext_vector_type(4))) float f32x4;
typedef __attribute__((ext_vector_type(4))) unsigned short u16x4;

__device__ __forceinline__ unsigned short f2bf(float f) {
  unsigned int u = __builtin_bit_cast(unsigned int, f);
  u += 0x7FFFu + ((u >> 16) & 1u);   // RNE
  return (unsigned short)(u >> 16);
}
__device__ __forceinline__ float bf2f(unsigned short u) {
  unsigned int v = ((unsigned int)u) << 16;
  return __builtin_bit_cast(float, v);
}
__device__ __forceinline__ void gll16(const void* g, void* l) {
  __builtin_amdgcn_global_load_lds(
      (const __attribute__((address_space(1))) unsigned int*)g,
      (__attribute__((address_space(3))) unsigned int*)l, 16, 0, 0);
}

// ---- K0: build Wt[1536][384] bf16. Rows 0..1151: per-HEAD blocks of 192
// (q d0-63 | k d0-63 | v d0-63); rows 1152..1535: proj^T. ----
__global__ __launch_bounds__(256)
void build_wt(const float* __restrict__ Wq, const float* __restrict__ Wk,
              const float* __restrict__ Wv, const float* __restrict__ Wp,
              unsigned short* __restrict__ Wt) {
  int idx = blockIdx.x * 256 + threadIdx.x;  // 1536*48 = 73728
  int n = idx / 48, e0 = (idx % 48) * 8;
  const float* src; int stride;
  if (n < 1152) {
    int h = n / 192, rem = n % 192, qkv = rem >> 6, d = rem & 63;
    const float* W = (qkv == 0) ? Wq : (qkv == 1) ? Wk : Wv;
    src = W + ((size_t)h * EMB + e0) * DH + d; stride = DH;
  } else {
    int c = n - 1152;
    src = Wp + (size_t)e0 * EMB + c; stride = EMB;
  }
  short8 o;
  #pragma unroll
  for (int j = 0; j < 8; ++j) o[j] = (short)f2bf(src[j * stride]);
  ((short8*)Wt)[idx] = o;
}

// ================= fused QKV-GEMM + attention, one block per (b,h) =================
// 1024 thr / 16 waves. A = x fp32 converted IN-STAGE (reg loads issued at step top,
// cvt+ds_write after compute -> latency hidden). Double-buffered (buf1 = KL/VL).
// XCD swizzle keeps each 96-bh chunk's x-panels L2-resident. PV big tiles spread
// across SIMDs via bigw = 2p + ((p>>1)&1).
__global__ __launch_bounds__(1024, 1)
void qkv_attn(const float* __restrict__ x, const unsigned short* __restrict__ Wt,
              unsigned short* __restrict__ O)
{
  __shared__ __align__(16) char EL[73728];   // GEMM buf0: A0(32K)+B0(24K); then Qtmp; then E
  __shared__ __align__(16) char KL[32768];   // GEMM buf1 A1; then K [256][64] swizzled
  __shared__ __align__(16) char VL[32768];   // GEMM buf1 B1 (24K); then V^T [64][256] swizzled
  __shared__ float Lpart[16][256];
  __shared__ float invL[256];

  const int bhRaw = blockIdx.x, tid = (int)threadIdx.x;
  const int bh = (bhRaw & 7) * 96 + (bhRaw >> 3);   // 768 = 8*96: bijective XCD swizzle
  const int w = tid >> 6, lane = tid & 63;
  const int la = lane & 15, kh = lane >> 4;
  const int b = bh / 6, h = bh - b * 6;
  const float* xf = x + (size_t)b * 256 * 384;
  const unsigned short* Wb = Wt + (size_t)h * 192 * 384;
  char* A0 = EL;            // 32 KB
  char* B0 = EL + 32768;    // 24 KB
  char* A1 = KL;            // 32 KB (scratch during GEMM)
  char* B1 = VL;            // 24 KB of 32 KB (scratch during GEMM)

  // ---------------- QKV GEMM: wave tile 64 x 48, double-buffered ----------------
  const int wr = (w >> 2) * 64, wc = (w & 3) * 48;
  f32x4 acc[4][3];
  #pragma unroll
  for (int i = 0; i < 4; ++i)
    #pragma unroll
    for (int j = 0; j < 3; ++j) acc[i][j] = f32x4{0.f, 0.f, 0.f, 0.f};

  // A reg-staging: 4 threads/row, thread covers chunks {aqq, aqq+4} (8 fp32 each)
  const int arow = tid >> 2, aqq = tid & 3;
  const float4* xfr = (const float4*)(xf + (size_t)arow * 384);

  float4 ra[4];
  auto loadA = [&](int kt) {
    const int base = kt * 16;              // float4 units (64 floats / step)
    #pragma unroll
    for (int i = 0; i < 2; ++i) {
      const int ch = aqq + 4 * i;
      ra[2*i]   = xfr[base + ch * 2];
      ra[2*i+1] = xfr[base + ch * 2 + 1];
    }
  };
  auto writeA = [&](char* A) {
    #pragma unroll
    for (int i = 0; i < 2; ++i) {
      const int ch = aqq + 4 * i;
      float4 va = ra[2*i], vb = ra[2*i+1];
      short8 o;
      o[0] = (short)f2bf(va.x); o[1] = (short)f2bf(va.y);
      o[2] = (short)f2bf(va.z); o[3] = (short)f2bf(va.w);
      o[4] = (short)f2bf(vb.x); o[5] = (short)f2bf(vb.y);
      o[6] = (short)f2bf(vb.z); o[7] = (short)f2bf(vb.w);
      *(short8*)(A + arow * 128 + ((ch ^ (arow & 7)) << 4)) = o;
    }
  };
  auto stageB = [&](char* B, int kt) {     // gll16, [192][64] bf16, 24KB
    const int Lb0 = tid * 16;
    const int row0 = Lb0 >> 7;
    const int kcs0 = ((Lb0 >> 4) & 7) ^ (row0 & 7);
    gll16(Wb + (size_t)row0 * 384 + kt * 64 + kcs0 * 8, B + Lb0);
    if (tid < 512) {
      const int Lb = 16384 + tid * 16;
      const int row = Lb >> 7;
      const int kcs = ((Lb >> 4) & 7) ^ (row & 7);
      gll16(Wb + (size_t)row * 384 + kt * 64 + kcs * 8, B + Lb);
    }
  };

  auto compute = [&](const char* A, const char* B) {
    #pragma unroll
    for (int kk = 0; kk < 2; ++kk) {
      const int ch = kk * 4 + kh;
      short8 a[4], bfr[3];
      #pragma unroll
      for (int mi = 0; mi < 4; ++mi) {
        const int r = wr + mi * 16 + la;
        a[mi] = *(const short8*)(A + r * 128 + ((ch ^ (r & 7)) << 4));
      }
      #pragma unroll
      for (int ni = 0; ni < 3; ++ni) {
        const int rB = wc + ni * 16 + la;
        bfr[ni] = *(const short8*)(B + rB * 128 + ((ch ^ (rB & 7)) << 4));
      }
      __builtin_amdgcn_s_setprio(1);
      #pragma unroll
      for (int mi = 0; mi < 4; ++mi)
        #pragma unroll
        for (int ni = 0; ni < 3; ++ni)
          acc[mi][ni] = __builtin_amdgcn_mfma_f32_16x16x32_bf16(a[mi], bfr[ni], acc[mi][ni], 0, 0, 0);
      __builtin_amdgcn_s_setprio(0);
    }
  };

  loadA(0);
  writeA(A0);
  stageB(B0, 0);
  __syncthreads();                       // buf0 ready (A lgkm + B vmcnt)
  #pragma unroll
  for (int g = 0; g < 3; ++g) {
    const int k1 = 2 * g + 1;
    loadA(k1);                           // issue early: hides under compute
    stageB(B1, k1);
    compute(A0, B0);
    writeA(A1);                          // loads have landed by now
    __syncthreads();                     // buf1 ready; buf0 readers done
    if (k1 + 1 < 6) { loadA(k1 + 1); stageB(B0, k1 + 1); }
    compute(A1, B1);
    if (k1 + 1 < 6) writeA(A0);
    __syncthreads();                     // buf0 ready; buf1 readers done
  }

  // ---- epilogue: Q -> Qtmp (EL, [256][64] swizzled), K -> KL, V^T -> VL ----
  #pragma unroll
  for (int mi = 0; mi < 4; ++mi) {
    #pragma unroll
    for (int ni = 0; ni < 3; ++ni) {
      const int col = wc + ni * 16 + la;
      const int tb = wr + mi * 16 + kh * 4;
      if (col < 64) {
        const int d = col;
        #pragma unroll
        for (int j = 0; j < 4; ++j) {
          const int t = tb + j;
          *(unsigned short*)(EL + t * 128 + (((d >> 3) ^ (t & 7)) << 4) + (d & 7) * 2)
              = f2bf(acc[mi][ni][j]);
        }
      } else if (col < 128) {
        const int d = col - 64;
        #pragma unroll
        for (int j = 0; j < 4; ++j) {
          const int t = tb + j;
          *(unsigned short*)(KL + t * 128 + (((d >> 3) ^ (t & 7)) << 4) + (d & 7) * 2)
              = f2bf(acc[mi][ni][j]);
        }
      } else {
        const int d = col - 128;
        u16x4 pk;
        #pragma unroll
        for (int j = 0; j < 4; ++j) pk[j] = f2bf(acc[mi][ni][j]);
        *(u16x4*)(VL + d * 512 + (((tb >> 3) ^ (d & 7)) << 4) + (tb & 7) * 2) = pk;
      }
    }
  }
  __syncthreads();

  // ---- hoist Q fragments for this wave's PAIR {p, 15-p}, p = w>>1 ----
  const int p = w >> 1;
  const int rts[2] = { p, 15 - p };
  short8 qa[2][2];
  #pragma unroll
  for (int ti = 0; ti < 2; ++ti)
    #pragma unroll
    for (int kk = 0; kk < 2; ++kk) {
      const int r = rts[ti] * 16 + la;
      const int ch = kk * 4 + kh;
      qa[ti][kk] = *(const short8*)(EL + r * 128 + ((ch ^ (r & 7)) << 4));
    }
  __syncthreads();   // EL now free for E strips

  int wps[2], eoffs[2];
  #pragma unroll
  for (int ti = 0; ti < 2; ++ti) {
    const int rt = rts[ti];
    wps[ti] = 32 * ((rt + 2) >> 1);
    const int S = (rt & 1) ? ((rt + 1) * (rt + 1) / 4) : (rt * (rt + 2) / 4);
    eoffs[ti] = 1024 * S;
  }

  // ---- zero own Lpart row (wave-local) ----
  #pragma unroll
  for (int i = 0; i < 4; ++i) Lpart[w][i * 64 + lane] = 0.f;

  // ---- QK^T + masked exp -> E strips; ns-parity split across the pair's waves ----
  #pragma unroll
  for (int ti = 0; ti < 2; ++ti) {
    const int rt = rts[ti], wp = wps[ti], stride = wp * 2;
    char* Ebase = EL + eoffs[ti];
    const int nns = wp >> 4;
    for (int ns = (w & 1); ns < nns; ns += 2) {
      f32x4 s4 = f32x4{0.f, 0.f, 0.f, 0.f};
      #pragma unroll
      for (int kk = 0; kk < 2; ++kk) {
        const int rB = ns * 16 + la, kc = kk * 4 + kh;
        short8 bf = *(const short8*)(KL + rB * 128 + ((kc ^ (rB & 7)) << 4));
        s4 = __builtin_amdgcn_mfma_f32_16x16x32_bf16(qa[ti][kk], bf, s4, 0, 0, 0);
      }
      const int c = ns * 16 + la, cc = c >> 3, co = (c & 7) * 2;
      float ps = 0.f;
      #pragma unroll
      for (int j = 0; j < 4; ++j) {
        const int r = kh * 4 + j;
        const int t = rt * 16 + r;
        const float e = (t >= c) ? __expf(s4[j] * SCALE) : 0.f;
        ps += e;
        *(unsigned short*)(Ebase + r * stride + ((cc ^ (r & 3)) << 4) + co) = f2bf(e);
      }
      ps += __shfl_xor(ps, 16);
      ps += __shfl_xor(ps, 32);        // 16-row tile-column sum in all kh lanes
      if (kh == 0) Lpart[w][c] += ps;  // wave-local row: no race
    }
  }
  __syncthreads();

  if (tid < 256) {
    float Ls = 0.f;
    #pragma unroll
    for (int ww = 0; ww < 16; ++ww) Ls += Lpart[ww][tid];
    invL[tid] = 1.f / Ls;
  }
  __syncthreads();

  // ---- fold 1/L_s into V (1024 threads: 2 chunks each) ----
  {
    const int d = tid >> 4, qq = tid & 15;
    #pragma unroll
    for (int i = 0; i < 2; ++i) {
      const int kcp = qq * 2 + i;
      char* pch = VL + d * 512 + kcp * 16;
      short8 v = *(short8*)pch;
      const int sb = (kcp ^ (d & 7)) * 8;
      short8 o;
      #pragma unroll
      for (int e = 0; e < 8; ++e)
        o[e] = (short)f2bf(bf2f((unsigned short)v[e]) * invL[sb + e]);
      *(short8*)pch = o;
    }
  }
  __syncthreads();

  // ---- O = E * V': big tile to wave bigw = 2p + ((p>>1)&1) (SIMD-balanced) ----
  unsigned short* Og = O + (size_t)b * 256 * 384 + h * 64;
  {
    const int bigw = 2 * p + ((p >> 1) & 1);
    const int ti = (w == bigw) ? 1 : 0;
    const int rt = rts[ti], wp = wps[ti], stride = wp * 2;
    const char* Ebase = EL + eoffs[ti];
    f32x4 oacc[4];
    #pragma unroll
    for (int nd = 0; nd < 4; ++nd) oacc[nd] = f32x4{0.f, 0.f, 0.f, 0.f};
    const int nks = wp >> 5;
    for (int ks = 0; ks < nks; ++ks) {
      const int cc = ks * 4 + kh;
      short8 ea = *(const short8*)(Ebase + la * stride + ((cc ^ (la & 3)) << 4));
      __builtin_amdgcn_s_setprio(1);
      #pragma unroll
      for (int nd = 0; nd < 4; ++nd) {
        const int d = nd * 16 + la;
        short8 vb = *(const short8*)(VL + d * 512 + ((cc ^ (d & 7)) << 4));
        oacc[nd] = __builtin_amdgcn_mfma_f32_16x16x32_bf16(ea, vb, oacc[nd], 0, 0, 0);
      }
      __builtin_amdgcn_s_setprio(0);
    }
    #pragma unroll
    for (int nd = 0; nd < 4; ++nd) {
      const int d = nd * 16 + la;
      #pragma unroll
      for (int j = 0; j < 4; ++j) {
        const int t = rt * 16 + kh * 4 + j;
        Og[(size_t)t * 384 + d] = f2bf(oacc[nd][j]);
      }
    }
  }
}

// ---------------- proj GEMM: out = O * proj + bias ----------------
__global__ __launch_bounds__(512, 1)
void proj_gemm(const unsigned short* __restrict__ A, const unsigned short* __restrict__ Bt,
               float* __restrict__ Co, const float* __restrict__ bias)
{
  __shared__ __align__(16) unsigned short AL[128 * 384];    // 96 KB
  __shared__ __align__(16) unsigned short BL[2][128 * 64];  // 2 x 16 KB
  const int tid = (int)threadIdx.x, w = tid >> 6, lane = tid & 63;
  const int la = lane & 15, kh = lane >> 4;
  const int m0 = blockIdx.x * 128;

  {
    const int row = tid >> 2, qq = tid & 3;
    const short8* O8 = (const short8*)(A + (size_t)(m0 + row) * 384);
    #pragma unroll
    for (int i = 0; i < 12; ++i) {
      const int ch = qq + 4 * i;
      *(short8*)((char*)AL + row * 768 + ((ch ^ (row & 7)) << 4)) = O8[ch];
    }
  }

  auto stageB = [&](int buf, int n0, int k0) {
    #pragma unroll
    for (int i = 0; i < 2; ++i) {
      const int Lb = i * 8192 + tid * 16;
      const int row = Lb >> 7;
      const int kcs = ((Lb >> 4) & 7) ^ (row & 7);
      gll16(Bt + (size_t)(n0 + row) * 384 + k0 + kcs * 8, (char*)BL[buf] + Lb);
    }
  };

  stageB(0, 0, 0);
  __syncthreads();

  const int wr = (w >> 2) * 64, wc = (w & 3) * 32;
  int buf = 0;
  for (int nt = 0; nt < 3; ++nt) {
    f32x4 acc[4][2];
    #pragma unroll
    for (int i = 0; i < 4; ++i) { acc[i][0] = f32x4{0.f,0.f,0.f,0.f}; acc[i][1] = f32x4{0.f,0.f,0.f,0.f}; }

    for (int kt = 0; kt < 6; ++kt) {
      if (kt < 5)          stageB(buf ^ 1, nt * 128, (kt + 1) * 64);
      else if (nt + 1 < 3) stageB(buf ^ 1, (nt + 1) * 128, 0);
      #pragma unroll
      for (int kk = 0; kk < 2; ++kk) {
        short8 a[4], bb[2];
        const int chA = kt * 8 + kk * 4 + kh;
        #pragma unroll
        for (int mi = 0; mi < 4; ++mi) {
          const int r = wr + mi * 16 + la;
          a[mi] = *(const short8*)((const char*)AL + r * 768 + ((chA ^ (r & 7)) << 4));
        }
        const int chB = kk * 4 + kh;
        #pragma unroll
        for (int ni = 0; ni < 2; ++ni) {
          const int rB = wc + ni * 16 + la;
          bb[ni] = *(const short8*)((const char*)BL[buf] + rB * 128 + ((chB ^ (rB & 7)) << 4));
        }
        __builtin_amdgcn_s_setprio(1);
        #pragma unroll
        for (int mi = 0; mi < 4; ++mi)
          #pragma unroll
          for (int ni = 0; ni < 2; ++ni)
            acc[mi][ni] = __builtin_amdgcn_mfma_f32_16x16x32_bf16(a[mi], bb[ni], acc[mi][ni], 0, 0, 0);
        __builtin_amdgcn_s_setprio(0);
      }
      __syncthreads();
      buf ^= 1;
    }

    #pragma unroll
    for (int mi = 0; mi < 4; ++mi) {
      const int mbase = m0 + wr + mi * 16 + kh * 4;
      #pragma unroll
      for (int ni = 0; ni < 2; ++ni) {
        const int nl = nt * 128 + wc + ni * 16 + la;
        const float bn = bias[nl];
        #pragma unroll
        for (int j = 0; j < 4; ++j)
          Co[(size_t)(mbase + j) * 384 + nl] = acc[mi][ni][j] + bn;
      }
    }
  }
}

// ================= fallback (fp32) for small ws =================
__global__ __launch_bounds__(256, 1)
void mha_fused(const float* __restrict__ x, const float* __restrict__ Wq,
               const float* __restrict__ Wk, const float* __restrict__ Wv,
               const float* __restrict__ Wp, const float* __restrict__ bp,
               float* __restrict__ out)
{
  const int bh = blockIdx.x;
  const int b = bh / HEADS, h = bh % HEADS;
  const int tid = (int)threadIdx.x;
  const int wave = tid >> 6, lane = tid & 63;
  const float* xb = x + (size_t)b * TT * EMB;
  const float* wq = Wq + (size_t)h * EMB * DH;
  const float* wk = Wk + (size_t)h * EMB * DH;
  const float* wv = Wv + (size_t)h * EMB * DH;
  __shared__ float Ks[TT][68];
  __shared__ float Vs[TT][64];
  __shared__ float Qt[64][68];
  for (int c = 0; c < 4; ++c) {
    const int s0 = wave * 64 + c * 16;
    float ak[16], av[16];
    #pragma unroll
    for (int r = 0; r < 16; ++r) { ak[r] = 0.f; av[r] = 0.f; }
    for (int e = 0; e < EMB; ++e) {
      const float kk = wk[e * DH + lane];
      const float vv = wv[e * DH + lane];
      #pragma unroll
      for (int r = 0; r < 16; ++r) {
        const float xv = xb[(s0 + r) * EMB + e];
        ak[r] += xv * kk; av[r] += xv * vv;
      }
    }
    #pragma unroll
    for (int r = 0; r < 16; ++r) { Ks[s0 + r][lane] = ak[r]; Vs[s0 + r][lane] = av[r]; }
  }
  __syncthreads();
  const int s = tid;
  float kreg[64];
  {
    const float4* k4 = (const float4*)&Ks[s][0];
    #pragma unroll
    for (int i = 0; i < 16; ++i) {
      float4 kv = k4[i];
      kreg[4*i+0] = kv.x; kreg[4*i+1] = kv.y; kreg[4*i+2] = kv.z; kreg[4*i+3] = kv.w;
    }
  }
  float Lsum = 0.f;
  for (int tile = 0; tile < 4; ++tile) {
    {
      const int r0 = tile * 64 + wave * 16;
      float aq[16];
      #pragma unroll
      for (int r = 0; r < 16; ++r) aq[r] = 0.f;
      for (int e = 0; e < EMB; ++e) {
        const float qw = wq[e * DH + lane];
        #pragma unroll
        for (int r = 0; r < 16; ++r) aq[r] += xb[(r0 + r) * EMB + e] * qw;
      }
      __syncthreads();
      #pragma unroll
      for (int r = 0; r < 16; ++r) Qt[wave*16 + r][lane] = aq[r];
      __syncthreads();
    }
    const int tbase = tile * 64;
    if (tbase + 63 >= s) {
      for (int tr = 0; tr < 64; ++tr) {
        const int t = tbase + tr;
        if (t < s) continue;
        float w = 0.f;
        const float4* q4 = (const float4*)&Qt[tr][0];
        #pragma unroll
        for (int i = 0; i < 16; ++i) {
          float4 qv = q4[i];
          w += qv.x*kreg[4*i+0] + qv.y*kreg[4*i+1] + qv.z*kreg[4*i+2] + qv.w*kreg[4*i+3];
        }
        Lsum += __expf(w * SCALE);
      }
    }
  }
  __syncthreads();
  {
    const float invL = 1.0f / Lsum;
    float4* v4 = (float4*)&Vs[s][0];
    #pragma unroll
    for (int i = 0; i < 16; ++i) {
      float4 vv = v4[i];
      vv.x *= invL; vv.y *= invL; vv.z *= invL; vv.w *= invL;
      v4[i] = vv;
    }
  }
  __syncthreads();
  const float bias1 = bp[tid];
  const float bias2 = (tid < 128) ? bp[256 + tid] : 0.f;
  const int tr = tid >> 2, dq = tid & 3;
  float* ob = out + (size_t)b * TT * EMB;
  for (int tile = 0; tile < 4; ++tile) {
    {
      const int r0 = tile * 64 + wave * 16;
      float aq[16];
      #pragma unroll
      for (int r = 0; r < 16; ++r) aq[r] = 0.f;
      for (int e = 0; e < EMB; ++e) {
        const float qw = wq[e * DH + lane];
        #pragma unroll
        for (int r = 0; r < 16; ++r) aq[r] += xb[(r0 + r) * EMB + e] * qw;
      }
      __syncthreads();
      #pragma unroll
      for (int r = 0; r < 16; ++r) Qt[wave*16 + r][lane] = aq[r];
      __syncthreads();
    }
    const int t = tile * 64 + tr;
    float qreg[16];
    {
      const float4* q4 = (const float4*)&Qt[tr][dq * 16];
      #pragma unroll
      for (int i = 0; i < 4; ++i) {
        float4 qv = q4[i];
        qreg[4*i+0] = qv.x; qreg[4*i+1] = qv.y; qreg[4*i+2] = qv.z; qreg[4*i+3] = qv.w;
      }
    }
    float acc[16];
    #pragma unroll
    for (int i = 0; i < 16; ++i) acc[i] = 0.f;
    for (int s2 = 0; s2 <= t; ++s2) {
      const float4* kk4 = (const float4*)&Ks[s2][dq * 16];
      float part = 0.f;
      #pragma unroll
      for (int i = 0; i < 4; ++i) {
        float4 kv = kk4[i];
        part += qreg[4*i+0]*kv.x + qreg[4*i+1]*kv.y + qreg[4*i+2]*kv.z + qreg[4*i+3]*kv.w;
      }
      part += __shfl_xor(part, 1);
      part += __shfl_xor(part, 2);
      const float p = __expf(part * SCALE);
      const float4* vv4 = (const float4*)&Vs[s2][dq * 16];
      #pragma unroll
      for (int i = 0; i < 4; ++i) {
        float4 vv = vv4[i];
        acc[4*i+0] += p * vv.x; acc[4*i+1] += p * vv.y;
        acc[4*i+2] += p * vv.z; acc[4*i+3] += p * vv.w;
      }
    }
    __syncthreads();
    #pragma unroll
    for (int i = 0; i < 16; ++i) Qt[tr][dq*16 + i] = acc[i];
    __syncthreads();
    const int c1 = tid;
    const int c2 = 256 + tid;
    for (int rg = 0; rg < 4; ++rg) {
      float a1[16], a2[16];
      #pragma unroll
      for (int r = 0; r < 16; ++r) { a1[r] = 0.f; a2[r] = 0.f; }
      for (int d = 0; d < 64; ++d) {
        const float wp1 = Wp[(size_t)(h*64 + d) * EMB + c1];
        const float wp2 = (tid < 128) ? Wp[(size_t)(h*64 + d) * EMB + c2] : 0.f;
        #pragma unroll
        for (int r = 0; r < 16; ++r) {
          const float a = Qt[rg*16 + r][d];
          a1[r] += a * wp1; a2[r] += a * wp2;
        }
      }
      if (h == 0) {
        #pragma unroll
        for (int r = 0; r < 16; ++r) { a1[r] += bias1; a2[r] += bias2; }
      }
      const int trow0 = tile*64 + rg*16;
      #pragma unroll
      for (int r = 0; r < 16; ++r)
        atomicAdd(&ob[(size_t)(trow0 + r) * EMB + c1], a1[r]);
      if (tid < 128) {
        #pragma unroll
        for (int r = 0; r < 16; ++r)
          atomicAdd(&ob[(size_t)(trow0 + r) * EMB + c2], a2[r]);
      }
    }
    __syncthreads();
  }
}

extern "C" void kernel_launch(void* const* d_in, const int* in_sizes, int n_in,
                              void* d_out, int out_size, void* d_ws, size_t ws_size,
                              hipStream_t stream) {
  const float* x  = (const float*)d_in[0];
  const float* Wq = (const float*)d_in[1];
  const float* Wk = (const float*)d_in[2];
  const float* Wv = (const float*)d_in[3];
  const float* Wp = (const float*)d_in[4];
  const float* bp = (const float*)d_in[5];

  const int nb = in_sizes[0] / (TT * EMB);       // batch (128)
  const size_t M = (size_t)nb * TT;              // 32768 rows
  const size_t XB = M * EMB * 2;                 // bf16 activation bytes (25 MB)
  const size_t WT = (size_t)1536 * 384 * 2;

  const size_t off_wt = 0;
  const size_t off_o  = off_wt + WT;
  const size_t need   = off_o + XB;

  if (ws_size < need || nb * HEADS != 768) {
    hipMemsetAsync(d_out, 0, (size_t)out_size * sizeof(float), stream);
    mha_fused<<<nb * HEADS, 256, 0, stream>>>(x, Wq, Wk, Wv, Wp, bp, (float*)d_out);
    return;
  }

  char* ws = (char*)d_ws;
  unsigned short* Wt = (unsigned short*)(ws + off_wt);
  unsigned short* Ow = (unsigned short*)(ws + off_o);

  build_wt<<<288, 256, 0, stream>>>(Wq, Wk, Wv, Wp, Wt);

  qkv_attn<<<nb * HEADS, 1024, 0, stream>>>(x, Wt, Ow);

  proj_gemm<<<(unsigned)(M / 128), 512, 0, stream>>>(
      Ow, Wt + (size_t)1152 * 384, (float*)d_out, bp);
}

// Round 15
// 100.428 us; speedup vs baseline: 1.4429x; 1.0319x over previous
//
#include <hip/hip_runtime.h>

#define EMB 384
#define HEADS 6
#define DH 64
#define TT 256

constexpr float SCALE = 0.05103103630798288f;  // 384^-0.5

typedef __attribute__((ext_vector_type(8))) short short8;
typedef __attribute__((ext_vector_type(4))) float f32x4;
typedef __attribute__((ext_vector_type(4))) unsigned short u16x4;

__device__ __forceinline__ unsigned short f2bf(float f) {
  unsigned int u = __builtin_bit_cast(unsigned int, f);
  u += 0x7FFFu + ((u >> 16) & 1u);   // RNE
  return (unsigned short)(u >> 16);
}
__device__ __forceinline__ float bf2f(unsigned short u) {
  unsigned int v = ((unsigned int)u) << 16;
  return __builtin_bit_cast(float, v);
}
__device__ __forceinline__ void gll16(const void* g, void* l) {
  __builtin_amdgcn_global_load_lds(
      (const __attribute__((address_space(1))) unsigned int*)g,
      (__attribute__((address_space(3))) unsigned int*)l, 16, 0, 0);
}

// ---- K0: build Wt[1536][384] bf16. Rows 0..1151: per-HEAD blocks of 192
// (q d0-63 | k d0-63 | v d0-63); rows 1152..1535: proj^T. ----
__global__ __launch_bounds__(256)
void build_wt(const float* __restrict__ Wq, const float* __restrict__ Wk,
              const float* __restrict__ Wv, const float* __restrict__ Wp,
              unsigned short* __restrict__ Wt) {
  int idx = blockIdx.x * 256 + threadIdx.x;  // 1536*48 = 73728
  int n = idx / 48, e0 = (idx % 48) * 8;
  const float* src; int stride;
  if (n < 1152) {
    int h = n / 192, rem = n % 192, qkv = rem >> 6, d = rem & 63;
    const float* W = (qkv == 0) ? Wq : (qkv == 1) ? Wk : Wv;
    src = W + ((size_t)h * EMB + e0) * DH + d; stride = DH;
  } else {
    int c = n - 1152;
    src = Wp + (size_t)e0 * EMB + c; stride = EMB;
  }
  short8 o;
  #pragma unroll
  for (int j = 0; j < 8; ++j) o[j] = (short)f2bf(src[j * stride]);
  ((short8*)Wt)[idx] = o;
}

// ================= fused QKV-GEMM + attention, one block per (b,h) =================
// 1024 thr / 16 waves. A = x fp32 converted in-stage with TWO reg sets:
// step k issues loadA(k+2), writes the set loaded at k-1 (landed -> no wait),
// then computes. B via gll16 double-buffer. XCD swizzle for x L2/L3 locality.
__global__ __launch_bounds__(1024, 1)
void qkv_attn(const float* __restrict__ x, const unsigned short* __restrict__ Wt,
              unsigned short* __restrict__ O)
{
  __shared__ __align__(16) char EL[73728];   // GEMM buf0: A0(32K)+B0(24K); then Qtmp; then E
  __shared__ __align__(16) char KL[32768];   // GEMM buf1 A1; then K [256][64] swizzled
  __shared__ __align__(16) char VL[32768];   // GEMM buf1 B1 (24K); then V^T [64][256] swizzled
  __shared__ float Lpart[16][256];
  __shared__ float invL[256];

  const int bhRaw = blockIdx.x, tid = (int)threadIdx.x;
  const int bh = (bhRaw & 7) * 96 + (bhRaw >> 3);   // 768 = 8*96: bijective XCD swizzle
  const int w = tid >> 6, lane = tid & 63;
  const int la = lane & 15, kh = lane >> 4;
  const int b = bh / 6, h = bh - b * 6;
  const float* xf = x + (size_t)b * 256 * 384;
  const unsigned short* Wb = Wt + (size_t)h * 192 * 384;
  char* A0 = EL;            // 32 KB
  char* B0 = EL + 32768;    // 24 KB
  char* A1 = KL;            // 32 KB (scratch during GEMM)
  char* B1 = VL;            // 24 KB of 32 KB (scratch during GEMM)

  // ---------------- QKV GEMM: wave tile 64 x 48, double-buffered ----------------
  const int wr = (w >> 2) * 64, wc = (w & 3) * 48;
  f32x4 acc[4][3];
  #pragma unroll
  for (int i = 0; i < 4; ++i)
    #pragma unroll
    for (int j = 0; j < 3; ++j) acc[i][j] = f32x4{0.f, 0.f, 0.f, 0.f};

  // A reg-staging: 4 threads/row, thread covers chunks {aqq, aqq+4} (8 fp32 each)
  const int arow = tid >> 2, aqq = tid & 3;
  const float4* xfr = (const float4*)(xf + (size_t)arow * 384);

  float4 raA[4], raB[4];
  auto loadA = [&](float4 (&ra)[4], int kt) {
    const int base = kt * 16;              // float4 units (64 floats / step)
    #pragma unroll
    for (int i = 0; i < 2; ++i) {
      const int ch = aqq + 4 * i;
      ra[2*i]   = xfr[base + ch * 2];
      ra[2*i+1] = xfr[base + ch * 2 + 1];
    }
  };
  auto writeA = [&](char* A, const float4 (&ra)[4]) {
    #pragma unroll
    for (int i = 0; i < 2; ++i) {
      const int ch = aqq + 4 * i;
      float4 va = ra[2*i], vb = ra[2*i+1];
      short8 o;
      o[0] = (short)f2bf(va.x); o[1] = (short)f2bf(va.y);
      o[2] = (short)f2bf(va.z); o[3] = (short)f2bf(va.w);
      o[4] = (short)f2bf(vb.x); o[5] = (short)f2bf(vb.y);
      o[6] = (short)f2bf(vb.z); o[7] = (short)f2bf(vb.w);
      *(short8*)(A + arow * 128 + ((ch ^ (arow & 7)) << 4)) = o;
    }
  };
  auto stageB = [&](char* B, int kt) {     // gll16, [192][64] bf16, 24KB
    const int Lb0 = tid * 16;
    const int row0 = Lb0 >> 7;
    const int kcs0 = ((Lb0 >> 4) & 7) ^ (row0 & 7);
    gll16(Wb + (size_t)row0 * 384 + kt * 64 + kcs0 * 8, B + Lb0);
    if (tid < 512) {
      const int Lb = 16384 + tid * 16;
      const int row = Lb >> 7;
      const int kcs = ((Lb >> 4) & 7) ^ (row & 7);
      gll16(Wb + (size_t)row * 384 + kt * 64 + kcs * 8, B + Lb);
    }
  };

  auto compute = [&](const char* A, const char* B) {
    #pragma unroll
    for (int kk = 0; kk < 2; ++kk) {
      const int ch = kk * 4 + kh;
      short8 a[4], bfr[3];
      #pragma unroll
      for (int mi = 0; mi < 4; ++mi) {
        const int r = wr + mi * 16 + la;
        a[mi] = *(const short8*)(A + r * 128 + ((ch ^ (r & 7)) << 4));
      }
      #pragma unroll
      for (int ni = 0; ni < 3; ++ni) {
        const int rB = wc + ni * 16 + la;
        bfr[ni] = *(const short8*)(B + rB * 128 + ((ch ^ (rB & 7)) << 4));
      }
      __builtin_amdgcn_s_setprio(1);
      #pragma unroll
      for (int mi = 0; mi < 4; ++mi)
        #pragma unroll
        for (int ni = 0; ni < 3; ++ni)
          acc[mi][ni] = __builtin_amdgcn_mfma_f32_16x16x32_bf16(a[mi], bfr[ni], acc[mi][ni], 0, 0, 0);
      __builtin_amdgcn_s_setprio(0);
    }
  };

  // prologue: raA=x(0) (cold wait in writeA), raB=x(1) in flight
  loadA(raA, 0);
  loadA(raB, 1);
  stageB(B0, 0);
  writeA(A0, raA);
  __syncthreads();                       // A0+B0 ready

  // step 0: compute k=0; write x(1); load x(2)
  loadA(raA, 2); stageB(B1, 1); writeA(A1, raB); compute(A0, B0);
  __syncthreads();
  // step 1: compute k=1; write x(2); load x(3)
  loadA(raB, 3); stageB(B0, 2); writeA(A0, raA); compute(A1, B1);
  __syncthreads();
  // step 2
  loadA(raA, 4); stageB(B1, 3); writeA(A1, raB); compute(A0, B0);
  __syncthreads();
  // step 3
  loadA(raB, 5); stageB(B0, 4); writeA(A0, raA); compute(A1, B1);
  __syncthreads();
  // step 4
  stageB(B1, 5); writeA(A1, raB); compute(A0, B0);
  __syncthreads();
  // step 5
  compute(A1, B1);
  __syncthreads();   // all reads of A1/B1 done before epilogue overwrites KL/VL

  // ---- epilogue: Q -> Qtmp (EL, [256][64] swizzled), K -> KL, V^T -> VL ----
  #pragma unroll
  for (int mi = 0; mi < 4; ++mi) {
    #pragma unroll
    for (int ni = 0; ni < 3; ++ni) {
      const int col = wc + ni * 16 + la;
      const int tb = wr + mi * 16 + kh * 4;
      if (col < 64) {
        const int d = col;
        #pragma unroll
        for (int j = 0; j < 4; ++j) {
          const int t = tb + j;
          *(unsigned short*)(EL + t * 128 + (((d >> 3) ^ (t & 7)) << 4) + (d & 7) * 2)
              = f2bf(acc[mi][ni][j]);
        }
      } else if (col < 128) {
        const int d = col - 64;
        #pragma unroll
        for (int j = 0; j < 4; ++j) {
          const int t = tb + j;
          *(unsigned short*)(KL + t * 128 + (((d >> 3) ^ (t & 7)) << 4) + (d & 7) * 2)
              = f2bf(acc[mi][ni][j]);
        }
      } else {
        const int d = col - 128;
        u16x4 pk;
        #pragma unroll
        for (int j = 0; j < 4; ++j) pk[j] = f2bf(acc[mi][ni][j]);
        *(u16x4*)(VL + d * 512 + (((tb >> 3) ^ (d & 7)) << 4) + (tb & 7) * 2) = pk;
      }
    }
  }
  __syncthreads();

  // ---- hoist Q fragments for this wave's PAIR {p, 15-p}, p = w>>1 ----
  const int p = w >> 1;
  const int rts[2] = { p, 15 - p };
  short8 qa[2][2];
  #pragma unroll
  for (int ti = 0; ti < 2; ++ti)
    #pragma unroll
    for (int kk = 0; kk < 2; ++kk) {
      const int r = rts[ti] * 16 + la;
      const int ch = kk * 4 + kh;
      qa[ti][kk] = *(const short8*)(EL + r * 128 + ((ch ^ (r & 7)) << 4));
    }
  __syncthreads();   // EL now free for E strips

  int wps[2], eoffs[2];
  #pragma unroll
  for (int ti = 0; ti < 2; ++ti) {
    const int rt = rts[ti];
    wps[ti] = 32 * ((rt + 2) >> 1);
    const int S = (rt & 1) ? ((rt + 1) * (rt + 1) / 4) : (rt * (rt + 2) / 4);
    eoffs[ti] = 1024 * S;
  }

  // ---- zero own Lpart row (wave-local) ----
  #pragma unroll
  for (int i = 0; i < 4; ++i) Lpart[w][i * 64 + lane] = 0.f;

  // ---- QK^T + masked exp -> E strips; ns-parity split across the pair's waves ----
  #pragma unroll
  for (int ti = 0; ti < 2; ++ti) {
    const int rt = rts[ti], wp = wps[ti], stride = wp * 2;
    char* Ebase = EL + eoffs[ti];
    const int nns = wp >> 4;
    for (int ns = (w & 1); ns < nns; ns += 2) {
      f32x4 s4 = f32x4{0.f, 0.f, 0.f, 0.f};
      #pragma unroll
      for (int kk = 0; kk < 2; ++kk) {
        const int rB = ns * 16 + la, kc = kk * 4 + kh;
        short8 bf = *(const short8*)(KL + rB * 128 + ((kc ^ (rB & 7)) << 4));
        s4 = __builtin_amdgcn_mfma_f32_16x16x32_bf16(qa[ti][kk], bf, s4, 0, 0, 0);
      }
      const int c = ns * 16 + la, cc = c >> 3, co = (c & 7) * 2;
      float ps = 0.f;
      #pragma unroll
      for (int j = 0; j < 4; ++j) {
        const int r = kh * 4 + j;
        const int t = rt * 16 + r;
        const float e = (t >= c) ? __expf(s4[j] * SCALE) : 0.f;
        ps += e;
        *(unsigned short*)(Ebase + r * stride + ((cc ^ (r & 3)) << 4) + co) = f2bf(e);
      }
      ps += __shfl_xor(ps, 16);
      ps += __shfl_xor(ps, 32);        // 16-row tile-column sum in all kh lanes
      if (kh == 0) Lpart[w][c] += ps;  // wave-local row: no race
    }
  }
  __syncthreads();

  if (tid < 256) {
    float Ls = 0.f;
    #pragma unroll
    for (int ww = 0; ww < 16; ++ww) Ls += Lpart[ww][tid];
    invL[tid] = 1.f / Ls;
  }
  __syncthreads();

  // ---- fold 1/L_s into V (1024 threads: 2 chunks each) ----
  {
    const int d = tid >> 4, qq = tid & 15;
    #pragma unroll
    for (int i = 0; i < 2; ++i) {
      const int kcp = qq * 2 + i;
      char* pch = VL + d * 512 + kcp * 16;
      short8 v = *(short8*)pch;
      const int sb = (kcp ^ (d & 7)) * 8;
      short8 o;
      #pragma unroll
      for (int e = 0; e < 8; ++e)
        o[e] = (short)f2bf(bf2f((unsigned short)v[e]) * invL[sb + e]);
      *(short8*)pch = o;
    }
  }
  __syncthreads();

  // ---- O = E * V': big tile to wave bigw = 2p + ((p>>1)&1) (SIMD-balanced) ----
  unsigned short* Og = O + (size_t)b * 256 * 384 + h * 64;
  {
    const int bigw = 2 * p + ((p >> 1) & 1);
    const int ti = (w == bigw) ? 1 : 0;
    const int rt = rts[ti], wp = wps[ti], stride = wp * 2;
    const char* Ebase = EL + eoffs[ti];
    f32x4 oacc[4];
    #pragma unroll
    for (int nd = 0; nd < 4; ++nd) oacc[nd] = f32x4{0.f, 0.f, 0.f, 0.f};
    const int nks = wp >> 5;
    for (int ks = 0; ks < nks; ++ks) {
      const int cc = ks * 4 + kh;
      short8 ea = *(const short8*)(Ebase + la * stride + ((cc ^ (la & 3)) << 4));
      __builtin_amdgcn_s_setprio(1);
      #pragma unroll
      for (int nd = 0; nd < 4; ++nd) {
        const int d = nd * 16 + la;
        short8 vb = *(const short8*)(VL + d * 512 + ((cc ^ (d & 7)) << 4));
        oacc[nd] = __builtin_amdgcn_mfma_f32_16x16x32_bf16(ea, vb, oacc[nd], 0, 0, 0);
      }
      __builtin_amdgcn_s_setprio(0);
    }
    #pragma unroll
    for (int nd = 0; nd < 4; ++nd) {
      const int d = nd * 16 + la;
      #pragma unroll
      for (int j = 0; j < 4; ++j) {
        const int t = rt * 16 + kh * 4 + j;
        Og[(size_t)t * 384 + d] = f2bf(oacc[nd][j]);
      }
    }
  }
}

// ---------------- proj GEMM: out = O * proj + bias (XCD-swizzled) ----------------
__global__ __launch_bounds__(512, 1)
void proj_gemm(const unsigned short* __restrict__ A, const unsigned short* __restrict__ Bt,
               float* __restrict__ Co, const float* __restrict__ bias)
{
  __shared__ __align__(16) unsigned short AL[128 * 384];    // 96 KB
  __shared__ __align__(16) unsigned short BL[2][128 * 64];  // 2 x 16 KB
  const int tid = (int)threadIdx.x, w = tid >> 6, lane = tid & 63;
  const int la = lane & 15, kh = lane >> 4;
  // 256 = 8*32 bijective swizzle: same-XCD as the qkv blocks that wrote these rows
  const int mt = ((int)blockIdx.x & 7) * 32 + ((int)blockIdx.x >> 3);
  const int m0 = mt * 128;

  {
    const int row = tid >> 2, qq = tid & 3;
    const short8* O8 = (const short8*)(A + (size_t)(m0 + row) * 384);
    #pragma unroll
    for (int i = 0; i < 12; ++i) {
      const int ch = qq + 4 * i;
      *(short8*)((char*)AL + row * 768 + ((ch ^ (row & 7)) << 4)) = O8[ch];
    }
  }

  auto stageB = [&](int buf, int n0, int k0) {
    #pragma unroll
    for (int i = 0; i < 2; ++i) {
      const int Lb = i * 8192 + tid * 16;
      const int row = Lb >> 7;
      const int kcs = ((Lb >> 4) & 7) ^ (row & 7);
      gll16(Bt + (size_t)(n0 + row) * 384 + k0 + kcs * 8, (char*)BL[buf] + Lb);
    }
  };

  stageB(0, 0, 0);
  __syncthreads();

  const int wr = (w >> 2) * 64, wc = (w & 3) * 32;
  int buf = 0;
  for (int nt = 0; nt < 3; ++nt) {
    f32x4 acc[4][2];
    #pragma unroll
    for (int i = 0; i < 4; ++i) { acc[i][0] = f32x4{0.f,0.f,0.f,0.f}; acc[i][1] = f32x4{0.f,0.f,0.f,0.f}; }

    for (int kt = 0; kt < 6; ++kt) {
      if (kt < 5)          stageB(buf ^ 1, nt * 128, (kt + 1) * 64);
      else if (nt + 1 < 3) stageB(buf ^ 1, (nt + 1) * 128, 0);
      #pragma unroll
      for (int kk = 0; kk < 2; ++kk) {
        short8 a[4], bb[2];
        const int chA = kt * 8 + kk * 4 + kh;
        #pragma unroll
        for (int mi = 0; mi < 4; ++mi) {
          const int r = wr + mi * 16 + la;
          a[mi] = *(const short8*)((const char*)AL + r * 768 + ((chA ^ (r & 7)) << 4));
        }
        const int chB = kk * 4 + kh;
        #pragma unroll
        for (int ni = 0; ni < 2; ++ni) {
          const int rB = wc + ni * 16 + la;
          bb[ni] = *(const short8*)((const char*)BL[buf] + rB * 128 + ((chB ^ (rB & 7)) << 4));
        }
        __builtin_amdgcn_s_setprio(1);
        #pragma unroll
        for (int mi = 0; mi < 4; ++mi)
          #pragma unroll
          for (int ni = 0; ni < 2; ++ni)
            acc[mi][ni] = __builtin_amdgcn_mfma_f32_16x16x32_bf16(a[mi], bb[ni], acc[mi][ni], 0, 0, 0);
        __builtin_amdgcn_s_setprio(0);
      }
      __syncthreads();
      buf ^= 1;
    }

    #pragma unroll
    for (int mi = 0; mi < 4; ++mi) {
      const int mbase = m0 + wr + mi * 16 + kh * 4;
      #pragma unroll
      for (int ni = 0; ni < 2; ++ni) {
        const int nl = nt * 128 + wc + ni * 16 + la;
        const float bn = bias[nl];
        #pragma unroll
        for (int j = 0; j < 4; ++j)
          Co[(size_t)(mbase + j) * 384 + nl] = acc[mi][ni][j] + bn;
      }
    }
  }
}

// ================= fallback (fp32) for small ws =================
__global__ __launch_bounds__(256, 1)
void mha_fused(const float* __restrict__ x, const float* __restrict__ Wq,
               const float* __restrict__ Wk, const float* __restrict__ Wv,
               const float* __restrict__ Wp, const float* __restrict__ bp,
               float* __restrict__ out)
{
  const int bh = blockIdx.x;
  const int b = bh / HEADS, h = bh % HEADS;
  const int tid = (int)threadIdx.x;
  const int wave = tid >> 6, lane = tid & 63;
  const float* xb = x + (size_t)b * TT * EMB;
  const float* wq = Wq + (size_t)h * EMB * DH;
  const float* wk = Wk + (size_t)h * EMB * DH;
  const float* wv = Wv + (size_t)h * EMB * DH;
  __shared__ float Ks[TT][68];
  __shared__ float Vs[TT][64];
  __shared__ float Qt[64][68];
  for (int c = 0; c < 4; ++c) {
    const int s0 = wave * 64 + c * 16;
    float ak[16], av[16];
    #pragma unroll
    for (int r = 0; r < 16; ++r) { ak[r] = 0.f; av[r] = 0.f; }
    for (int e = 0; e < EMB; ++e) {
      const float kk = wk[e * DH + lane];
      const float vv = wv[e * DH + lane];
      #pragma unroll
      for (int r = 0; r < 16; ++r) {
        const float xv = xb[(s0 + r) * EMB + e];
        ak[r] += xv * kk; av[r] += xv * vv;
      }
    }
    #pragma unroll
    for (int r = 0; r < 16; ++r) { Ks[s0 + r][lane] = ak[r]; Vs[s0 + r][lane] = av[r]; }
  }
  __syncthreads();
  const int s = tid;
  float kreg[64];
  {
    const float4* k4 = (const float4*)&Ks[s][0];
    #pragma unroll
    for (int i = 0; i < 16; ++i) {
      float4 kv = k4[i];
      kreg[4*i+0] = kv.x; kreg[4*i+1] = kv.y; kreg[4*i+2] = kv.z; kreg[4*i+3] = kv.w;
    }
  }
  float Lsum = 0.f;
  for (int tile = 0; tile < 4; ++tile) {
    {
      const int r0 = tile * 64 + wave * 16;
      float aq[16];
      #pragma unroll
      for (int r = 0; r < 16; ++r) aq[r] = 0.f;
      for (int e = 0; e < EMB; ++e) {
        const float qw = wq[e * DH + lane];
        #pragma unroll
        for (int r = 0; r < 16; ++r) aq[r] += xb[(r0 + r) * EMB + e] * qw;
      }
      __syncthreads();
      #pragma unroll
      for (int r = 0; r < 16; ++r) Qt[wave*16 + r][lane] = aq[r];
      __syncthreads();
    }
    const int tbase = tile * 64;
    if (tbase + 63 >= s) {
      for (int tr = 0; tr < 64; ++tr) {
        const int t = tbase + tr;
        if (t < s) continue;
        float w = 0.f;
        const float4* q4 = (const float4*)&Qt[tr][0];
        #pragma unroll
        for (int i = 0; i < 16; ++i) {
          float4 qv = q4[i];
          w += qv.x*kreg[4*i+0] + qv.y*kreg[4*i+1] + qv.z*kreg[4*i+2] + qv.w*kreg[4*i+3];
        }
        Lsum += __expf(w * SCALE);
      }
    }
  }
  __syncthreads();
  {
    const float invL = 1.0f / Lsum;
    float4* v4 = (float4*)&Vs[s][0];
    #pragma unroll
    for (int i = 0; i < 16; ++i) {
      float4 vv = v4[i];
      vv.x *= invL; vv.y *= invL; vv.z *= invL; vv.w *= invL;
      v4[i] = vv;
    }
  }
  __syncthreads();
  const float bias1 = bp[tid];
  const float bias2 = (tid < 128) ? bp[256 + tid] : 0.f;
  const int tr = tid >> 2, dq = tid & 3;
  float* ob = out + (size_t)b * TT * EMB;
  for (int tile = 0; tile < 4; ++tile) {
    {
      const int r0 = tile * 64 + wave * 16;
      float aq[16];
      #pragma unroll
      for (int r = 0; r < 16; ++r) aq[r] = 0.f;
      for (int e = 0; e < EMB; ++e) {
        const float qw = wq[e * DH + lane];
        #pragma unroll
        for (int r = 0; r < 16; ++r) aq[r] += xb[(r0 + r) * EMB + e] * qw;
      }
      __syncthreads();
      #pragma unroll
      for (int r = 0; r < 16; ++r) Qt[wave*16 + r][lane] = aq[r];
      __syncthreads();
    }
    const int t = tile * 64 + tr;
    float qreg[16];
    {
      const float4* q4 = (const float4*)&Qt[tr][dq * 16];
      #pragma unroll
      for (int i = 0; i < 4; ++i) {
        float4 qv = q4[i];
        qreg[4*i+0] = qv.x; qreg[4*i+1] = qv.y; qreg[4*i+2] = qv.z; qreg[4*i+3] = qv.w;
      }
    }
    float acc[16];
    #pragma unroll
    for (int i = 0; i < 16; ++i) acc[i] = 0.f;
    for (int s2 = 0; s2 <= t; ++s2) {
      const float4* kk4 = (const float4*)&Ks[s2][dq * 16];
      float part = 0.f;
      #pragma unroll
      for (int i = 0; i < 4; ++i) {
        float4 kv = kk4[i];
        part += qreg[4*i+0]*kv.x + qreg[4*i+1]*kv.y + qreg[4*i+2]*kv.z + qreg[4*i+3]*kv.w;
      }
      part += __shfl_xor(part, 1);
      part += __shfl_xor(part, 2);
      const float p = __expf(part * SCALE);
      const float4* vv4 = (const float4*)&Vs[s2][dq * 16];
      #pragma unroll
      for (int i = 0; i < 4; ++i) {
        float4 vv = vv4[i];
        acc[4*i+0] += p * vv.x; acc[4*i+1] += p * vv.y;
        acc[4*i+2] += p * vv.z; acc[4*i+3] += p * vv.w;
      }
    }
    __syncthreads();
    #pragma unroll
    for (int i = 0; i < 16; ++i) Qt[tr][dq*16 + i] = acc[i];
    __syncthreads();
    const int c1 = tid;
    const int c2 = 256 + tid;
    for (int rg = 0; rg < 4; ++rg) {
      float a1[16], a2[16];
      #pragma unroll
      for (int r = 0; r < 16; ++r) { a1[r] = 0.f; a2[r] = 0.f; }
      for (int d = 0; d < 64; ++d) {
        const float wp1 = Wp[(size_t)(h*64 + d) * EMB + c1];
        const float wp2 = (tid < 128) ? Wp[(size_t)(h*64 + d) * EMB + c2] : 0.f;
        #pragma unroll
        for (int r = 0; r < 16; ++r) {
          const float a = Qt[rg*16 + r][d];
          a1[r] += a * wp1; a2[r] += a * wp2;
        }
      }
      if (h == 0) {
        #pragma unroll
        for (int r = 0; r < 16; ++r) { a1[r] += bias1; a2[r] += bias2; }
      }
      const int trow0 = tile*64 + rg*16;
      #pragma unroll
      for (int r = 0; r < 16; ++r)
        atomicAdd(&ob[(size_t)(trow0 + r) * EMB + c1], a1[r]);
      if (tid < 128) {
        #pragma unroll
        for (int r = 0; r < 16; ++r)
          atomicAdd(&ob[(size_t)(trow0 + r) * EMB + c2], a2[r]);
      }
    }
    __syncthreads();
  }
}

extern "C" void kernel_launch(void* const* d_in, const int* in_sizes, int n_in,
                              void* d_out, int out_size, void* d_ws, size_t ws_size,
                              hipStream_t stream) {
  const float* x  = (const float*)d_in[0];
  const float* Wq = (const float*)d_in[1];
  const float* Wk = (const float*)d_in[2];
  const float* Wv = (const float*)d_in[3];
  const float* Wp = (const float*)d_in[4];
  const float* bp = (const float*)d_in[5];

  const int nb = in_sizes[0] / (TT * EMB);       // batch (128)
  const size_t M = (size_t)nb * TT;              // 32768 rows
  const size_t XB = M * EMB * 2;                 // bf16 activation bytes (25 MB)
  const size_t WT = (size_t)1536 * 384 * 2;

  const size_t off_wt = 0;
  const size_t off_o  = off_wt + WT;
  const size_t need   = off_o + XB;

  if (ws_size < need || nb * HEADS != 768) {
    hipMemsetAsync(d_out, 0, (size_t)out_size * sizeof(float), stream);
    mha_fused<<<nb * HEADS, 256, 0, stream>>>(x, Wq, Wk, Wv, Wp, bp, (float*)d_out);
    return;
  }

  char* ws = (char*)d_ws;
  unsigned short* Wt = (unsigned short*)(ws + off_wt);
  unsigned short* Ow = (unsigned short*)(ws + off_o);

  build_wt<<<288, 256, 0, stream>>>(Wq, Wk, Wv, Wp, Wt);

  qkv_attn<<<nb * HEADS, 1024, 0, stream>>>(x, Wt, Ow);

  proj_gemm<<<(unsigned)(M / 128), 512, 0, stream>>>(
      Ow, Wt + (size_t)1152 * 384, (float*)d_out, bp);
}